// Round 1
// baseline (332.776 us; speedup 1.0000x reference)
//
#include <hip/hip_runtime.h>
#include <hip/hip_bf16.h>

typedef unsigned short u16;
typedef short short8 __attribute__((ext_vector_type(8)));
typedef u16 u16x8 __attribute__((ext_vector_type(8)));
typedef float f32x4 __attribute__((ext_vector_type(4)));

#define MFMA(a, b, c) __builtin_amdgcn_mfma_f32_16x16x32_bf16((a), (b), (c), 0, 0, 0)

#define NB 2
#define NS 2048
#define ND 1024
#define NH 16

// ---------- helpers ----------
__device__ __forceinline__ u16 f2bf(float f) {
  unsigned u = __float_as_uint(f);
  unsigned r = (u + 0x7fffu + ((u >> 16) & 1u)) >> 16;   // RNE
  return (u16)r;
}
__device__ __forceinline__ float bf2f(u16 h) {
  return __uint_as_float(((unsigned)h) << 16);
}
__device__ __forceinline__ void async16(const void* g, void* l) {
  __builtin_amdgcn_global_load_lds(
      (const __attribute__((address_space(1))) void*)g,
      (__attribute__((address_space(3))) void*)l, 16, 0, 0);
}

// ---------- 1. f32 -> bf16 convert (x, wq, wk, wv, wo) ----------
__global__ __launch_bounds__(256) void convert_kernel(
    const float* __restrict__ x, const float* __restrict__ wq,
    const float* __restrict__ wk, const float* __restrict__ wv,
    const float* __restrict__ wo, u16* __restrict__ ws) {
  int blk = blockIdx.x;
  const float* src; u16* dst;
  if (blk < 2048)      { src = x;  dst = ws; }
  else if (blk < 2560) { src = wq; dst = ws + 4194304;               blk -= 2048; }
  else if (blk < 3072) { src = wk; dst = ws + 4194304 + 1048576;     blk -= 2560; }
  else if (blk < 3584) { src = wv; dst = ws + 4194304 + 2 * 1048576; blk -= 3072; }
  else                 { src = wo; dst = ws + 4194304 + 3 * 1048576; blk -= 3584; }
  int idx = (blk * 256 + threadIdx.x) * 8;
  float4 v0 = *(const float4*)(src + idx);
  float4 v1 = *(const float4*)(src + idx + 4);
  u16x8 o;
  o[0] = f2bf(v0.x); o[1] = f2bf(v0.y); o[2] = f2bf(v0.z); o[3] = f2bf(v0.w);
  o[4] = f2bf(v1.x); o[5] = f2bf(v1.y); o[6] = f2bf(v1.z); o[7] = f2bf(v1.w);
  *(u16x8*)(dst + idx) = o;
}

// ---------- GEMM core: C[128x128] = A[128xK] * B[128xK]^T (NT, bf16, f32 acc) ----------
// m97 structure: 4 waves (2x2), each wave 64x64 = 4x4 fragments of 16x16x32.
__device__ __forceinline__ void gemm_tile(const u16* __restrict__ A,
                                          const u16* __restrict__ Bm, int K,
                                          int rowBase, int colBase, u16* As,
                                          u16* Bs, f32x4 acc[4][4]) {
  const int tid = threadIdx.x;
  const int lane = tid & 63, wid = tid >> 6;
  const int wr = wid >> 1, wc = wid & 1;
  const int g = lane >> 4, r = lane & 15;

#pragma unroll
  for (int m = 0; m < 4; m++)
#pragma unroll
    for (int n = 0; n < 4; n++) acc[m][n] = (f32x4){0.f, 0.f, 0.f, 0.f};

  const int nkt = K >> 6;
  for (int kt = 0; kt < nkt; ++kt) {
    // stage A tile: 128 rows x 64 k = 1024 chunks of 16B, 4 per thread
#pragma unroll
    for (int i = 0; i < 4; ++i) {
      int c = i * 256 + tid;
      int row = c >> 3, kc = c & 7;
      async16(A + (size_t)(rowBase + row) * K + (kt << 6) + kc * 8,
              (char*)As + c * 16);
    }
#pragma unroll
    for (int i = 0; i < 4; ++i) {
      int c = i * 256 + tid;
      int row = c >> 3, kc = c & 7;
      async16(Bm + (size_t)(colBase + row) * K + (kt << 6) + kc * 8,
              (char*)Bs + c * 16);
    }
    __syncthreads();  // drains vmcnt before LDS reads
#pragma unroll
    for (int ks = 0; ks < 2; ++ks) {
      short8 af[4], bfr[4];
#pragma unroll
      for (int m = 0; m < 4; m++)
        af[m] = *(const short8*)(As + (wr * 64 + m * 16 + r) * 64 + ks * 32 + g * 8);
#pragma unroll
      for (int n = 0; n < 4; n++)
        bfr[n] = *(const short8*)(Bs + (wc * 64 + n * 16 + r) * 64 + ks * 32 + g * 8);
#pragma unroll
      for (int m = 0; m < 4; m++)
#pragma unroll
        for (int n = 0; n < 4; n++)
          acc[m][n] = MFMA(af[m], bfr[n], acc[m][n]);
    }
    __syncthreads();  // protect LDS before next stage
  }
}

// ---------- 2. fused QKV projection (grid.z selects weight) ----------
__global__ __launch_bounds__(256) void gemm_qkv(
    const u16* __restrict__ xb, const u16* __restrict__ wqb,
    const u16* __restrict__ wkb, const u16* __restrict__ wvb,
    u16* __restrict__ qb, u16* __restrict__ kb, u16* __restrict__ vt) {
  __shared__ u16 As[128 * 64], Bs[128 * 64];
  const int z = blockIdx.z;
  const u16* W = (z == 0) ? wqb : (z == 1) ? wkb : wvb;
  f32x4 acc[4][4];
  gemm_tile(xb, W, 1024, blockIdx.y * 128, blockIdx.x * 128, As, Bs, acc);

  const int lane = threadIdx.x & 63, wid = threadIdx.x >> 6;
  const int wr = wid >> 1, wc = wid & 1, g = lane >> 4, r = lane & 15;
  const int rowB = blockIdx.y * 128 + wr * 64;
  const int colB = blockIdx.x * 128 + wc * 64;
  if (z < 2) {
    u16* dst = z ? kb : qb;
#pragma unroll
    for (int m = 0; m < 4; m++)
#pragma unroll
      for (int n = 0; n < 4; n++)
#pragma unroll
        for (int i = 0; i < 4; i++)
          dst[(size_t)(rowB + m * 16 + g * 4 + i) * 1024 + colB + n * 16 + r] =
              f2bf(acc[m][n][i]);
  } else {
    // V: write transposed vt[b][h][d][s]
#pragma unroll
    for (int m = 0; m < 4; m++)
#pragma unroll
      for (int n = 0; n < 4; n++)
#pragma unroll
        for (int i = 0; i < 4; i++) {
          int row = rowB + m * 16 + g * 4 + i;  // b*2048 + s
          int col = colB + n * 16 + r;          // h*64 + d
          int b = row >> 11, s = row & 2047;
          vt[(size_t)((b * 16 + (col >> 6)) * 64 + (col & 63)) * 2048 + s] =
              f2bf(acc[m][n][i]);
        }
  }
}

// ---------- 3. RoPE in place on q, k ----------
__global__ __launch_bounds__(256) void rope_kernel(u16* __restrict__ qb,
                                                   u16* __restrict__ kb,
                                                   const int* __restrict__ tp) {
  int t = blockIdx.x * 256 + threadIdx.x;  // 524288 threads
  int dg = t & 7;
  int h = (t >> 3) & 15;
  int s = (t >> 7) & 2047;
  int b = t >> 18;
  size_t off = (size_t)((b << 11) + s) * 1024 + (h << 6) + dg * 8;
  float fp = (float)tp[(b << 11) + s];
  u16x8 qv = *(u16x8*)(qb + off), kv = *(u16x8*)(kb + off);
  u16x8 qo, ko;
#pragma unroll
  for (int i = 0; i < 4; i++) {
    int p = dg * 4 + i;
    float freq = __powf(10000.0f, -(float)p / 32.0f);
    float ang = fp * freq;
    float sn, cs;
    sincosf(ang, &sn, &cs);
    float qe = bf2f(qv[2 * i]), qd = bf2f(qv[2 * i + 1]);
    float ke = bf2f(kv[2 * i]), kd = bf2f(kv[2 * i + 1]);
    qo[2 * i] = f2bf(qe * cs - qd * sn);
    qo[2 * i + 1] = f2bf(qe * sn + qd * cs);
    ko[2 * i] = f2bf(ke * cs - kd * sn);
    ko[2 * i + 1] = f2bf(ke * sn + kd * cs);
  }
  *(u16x8*)(qb + off) = qo;
  *(u16x8*)(kb + off) = ko;
}

// ---------- 4. flash attention: 1 wave = 16 q-rows, KV tiles of 64 ----------
__global__ __launch_bounds__(256) void attn_kernel(const u16* __restrict__ qb,
                                                   const u16* __restrict__ kb,
                                                   const u16* __restrict__ vt,
                                                   u16* __restrict__ ab) {
  __shared__ u16 plds[4][16 * 64];
  const int tid = threadIdx.x, wid = tid >> 6, lane = tid & 63;
  const int g = lane >> 4, r = lane & 15;
  const int gw = blockIdx.x * 4 + wid;
  const int qt = gw & 127;  // 128 q-tiles per (b,h)
  const int bh = gw >> 7;
  const int b = bh >> 4, h = bh & 15;
  const int qw = qt << 4;

  short8 aq0, aq1;
  {
    const u16* qp = qb + (size_t)((b << 11) + qw + r) * 1024 + (h << 6) + g * 8;
    aq0 = *(const short8*)qp;
    aq1 = *(const short8*)(qp + 32);
  }
  f32x4 O[4];
  float m_r[4], l_r[4];
#pragma unroll
  for (int i = 0; i < 4; i++) {
    O[i] = (f32x4){0.f, 0.f, 0.f, 0.f};
    m_r[i] = -1e30f;
    l_r[i] = 0.f;
  }

  const int jb = qw >> 6;
  for (int j = 0; j <= jb; ++j) {
    // S = Q K^T  (C layout: row=g*4+i (q), col=r (kv within 16-subtile n))
    f32x4 sa[4];
#pragma unroll
    for (int n = 0; n < 4; n++) {
      const u16* kp =
          kb + (size_t)((b << 11) + (j << 6) + n * 16 + r) * 1024 + (h << 6) + g * 8;
      f32x4 z = {0.f, 0.f, 0.f, 0.f};
      z = MFMA(aq0, *(const short8*)kp, z);
      z = MFMA(aq1, *(const short8*)(kp + 32), z);
      sa[n] = z;
    }
    const bool boundary = (j == jb);
    float pf[4][4];
#pragma unroll
    for (int i = 0; i < 4; i++) {
      const int qg = qw + g * 4 + i;
      float mx = -1e30f;
      float sv[4];
#pragma unroll
      for (int n = 0; n < 4; n++) {
        float v = sa[n][i] * 0.125f;
        if (boundary && ((j << 6) + n * 16 + r) > qg) v = -1e30f;
        sv[n] = v;
        mx = fmaxf(mx, v);
      }
      mx = fmaxf(mx, __shfl_xor(mx, 1));
      mx = fmaxf(mx, __shfl_xor(mx, 2));
      mx = fmaxf(mx, __shfl_xor(mx, 4));
      mx = fmaxf(mx, __shfl_xor(mx, 8));
      float mnew = fmaxf(m_r[i], mx);
      float sc = __expf(m_r[i] - mnew);
      float rs = 0.f;
#pragma unroll
      for (int n = 0; n < 4; n++) {
        float p = __expf(sv[n] - mnew);
        pf[n][i] = p;
        rs += p;
      }
      rs += __shfl_xor(rs, 1);
      rs += __shfl_xor(rs, 2);
      rs += __shfl_xor(rs, 4);
      rs += __shfl_xor(rs, 8);
      m_r[i] = mnew;
      l_r[i] = l_r[i] * sc + rs;
#pragma unroll
      for (int n = 0; n < 4; n++) O[n][i] *= sc;
    }
    // transpose P via per-wave LDS (C layout -> A-fragment layout)
    u16* pw = plds[wid];
#pragma unroll
    for (int n = 0; n < 4; n++)
#pragma unroll
      for (int i = 0; i < 4; i++)
        pw[(g * 4 + i) * 64 + n * 16 + r] = f2bf(pf[n][i]);
    asm volatile("s_waitcnt lgkmcnt(0)" ::: "memory");
    short8 ap0 = *(const short8*)(pw + r * 64 + g * 8);
    short8 ap1 = *(const short8*)(pw + r * 64 + 32 + g * 8);
#pragma unroll
    for (int n = 0; n < 4; n++) {
      const u16* vp =
          vt + (size_t)((bh << 6) + n * 16 + r) * 2048 + (j << 6) + g * 8;
      O[n] = MFMA(ap0, *(const short8*)vp, O[n]);
      O[n] = MFMA(ap1, *(const short8*)(vp + 32), O[n]);
    }
  }
#pragma unroll
  for (int n = 0; n < 4; n++)
#pragma unroll
    for (int i = 0; i < 4; i++) {
      float o = O[n][i] / l_r[i];
      ab[(size_t)((b << 11) + qw + g * 4 + i) * 1024 + (h << 6) + n * 16 + r] =
          f2bf(o);
    }
}

// ---------- 5. output projection: out = attn * wo^T (f32 out) ----------
__global__ __launch_bounds__(256) void gemm_ao(const u16* __restrict__ ab,
                                               const u16* __restrict__ wob,
                                               float* __restrict__ out) {
  __shared__ u16 As[128 * 64], Bs[128 * 64];
  f32x4 acc[4][4];
  gemm_tile(ab, wob, 1024, blockIdx.y * 128, blockIdx.x * 128, As, Bs, acc);
  const int lane = threadIdx.x & 63, wid = threadIdx.x >> 6;
  const int wr = wid >> 1, wc = wid & 1, g = lane >> 4, r = lane & 15;
  const int rowB = blockIdx.y * 128 + wr * 64;
  const int colB = blockIdx.x * 128 + wc * 64;
#pragma unroll
  for (int m = 0; m < 4; m++)
#pragma unroll
    for (int n = 0; n < 4; n++)
#pragma unroll
      for (int i = 0; i < 4; i++)
        out[(size_t)(rowB + m * 16 + g * 4 + i) * 1024 + colB + n * 16 + r] =
            acc[m][n][i];
}

extern "C" void kernel_launch(void* const* d_in, const int* in_sizes, int n_in,
                              void* d_out, int out_size, void* d_ws,
                              size_t ws_size, hipStream_t stream) {
  const float* x = (const float*)d_in[0];
  const int* tp = (const int*)d_in[1];
  const float* wq = (const float*)d_in[2];
  const float* wk = (const float*)d_in[3];
  const float* wv = (const float*)d_in[4];
  const float* wo = (const float*)d_in[5];
  float* out = (float*)d_out;

  u16* ws = (u16*)d_ws;
  u16* xb = ws;                   // 4194304
  u16* wqb = xb + 4194304;        // 1048576
  u16* wkb = wqb + 1048576;
  u16* wvb = wkb + 1048576;
  u16* wob = wvb + 1048576;
  u16* qb = wob + 1048576;        // 4194304
  u16* kb = qb + 4194304;
  u16* vtb = kb + 4194304;        // [b][h][d][s]
  u16* ab = vtb + 4194304;

  convert_kernel<<<4096, 256, 0, stream>>>(x, wq, wk, wv, wo, ws);
  gemm_qkv<<<dim3(8, 32, 3), 256, 0, stream>>>(xb, wqb, wkb, wvb, qb, kb, vtb);
  rope_kernel<<<2048, 256, 0, stream>>>(qb, kb, tp);
  attn_kernel<<<1024, 256, 0, stream>>>(qb, kb, vtb, ab);
  gemm_ao<<<dim3(8, 32), 256, 0, stream>>>(ab, wob, out);
}

// Round 2
// 194.026 us; speedup vs baseline: 1.7151x; 1.7151x over previous
//
#include <hip/hip_runtime.h>
#include <hip/hip_bf16.h>

typedef unsigned short u16;
typedef short short8 __attribute__((ext_vector_type(8)));
typedef u16 u16x8 __attribute__((ext_vector_type(8)));
typedef u16 u16x4 __attribute__((ext_vector_type(4)));
typedef float f32x4 __attribute__((ext_vector_type(4)));

#define MFMA(a, b, c) __builtin_amdgcn_mfma_f32_16x16x32_bf16((a), (b), (c), 0, 0, 0)

// ---------- helpers ----------
__device__ __forceinline__ u16 f2bf(float f) {
  unsigned u = __float_as_uint(f);
  unsigned r = (u + 0x7fffu + ((u >> 16) & 1u)) >> 16;   // RNE
  return (u16)r;
}
__device__ __forceinline__ float bf2f(u16 h) {
  return __uint_as_float(((unsigned)h) << 16);
}
__device__ __forceinline__ void async16(const void* g, void* l) {
  __builtin_amdgcn_global_load_lds(
      (const __attribute__((address_space(1))) void*)g,
      (__attribute__((address_space(3))) void*)l, 16, 0, 0);
}

// ---------- 1. f32 -> bf16 convert (x, wq, wk, wv, wo) ----------
__global__ __launch_bounds__(256) void convert_kernel(
    const float* __restrict__ x, const float* __restrict__ wq,
    const float* __restrict__ wk, const float* __restrict__ wv,
    const float* __restrict__ wo, u16* __restrict__ ws) {
  int blk = blockIdx.x;
  const float* src; u16* dst;
  if (blk < 2048)      { src = x;  dst = ws; }
  else if (blk < 2560) { src = wq; dst = ws + 4194304;               blk -= 2048; }
  else if (blk < 3072) { src = wk; dst = ws + 4194304 + 1048576;     blk -= 2560; }
  else if (blk < 3584) { src = wv; dst = ws + 4194304 + 2 * 1048576; blk -= 3072; }
  else                 { src = wo; dst = ws + 4194304 + 3 * 1048576; blk -= 3584; }
  int idx = (blk * 256 + threadIdx.x) * 8;
  float4 v0 = *(const float4*)(src + idx);
  float4 v1 = *(const float4*)(src + idx + 4);
  u16x8 o;
  o[0] = f2bf(v0.x); o[1] = f2bf(v0.y); o[2] = f2bf(v0.z); o[3] = f2bf(v0.w);
  o[4] = f2bf(v1.x); o[5] = f2bf(v1.y); o[6] = f2bf(v1.z); o[7] = f2bf(v1.w);
  *(u16x8*)(dst + idx) = o;
}

// ---------- GEMM core: C[128x128] = A[128xK] * B[128xK]^T (NT, bf16, f32 acc) ----------
__device__ __forceinline__ void gemm_tile(const u16* __restrict__ A,
                                          const u16* __restrict__ Bm, int K,
                                          int rowBase, int colBase, u16* As,
                                          u16* Bs, f32x4 acc[4][4]) {
  const int tid = threadIdx.x;
  const int lane = tid & 63, wid = tid >> 6;
  const int wr = wid >> 1, wc = wid & 1;
  const int g = lane >> 4, r = lane & 15;

#pragma unroll
  for (int m = 0; m < 4; m++)
#pragma unroll
    for (int n = 0; n < 4; n++) acc[m][n] = (f32x4){0.f, 0.f, 0.f, 0.f};

  const int nkt = K >> 6;
  for (int kt = 0; kt < nkt; ++kt) {
#pragma unroll
    for (int i = 0; i < 4; ++i) {
      int c = i * 256 + tid;
      int row = c >> 3, kc = c & 7;
      async16(A + (size_t)(rowBase + row) * K + (kt << 6) + kc * 8,
              (char*)As + c * 16);
    }
#pragma unroll
    for (int i = 0; i < 4; ++i) {
      int c = i * 256 + tid;
      int row = c >> 3, kc = c & 7;
      async16(Bm + (size_t)(colBase + row) * K + (kt << 6) + kc * 8,
              (char*)Bs + c * 16);
    }
    __syncthreads();
#pragma unroll
    for (int ks = 0; ks < 2; ++ks) {
      short8 af[4], bfr[4];
#pragma unroll
      for (int m = 0; m < 4; m++)
        af[m] = *(const short8*)(As + (wr * 64 + m * 16 + r) * 64 + ks * 32 + g * 8);
#pragma unroll
      for (int n = 0; n < 4; n++)
        bfr[n] = *(const short8*)(Bs + (wc * 64 + n * 16 + r) * 64 + ks * 32 + g * 8);
#pragma unroll
      for (int m = 0; m < 4; m++)
#pragma unroll
        for (int n = 0; n < 4; n++)
          acc[m][n] = MFMA(af[m], bfr[n], acc[m][n]);
    }
    __syncthreads();
  }
}

// ---------- 2. fused QKV projection (grid.z selects weight) ----------
__global__ __launch_bounds__(256) void gemm_qkv(
    const u16* __restrict__ xb, const u16* __restrict__ wqb,
    const u16* __restrict__ wkb, const u16* __restrict__ wvb,
    u16* __restrict__ qb, u16* __restrict__ kb, u16* __restrict__ vt) {
  __shared__ u16 As[128 * 64], Bs[128 * 64];
  const int z = blockIdx.z;
  const u16* W = (z == 0) ? wqb : (z == 1) ? wkb : wvb;
  f32x4 acc[4][4];
  gemm_tile(xb, W, 1024, blockIdx.y * 128, blockIdx.x * 128, As, Bs, acc);

  const int lane = threadIdx.x & 63, wid = threadIdx.x >> 6;
  const int wr = wid >> 1, wc = wid & 1, g = lane >> 4, r = lane & 15;
  const int rowB = blockIdx.y * 128 + wr * 64;
  const int colB = blockIdx.x * 128 + wc * 64;
  if (z < 2) {
    u16* dst = z ? kb : qb;
#pragma unroll
    for (int m = 0; m < 4; m++)
#pragma unroll
      for (int n = 0; n < 4; n++)
#pragma unroll
        for (int i = 0; i < 4; i++)
          dst[(size_t)(rowB + m * 16 + g * 4 + i) * 1024 + colB + n * 16 + r] =
              f2bf(acc[m][n][i]);
  } else {
#pragma unroll
    for (int m = 0; m < 4; m++)
#pragma unroll
      for (int n = 0; n < 4; n++)
#pragma unroll
        for (int i = 0; i < 4; i++) {
          int row = rowB + m * 16 + g * 4 + i;  // b*2048 + s
          int col = colB + n * 16 + r;          // h*64 + d
          int b = row >> 11, s = row & 2047;
          vt[(size_t)((b * 16 + (col >> 6)) * 64 + (col & 63)) * 2048 + s] =
              f2bf(acc[m][n][i]);
        }
  }
}

// ---------- 3. RoPE in place on q, k ----------
__global__ __launch_bounds__(256) void rope_kernel(u16* __restrict__ qb,
                                                   u16* __restrict__ kb,
                                                   const int* __restrict__ tp) {
  int t = blockIdx.x * 256 + threadIdx.x;
  int dg = t & 7;
  int h = (t >> 3) & 15;
  int s = (t >> 7) & 2047;
  int b = t >> 18;
  size_t off = (size_t)((b << 11) + s) * 1024 + (h << 6) + dg * 8;
  float fp = (float)tp[(b << 11) + s];
  u16x8 qv = *(u16x8*)(qb + off), kv = *(u16x8*)(kb + off);
  u16x8 qo, ko;
#pragma unroll
  for (int i = 0; i < 4; i++) {
    int p = dg * 4 + i;
    float freq = __powf(10000.0f, -(float)p / 32.0f);
    float ang = fp * freq;
    float sn, cs;
    sincosf(ang, &sn, &cs);
    float qe = bf2f(qv[2 * i]), qd = bf2f(qv[2 * i + 1]);
    float ke = bf2f(kv[2 * i]), kd = bf2f(kv[2 * i + 1]);
    qo[2 * i] = f2bf(qe * cs - qd * sn);
    qo[2 * i + 1] = f2bf(qe * sn + qd * cs);
    ko[2 * i] = f2bf(ke * cs - kd * sn);
    ko[2 * i + 1] = f2bf(ke * sn + kd * cs);
  }
  *(u16x8*)(qb + off) = qo;
  *(u16x8*)(kb + off) = ko;
}

// ---------- 4. flash attention, swapped-QK^T, LDS-staged K/V ----------
// Block: 4 waves, 128 q-rows (32/wave), one (b,h). KV tiles of 64, dbuf LDS.
// S^T = mfma(K, Q): lane holds (kv = mk*16+g*4+i, q = n*16+r) -> row-reduce is
// 15 reg ops + 2 shfl.  O^T = mfma(V^T, P): lane holds (d = md*16+g*4+i, q).
__global__ __launch_bounds__(256) void attn_kernel(const u16* __restrict__ qg,
                                                   const u16* __restrict__ kg,
                                                   const u16* __restrict__ vt,
                                                   u16* __restrict__ ab) {
  __shared__ u16 Ks[2][64 * 64];
  __shared__ u16 Vs[2][64 * 64];
  __shared__ u16 Ps[4][32 * 64];
  const int tid = threadIdx.x, wid = tid >> 6, lane = tid & 63;
  const int g = lane >> 4, r = lane & 15;
  const int qb = blockIdx.x, bh = blockIdx.y;
  const int b = bh >> 4, h = bh & 15;
  const int q0 = qb << 7;
  const int qw = q0 + wid * 32;        // wave q base
  const int jmax = (qb << 1) + 1;      // last kv tile index for this block
  const int jmask0 = qw >> 6;          // first tile needing causal mask

  // Q fragments (B operand): [n][ks], from global, once
  short8 bq[2][2];
#pragma unroll
  for (int n = 0; n < 2; n++) {
    const u16* qp = qg + (size_t)((b << 11) + qw + n * 16 + r) * 1024 + (h << 6) + g * 8;
    bq[n][0] = *(const short8*)qp;
    bq[n][1] = *(const short8*)(qp + 32);
  }

  f32x4 accO[4][2];
  float m_r[2] = {-1e30f, -1e30f}, l_r[2] = {0.f, 0.f};
#pragma unroll
  for (int md = 0; md < 4; md++)
#pragma unroll
    for (int n = 0; n < 2; n++) accO[md][n] = (f32x4){0.f, 0.f, 0.f, 0.f};

  // Stage K tile (64 kv x 64 d) + V^T tile (64 d x 64 s), XOR-swizzled source
  // so reads at chunk ((ks*4+g)^(r&7)) are bank-spread. 1024 x 16B chunks.
#define STAGE(JT, BUF)                                                         \
  do {                                                                         \
    const int jj = (JT);                                                       \
    _Pragma("unroll") for (int i_ = 0; i_ < 2; i_++) {                         \
      int c = i_ * 256 + tid;                                                  \
      int row = c >> 3, kc = (c & 7) ^ (row & 7);                              \
      async16(kg + (size_t)((b << 11) + (jj << 6) + row) * 1024 + (h << 6) + kc * 8, \
              (char*)Ks[BUF] + c * 16);                                        \
    }                                                                          \
    _Pragma("unroll") for (int i_ = 0; i_ < 2; i_++) {                         \
      int c = i_ * 256 + tid;                                                  \
      int row = c >> 3, kc = (c & 7) ^ (row & 7);                              \
      async16(vt + (size_t)((bh << 6) + row) * 2048 + (jj << 6) + kc * 8,      \
              (char*)Vs[BUF] + c * 16);                                        \
    }                                                                          \
  } while (0)

  STAGE(0, 0);
  __syncthreads();

  for (int j = 0; j <= jmax; ++j) {
    const int cur = j & 1;
    if (j < jmax) STAGE(j + 1, cur ^ 1);   // prefetch next tile
    if ((j << 6) <= qw + 31) {             // skip fully-masked tiles
      const u16* Kb = Ks[cur];
      const u16* Vb = Vs[cur];
      // S^T
      f32x4 accS[4][2];
#pragma unroll
      for (int mk = 0; mk < 4; mk++) {
        short8 k0 = *(const short8*)(Kb + (mk * 16 + r) * 64 + ((g) ^ (r & 7)) * 8);
        short8 k1 = *(const short8*)(Kb + (mk * 16 + r) * 64 + ((4 + g) ^ (r & 7)) * 8);
#pragma unroll
        for (int n = 0; n < 2; n++) {
          f32x4 z = {0.f, 0.f, 0.f, 0.f};
          z = MFMA(k0, bq[n][0], z);
          z = MFMA(k1, bq[n][1], z);
          accS[mk][n] = z;
        }
      }
      // softmax per n (lane owns q = n*16+r)
      u16* pw = Ps[wid];
      const bool needm = (j >= jmask0);
#pragma unroll
      for (int n = 0; n < 2; n++) {
        const int qgl = qw + n * 16 + r;
        float sv[4][4];
        float pmax = -1e30f;
#pragma unroll
        for (int mk = 0; mk < 4; mk++)
#pragma unroll
          for (int i = 0; i < 4; i++) {
            float v = accS[mk][n][i] * 0.125f;
            if (needm && ((j << 6) + mk * 16 + g * 4 + i) > qgl) v = -1e30f;
            sv[mk][i] = v;
            pmax = fmaxf(pmax, v);
          }
        pmax = fmaxf(pmax, __shfl_xor(pmax, 16));
        pmax = fmaxf(pmax, __shfl_xor(pmax, 32));
        float mnew = fmaxf(m_r[n], pmax);
        float sc = __expf(m_r[n] - mnew);
        float rs = 0.f;
        const int qrow = n * 16 + r;
#pragma unroll
        for (int mk = 0; mk < 4; mk++) {
          u16x4 pk;
#pragma unroll
          for (int i = 0; i < 4; i++) {
            float p = __expf(sv[mk][i] - mnew);
            rs += p;
            pk[i] = f2bf(p);
          }
          const int chunk = (mk * 2 + (g >> 1)) ^ (qrow & 7);
          *(u16x4*)((char*)pw + qrow * 128 + chunk * 16 + (g & 1) * 8) = pk;
        }
        rs += __shfl_xor(rs, 16);
        rs += __shfl_xor(rs, 32);
        l_r[n] = l_r[n] * sc + rs;
        m_r[n] = mnew;
#pragma unroll
        for (int md = 0; md < 4; md++) accO[md][n] *= sc;
      }
      // PV: O^T += V^T * P   (B frag = P rows of 8 consecutive kv)
      short8 pb[2][2];
#pragma unroll
      for (int n = 0; n < 2; n++)
#pragma unroll
        for (int ks = 0; ks < 2; ks++) {
          const int qrow = n * 16 + r;
          const int chunk = (ks * 4 + g) ^ (qrow & 7);
          pb[n][ks] = *(const short8*)((const char*)pw + qrow * 128 + chunk * 16);
        }
#pragma unroll
      for (int md = 0; md < 4; md++) {
        short8 v0 = *(const short8*)(Vb + (md * 16 + r) * 64 + ((g) ^ (r & 7)) * 8);
        short8 v1 = *(const short8*)(Vb + (md * 16 + r) * 64 + ((4 + g) ^ (r & 7)) * 8);
#pragma unroll
        for (int n = 0; n < 2; n++) {
          accO[md][n] = MFMA(v0, pb[n][0], accO[md][n]);
          accO[md][n] = MFMA(v1, pb[n][1], accO[md][n]);
        }
      }
    }
    __syncthreads();
  }
#undef STAGE

  // epilogue: ab[b, s=q, h*64+d] = O^T / l
#pragma unroll
  for (int n = 0; n < 2; n++) {
    float inv = 1.0f / l_r[n];
#pragma unroll
    for (int md = 0; md < 4; md++) {
      u16x4 o;
#pragma unroll
      for (int i = 0; i < 4; i++) o[i] = f2bf(accO[md][n][i] * inv);
      *(u16x4*)(ab + (size_t)((b << 11) + qw + n * 16 + r) * 1024 + (h << 6) +
                md * 16 + g * 4) = o;
    }
  }
}

// ---------- 5. output projection: out = attn * wo^T (f32 out) ----------
__global__ __launch_bounds__(256) void gemm_ao(const u16* __restrict__ ab,
                                               const u16* __restrict__ wob,
                                               float* __restrict__ out) {
  __shared__ u16 As[128 * 64], Bs[128 * 64];
  f32x4 acc[4][4];
  gemm_tile(ab, wob, 1024, blockIdx.y * 128, blockIdx.x * 128, As, Bs, acc);
  const int lane = threadIdx.x & 63, wid = threadIdx.x >> 6;
  const int wr = wid >> 1, wc = wid & 1, g = lane >> 4, r = lane & 15;
  const int rowB = blockIdx.y * 128 + wr * 64;
  const int colB = blockIdx.x * 128 + wc * 64;
#pragma unroll
  for (int m = 0; m < 4; m++)
#pragma unroll
    for (int n = 0; n < 4; n++)
#pragma unroll
      for (int i = 0; i < 4; i++)
        out[(size_t)(rowB + m * 16 + g * 4 + i) * 1024 + colB + n * 16 + r] =
            acc[m][n][i];
}

extern "C" void kernel_launch(void* const* d_in, const int* in_sizes, int n_in,
                              void* d_out, int out_size, void* d_ws,
                              size_t ws_size, hipStream_t stream) {
  const float* x = (const float*)d_in[0];
  const int* tp = (const int*)d_in[1];
  const float* wq = (const float*)d_in[2];
  const float* wk = (const float*)d_in[3];
  const float* wv = (const float*)d_in[4];
  const float* wo = (const float*)d_in[5];
  float* out = (float*)d_out;

  u16* ws = (u16*)d_ws;
  u16* xb = ws;                   // 4194304
  u16* wqb = xb + 4194304;        // 1048576
  u16* wkb = wqb + 1048576;
  u16* wvb = wkb + 1048576;
  u16* wob = wvb + 1048576;
  u16* qb = wob + 1048576;        // 4194304
  u16* kb = qb + 4194304;
  u16* vtb = kb + 4194304;        // [b][h][d][s]
  u16* ab = vtb + 4194304;

  convert_kernel<<<4096, 256, 0, stream>>>(x, wq, wk, wv, wo, ws);
  gemm_qkv<<<dim3(8, 32, 3), 256, 0, stream>>>(xb, wqb, wkb, wvb, qb, kb, vtb);
  rope_kernel<<<2048, 256, 0, stream>>>(qb, kb, tp);
  attn_kernel<<<dim3(16, 32), 256, 0, stream>>>(qb, kb, vtb, ab);
  gemm_ao<<<dim3(8, 32), 256, 0, stream>>>(ab, wob, out);
}

// Round 3
// 150.198 us; speedup vs baseline: 2.2156x; 1.2918x over previous
//
#include <hip/hip_runtime.h>
#include <hip/hip_bf16.h>

typedef unsigned short u16;
typedef unsigned int u32;
typedef short short8 __attribute__((ext_vector_type(8)));
typedef u16 u16x8 __attribute__((ext_vector_type(8)));
typedef u16 u16x4 __attribute__((ext_vector_type(4)));
typedef float f32x4 __attribute__((ext_vector_type(4)));

#define MFMA(a, b, c) __builtin_amdgcn_mfma_f32_16x16x32_bf16((a), (b), (c), 0, 0, 0)

// log2(e)*0.125 folded into Q at rope time; softmax runs in exp2 domain.
#define QSCALE 0.18033688011112042f

// ---------- helpers ----------
__device__ __forceinline__ u16 f2bf(float f) {
  unsigned u = __float_as_uint(f);
  unsigned r = (u + 0x7fffu + ((u >> 16) & 1u)) >> 16;  // RNE
  return (u16)r;
}
__device__ __forceinline__ float bf2f(u16 h) {
  return __uint_as_float(((unsigned)h) << 16);
}
__device__ __forceinline__ float exp2hw(float x) {
  float r;
  asm("v_exp_f32 %0, %1" : "=v"(r) : "v"(x));
  return r;
}
__device__ __forceinline__ u32 cvtpk(float lo, float hi) {
  u32 d;
  asm("v_cvt_pk_bf16_f32 %0, %1, %2" : "=v"(d) : "v"(lo), "v"(hi));
  return d;
}
__device__ __forceinline__ void async16(const void* g, void* l) {
  __builtin_amdgcn_global_load_lds(
      (const __attribute__((address_space(1))) void*)g,
      (__attribute__((address_space(3))) void*)l, 16, 0, 0);
}

// ---------- 1. f32 -> bf16 convert (x, wq, wk, wv, wo) ----------
__global__ __launch_bounds__(256) void convert_kernel(
    const float* __restrict__ x, const float* __restrict__ wq,
    const float* __restrict__ wk, const float* __restrict__ wv,
    const float* __restrict__ wo, u16* __restrict__ ws) {
  int blk = blockIdx.x;
  const float* src; u16* dst;
  if (blk < 2048)      { src = x;  dst = ws; }
  else if (blk < 2560) { src = wq; dst = ws + 4194304;               blk -= 2048; }
  else if (blk < 3072) { src = wk; dst = ws + 4194304 + 1048576;     blk -= 2560; }
  else if (blk < 3584) { src = wv; dst = ws + 4194304 + 2 * 1048576; blk -= 3072; }
  else                 { src = wo; dst = ws + 4194304 + 3 * 1048576; blk -= 3584; }
  int idx = (blk * 256 + threadIdx.x) * 8;
  float4 v0 = *(const float4*)(src + idx);
  float4 v1 = *(const float4*)(src + idx + 4);
  u16x8 o;
  o[0] = f2bf(v0.x); o[1] = f2bf(v0.y); o[2] = f2bf(v0.z); o[3] = f2bf(v0.w);
  o[4] = f2bf(v1.x); o[5] = f2bf(v1.y); o[6] = f2bf(v1.z); o[7] = f2bf(v1.w);
  *(u16x8*)(dst + idx) = o;
}

// ---------- GEMM core: C[128x128] = A[128xK] * B[128xK]^T (NT, bf16, f32 acc) ----------
__device__ __forceinline__ void gemm_tile(const u16* __restrict__ A,
                                          const u16* __restrict__ Bm, int K,
                                          int rowBase, int colBase, u16* As,
                                          u16* Bs, f32x4 acc[4][4]) {
  const int tid = threadIdx.x;
  const int lane = tid & 63, wid = tid >> 6;
  const int wr = wid >> 1, wc = wid & 1;
  const int g = lane >> 4, r = lane & 15;

#pragma unroll
  for (int m = 0; m < 4; m++)
#pragma unroll
    for (int n = 0; n < 4; n++) acc[m][n] = (f32x4){0.f, 0.f, 0.f, 0.f};

  const int nkt = K >> 6;
  for (int kt = 0; kt < nkt; ++kt) {
#pragma unroll
    for (int i = 0; i < 4; ++i) {
      int c = i * 256 + tid;
      int row = c >> 3, kc = c & 7;
      async16(A + (size_t)(rowBase + row) * K + (kt << 6) + kc * 8,
              (char*)As + c * 16);
    }
#pragma unroll
    for (int i = 0; i < 4; ++i) {
      int c = i * 256 + tid;
      int row = c >> 3, kc = c & 7;
      async16(Bm + (size_t)(colBase + row) * K + (kt << 6) + kc * 8,
              (char*)Bs + c * 16);
    }
    __syncthreads();
#pragma unroll
    for (int ks = 0; ks < 2; ++ks) {
      short8 af[4], bfr[4];
#pragma unroll
      for (int m = 0; m < 4; m++)
        af[m] = *(const short8*)(As + (wr * 64 + m * 16 + r) * 64 + ks * 32 + g * 8);
#pragma unroll
      for (int n = 0; n < 4; n++)
        bfr[n] = *(const short8*)(Bs + (wc * 64 + n * 16 + r) * 64 + ks * 32 + g * 8);
#pragma unroll
      for (int m = 0; m < 4; m++)
#pragma unroll
        for (int n = 0; n < 4; n++)
          acc[m][n] = MFMA(af[m], bfr[n], acc[m][n]);
    }
    __syncthreads();
  }
}

// ---------- 2. fused QKV projection (grid.z selects weight) ----------
__global__ __launch_bounds__(256) void gemm_qkv(
    const u16* __restrict__ xb, const u16* __restrict__ wqb,
    const u16* __restrict__ wkb, const u16* __restrict__ wvb,
    u16* __restrict__ qb, u16* __restrict__ kb, u16* __restrict__ vt) {
  __shared__ u16 As[128 * 64], Bs[128 * 64];
  const int z = blockIdx.z;
  const u16* W = (z == 0) ? wqb : (z == 1) ? wkb : wvb;
  f32x4 acc[4][4];
  gemm_tile(xb, W, 1024, blockIdx.y * 128, blockIdx.x * 128, As, Bs, acc);

  const int lane = threadIdx.x & 63, wid = threadIdx.x >> 6;
  const int wr = wid >> 1, wc = wid & 1, g = lane >> 4, r = lane & 15;
  const int rowB = blockIdx.y * 128 + wr * 64;
  const int colB = blockIdx.x * 128 + wc * 64;
  if (z < 2) {
    u16* dst = z ? kb : qb;
#pragma unroll
    for (int m = 0; m < 4; m++)
#pragma unroll
      for (int n = 0; n < 4; n++)
#pragma unroll
        for (int i = 0; i < 4; i++)
          dst[(size_t)(rowB + m * 16 + g * 4 + i) * 1024 + colB + n * 16 + r] =
              f2bf(acc[m][n][i]);
  } else {
#pragma unroll
    for (int m = 0; m < 4; m++)
#pragma unroll
      for (int n = 0; n < 4; n++)
#pragma unroll
        for (int i = 0; i < 4; i++) {
          int row = rowB + m * 16 + g * 4 + i;  // b*2048 + s
          int col = colB + n * 16 + r;          // h*64 + d
          int b = row >> 11, s = row & 2047;
          vt[(size_t)((b * 16 + (col >> 6)) * 64 + (col & 63)) * 2048 + s] =
              f2bf(acc[m][n][i]);
        }
  }
}

// ---------- 3a. cos/sin table: tab[bs*64 + p*2 + {0,1}] = cos/sin(tp[bs]*freq_p)
__global__ __launch_bounds__(256) void rope_table(const int* __restrict__ tp,
                                                  float* __restrict__ tab) {
  int t = blockIdx.x * 256 + threadIdx.x;  // 131072
  int bs = t >> 5, p = t & 31;
  // freq = 10000^(-p/32) = exp2(-p * log2(10000)/32)
  float freq = exp2hw(-(float)p * 0.4152410118609203f);
  float ang = (float)tp[bs] * freq;
  float sn, cs;
  sincosf(ang, &sn, &cs);
  tab[bs * 64 + p * 2] = cs;
  tab[bs * 64 + p * 2 + 1] = sn;
}

// ---------- 3b. RoPE in place on q, k (q additionally scaled by QSCALE) ----
__global__ __launch_bounds__(256) void rope_kernel(u16* __restrict__ qb,
                                                   u16* __restrict__ kb,
                                                   const float* __restrict__ tab) {
  int t = blockIdx.x * 256 + threadIdx.x;
  int dg = t & 7;
  int h = (t >> 3) & 15;
  int bs = t >> 7;  // b*2048 + s
  size_t off = (size_t)bs * 1024 + (h << 6) + dg * 8;
  float4 t0 = *(const float4*)(tab + bs * 64 + dg * 8);      // p=4dg,4dg+1
  float4 t1 = *(const float4*)(tab + bs * 64 + dg * 8 + 4);  // p=4dg+2,4dg+3
  float cs_[4] = {t0.x, t0.z, t1.x, t1.z};
  float sn_[4] = {t0.y, t0.w, t1.y, t1.w};
  u16x8 qv = *(u16x8*)(qb + off), kv = *(u16x8*)(kb + off);
  u16x8 qo, ko;
#pragma unroll
  for (int i = 0; i < 4; i++) {
    float cs = cs_[i], sn = sn_[i];
    float qe = bf2f(qv[2 * i]), qd = bf2f(qv[2 * i + 1]);
    float ke = bf2f(kv[2 * i]), kd = bf2f(kv[2 * i + 1]);
    qo[2 * i]     = f2bf((qe * cs - qd * sn) * QSCALE);
    qo[2 * i + 1] = f2bf((qe * sn + qd * cs) * QSCALE);
    ko[2 * i]     = f2bf(ke * cs - kd * sn);
    ko[2 * i + 1] = f2bf(ke * sn + kd * cs);
  }
  *(u16x8*)(qb + off) = qo;
  *(u16x8*)(kb + off) = ko;
}

// ---------- 4. flash attention, causal-paired blocks ----------
// Block = (a, bh): q-tiles {a, 15-a} of 128 rows each. 8 waves; wave owns 16
// rows of each tile (grp 0 = lo, grp 1 = hi). Equal work per block (34
// grp-tiles). idx = a*32+bh puts same-bh blocks on one XCD (idx%8 = bh%8).
__global__ __launch_bounds__(512) void attn_kernel(const u16* __restrict__ qg,
                                                   const u16* __restrict__ kg,
                                                   const u16* __restrict__ vt,
                                                   u16* __restrict__ ab) {
  __shared__ u16 Ks[2][64 * 64];
  __shared__ u16 Vs[2][64 * 64];
  __shared__ u16 Ps[16][1024];  // [wid*2+grp][16 q x 64 kv]
  const int tid = threadIdx.x, wid = tid >> 6, lane = tid & 63;
  const int g = lane >> 4, r = lane & 15;
  const int a = blockIdx.x >> 5, bh = blockIdx.x & 31;
  const int b = bh >> 4, h = bh & 15;
  const int rb[2] = {(a << 7) + wid * 16, ((15 - a) << 7) + wid * 16};
  const int jend = 31 - 2 * a;

  // Q fragments per grp (B operand), Q pre-scaled by QSCALE in rope
  short8 bq[2][2];
#pragma unroll
  for (int g2 = 0; g2 < 2; g2++) {
    const u16* qp =
        qg + (size_t)((b << 11) + rb[g2] + r) * 1024 + (h << 6) + g * 8;
    bq[g2][0] = *(const short8*)qp;
    bq[g2][1] = *(const short8*)(qp + 32);
  }

  f32x4 accO[2][4];
  float m_r[2] = {-1e30f, -1e30f}, l_r[2] = {0.f, 0.f};
#pragma unroll
  for (int g2 = 0; g2 < 2; g2++)
#pragma unroll
    for (int md = 0; md < 4; md++) accO[g2][md] = (f32x4){0.f, 0.f, 0.f, 0.f};

  // stage K tile [kv][d] and V^T tile [d][kv], source-XOR-swizzled chunks
#define STAGE(JT, BUF)                                                        \
  do {                                                                        \
    int c = tid;                                                              \
    int row = c >> 3, cc = (c & 7) ^ (row & 7);                               \
    async16(kg + (size_t)((b << 11) + ((JT) << 6) + row) * 1024 + (h << 6) +  \
                cc * 8,                                                       \
            (char*)Ks[BUF] + c * 16);                                         \
    async16(vt + (size_t)((bh << 6) + row) * 2048 + ((JT) << 6) + cc * 8,     \
            (char*)Vs[BUF] + c * 16);                                         \
  } while (0)

  STAGE(0, 0);
  __syncthreads();

  for (int j = 0; j <= jend; ++j) {
    const int cur = j & 1;
    if (j < jend) STAGE(j + 1, cur ^ 1);
    const bool act0 = (j <= (rb[0] >> 6));
    const bool act1 = (j <= (rb[1] >> 6));
    if (act0 | act1) {
      const u16* Kb = Ks[cur];
      const u16* Vb = Vs[cur];
      // K fragments (A operand), shared by both groups
      short8 kf[4][2];
#pragma unroll
      for (int mk = 0; mk < 4; mk++) {
        kf[mk][0] = *(const short8*)(Kb + (mk * 16 + r) * 64 + ((g) ^ (r & 7)) * 8);
        kf[mk][1] = *(const short8*)(Kb + (mk * 16 + r) * 64 + ((4 + g) ^ (r & 7)) * 8);
      }
      // QK^T + softmax per active group
#pragma unroll
      for (int g2 = 0; g2 < 2; g2++) {
        if (!(g2 ? act1 : act0)) continue;
        f32x4 accS[4];
#pragma unroll
        for (int mk = 0; mk < 4; mk++) {
          f32x4 z = {0.f, 0.f, 0.f, 0.f};
          z = MFMA(kf[mk][0], bq[g2][0], z);
          z = MFMA(kf[mk][1], bq[g2][1], z);
          accS[mk] = z;
        }
        const int qrow = rb[g2] + r;
        if (j == (rb[g2] >> 6)) {  // boundary tile: causal mask (wave-uniform)
#pragma unroll
          for (int mk = 0; mk < 4; mk++)
#pragma unroll
            for (int i = 0; i < 4; i++)
              if ((j << 6) + mk * 16 + g * 4 + i > qrow) accS[mk][i] = -1e30f;
        }
        float pmax = accS[0][0];
#pragma unroll
        for (int mk = 0; mk < 4; mk++)
#pragma unroll
          for (int i = 0; i < 4; i++) pmax = fmaxf(pmax, accS[mk][i]);
        pmax = fmaxf(pmax, __shfl_xor(pmax, 16));
        pmax = fmaxf(pmax, __shfl_xor(pmax, 32));
        float mnew = m_r[g2];
        if (!__all(pmax <= mnew + 8.0f)) {  // T13 defer-max
          mnew = fmaxf(mnew, pmax);
          float sc = exp2hw(m_r[g2] - mnew);
          l_r[g2] *= sc;
#pragma unroll
          for (int md = 0; md < 4; md++) accO[g2][md] *= sc;
          m_r[g2] = mnew;
        }
        float rs = 0.f;
        u16* pw = Ps[wid * 2 + g2];
#pragma unroll
        for (int mk = 0; mk < 4; mk++) {
          float p0 = exp2hw(accS[mk][0] - mnew);
          float p1 = exp2hw(accS[mk][1] - mnew);
          float p2 = exp2hw(accS[mk][2] - mnew);
          float p3 = exp2hw(accS[mk][3] - mnew);
          rs += (p0 + p1) + (p2 + p3);
          u32 d0 = cvtpk(p0, p1), d1 = cvtpk(p2, p3);
          uint2 dd = {d0, d1};
          *(uint2*)((char*)pw + r * 128 +
                    (((mk * 2 + (g >> 1)) ^ (r & 7)) << 4) + ((g & 1) << 3)) = dd;
        }
        rs += __shfl_xor(rs, 16);
        rs += __shfl_xor(rs, 32);
        l_r[g2] += rs;
      }
      // V fragments (A operand), shared by both groups
      asm volatile("s_waitcnt lgkmcnt(0)" ::: "memory");
      short8 vf[4][2];
#pragma unroll
      for (int md = 0; md < 4; md++) {
        vf[md][0] = *(const short8*)(Vb + (md * 16 + r) * 64 + ((g) ^ (r & 7)) * 8);
        vf[md][1] = *(const short8*)(Vb + (md * 16 + r) * 64 + ((4 + g) ^ (r & 7)) * 8);
      }
#pragma unroll
      for (int g2 = 0; g2 < 2; g2++) {
        if (!(g2 ? act1 : act0)) continue;
        const u16* pw = Ps[wid * 2 + g2];
        short8 pb0 = *(const short8*)((const char*)pw + r * 128 + (((g) ^ (r & 7)) << 4));
        short8 pb1 = *(const short8*)((const char*)pw + r * 128 + (((4 + g) ^ (r & 7)) << 4));
#pragma unroll
        for (int md = 0; md < 4; md++) {
          accO[g2][md] = MFMA(vf[md][0], pb0, accO[g2][md]);
          accO[g2][md] = MFMA(vf[md][1], pb1, accO[g2][md]);
        }
      }
    }
    __syncthreads();
  }
#undef STAGE

  // epilogue: ab[b, s=q, h*64+d] = O^T / l
#pragma unroll
  for (int g2 = 0; g2 < 2; g2++) {
    float inv = 1.0f / l_r[g2];
#pragma unroll
    for (int md = 0; md < 4; md++) {
      u16x4 o;
#pragma unroll
      for (int i = 0; i < 4; i++) o[i] = f2bf(accO[g2][md][i] * inv);
      *(u16x4*)(ab + (size_t)((b << 11) + rb[g2] + r) * 1024 + (h << 6) +
                md * 16 + g * 4) = o;
    }
  }
}

// ---------- 5. output projection: out = attn * wo^T (f32 out) ----------
__global__ __launch_bounds__(256) void gemm_ao(const u16* __restrict__ ab,
                                               const u16* __restrict__ wob,
                                               float* __restrict__ out) {
  __shared__ u16 As[128 * 64], Bs[128 * 64];
  f32x4 acc[4][4];
  gemm_tile(ab, wob, 1024, blockIdx.y * 128, blockIdx.x * 128, As, Bs, acc);
  const int lane = threadIdx.x & 63, wid = threadIdx.x >> 6;
  const int wr = wid >> 1, wc = wid & 1, g = lane >> 4, r = lane & 15;
  const int rowB = blockIdx.y * 128 + wr * 64;
  const int colB = blockIdx.x * 128 + wc * 64;
#pragma unroll
  for (int m = 0; m < 4; m++)
#pragma unroll
    for (int n = 0; n < 4; n++)
#pragma unroll
      for (int i = 0; i < 4; i++)
        out[(size_t)(rowB + m * 16 + g * 4 + i) * 1024 + colB + n * 16 + r] =
            acc[m][n][i];
}

extern "C" void kernel_launch(void* const* d_in, const int* in_sizes, int n_in,
                              void* d_out, int out_size, void* d_ws,
                              size_t ws_size, hipStream_t stream) {
  const float* x = (const float*)d_in[0];
  const int* tp = (const int*)d_in[1];
  const float* wq = (const float*)d_in[2];
  const float* wk = (const float*)d_in[3];
  const float* wv = (const float*)d_in[4];
  const float* wo = (const float*)d_in[5];
  float* out = (float*)d_out;

  u16* ws = (u16*)d_ws;
  u16* xb = ws;                   // 4194304 (reused as f32 rope table later)
  u16* wqb = xb + 4194304;        // 1048576
  u16* wkb = wqb + 1048576;
  u16* wvb = wkb + 1048576;
  u16* wob = wvb + 1048576;
  u16* qb = wob + 1048576;        // 4194304
  u16* kb = qb + 4194304;
  u16* vtb = kb + 4194304;        // [b][h][d][s]
  u16* ab = vtb + 4194304;
  float* tab = (float*)ws;        // overlaps xb (dead after gemm_qkv)

  convert_kernel<<<4096, 256, 0, stream>>>(x, wq, wk, wv, wo, ws);
  gemm_qkv<<<dim3(8, 32, 3), 256, 0, stream>>>(xb, wqb, wkb, wvb, qb, kb, vtb);
  rope_table<<<512, 256, 0, stream>>>(tp, tab);
  rope_kernel<<<2048, 256, 0, stream>>>(qb, kb, tab);
  attn_kernel<<<256, 512, 0, stream>>>(qb, kb, vtb, ab);
  gemm_ao<<<dim3(8, 32), 256, 0, stream>>>(ab, wob, out);
}

// Round 4
// 147.135 us; speedup vs baseline: 2.2617x; 1.0208x over previous
//
#include <hip/hip_runtime.h>
#include <hip/hip_bf16.h>

typedef unsigned short u16;
typedef unsigned int u32;
typedef short short8 __attribute__((ext_vector_type(8)));
typedef u16 u16x8 __attribute__((ext_vector_type(8)));
typedef u16 u16x4 __attribute__((ext_vector_type(4)));
typedef float f32x4 __attribute__((ext_vector_type(4)));

#define MFMA(a, b, c) __builtin_amdgcn_mfma_f32_16x16x32_bf16((a), (b), (c), 0, 0, 0)

// log2(e)*0.125 folded into Q at projection time; softmax runs in exp2 domain.
#define QSCALE 0.18033688011112042f

// ---------- helpers ----------
__device__ __forceinline__ u16 f2bf(float f) {
  unsigned u = __float_as_uint(f);
  unsigned r = (u + 0x7fffu + ((u >> 16) & 1u)) >> 16;  // RNE
  return (u16)r;
}
__device__ __forceinline__ float bf2f(u16 h) {
  return __uint_as_float(((unsigned)h) << 16);
}
__device__ __forceinline__ float exp2hw(float x) {
  float r;
  asm("v_exp_f32 %0, %1" : "=v"(r) : "v"(x));
  return r;
}
__device__ __forceinline__ u32 cvtpk(float lo, float hi) {
  u32 d;
  asm("v_cvt_pk_bf16_f32 %0, %1, %2" : "=v"(d) : "v"(lo), "v"(hi));
  return d;
}
__device__ __forceinline__ void async16(const void* g, void* l) {
  __builtin_amdgcn_global_load_lds(
      (const __attribute__((address_space(1))) void*)g,
      (__attribute__((address_space(3))) void*)l, 16, 0, 0);
}

// ---------- 1. f32 -> bf16 convert (x, wq, wk, wv, wo) ----------
__global__ __launch_bounds__(256) void convert_kernel(
    const float* __restrict__ x, const float* __restrict__ wq,
    const float* __restrict__ wk, const float* __restrict__ wv,
    const float* __restrict__ wo, u16* __restrict__ ws) {
  int blk = blockIdx.x;
  const float* src; u16* dst;
  if (blk < 2048)      { src = x;  dst = ws; }
  else if (blk < 2560) { src = wq; dst = ws + 4194304;               blk -= 2048; }
  else if (blk < 3072) { src = wk; dst = ws + 4194304 + 1048576;     blk -= 2560; }
  else if (blk < 3584) { src = wv; dst = ws + 4194304 + 2 * 1048576; blk -= 3072; }
  else                 { src = wo; dst = ws + 4194304 + 3 * 1048576; blk -= 3584; }
  int idx = (blk * 256 + threadIdx.x) * 8;
  float4 v0 = *(const float4*)(src + idx);
  float4 v1 = *(const float4*)(src + idx + 4);
  u16x8 o;
  o[0] = f2bf(v0.x); o[1] = f2bf(v0.y); o[2] = f2bf(v0.z); o[3] = f2bf(v0.w);
  o[4] = f2bf(v1.x); o[5] = f2bf(v1.y); o[6] = f2bf(v1.z); o[7] = f2bf(v1.w);
  *(u16x8*)(dst + idx) = o;
}

// ---------- 2a. cos/sin table: tab[bs*64 + p*2 + {0,1}] = cos/sin(tp[bs]*freq_p)
__global__ __launch_bounds__(256) void rope_table(const int* __restrict__ tp,
                                                  float* __restrict__ tab) {
  int t = blockIdx.x * 256 + threadIdx.x;  // 131072
  int bs = t >> 5, p = t & 31;
  // freq = 10000^(-p/32) = exp2(-p * log2(10000)/32)
  float freq = exp2hw(-(float)p * 0.4152410118609203f);
  float ang = (float)tp[bs] * freq;
  float sn, cs;
  sincosf(ang, &sn, &cs);
  tab[bs * 64 + p * 2] = cs;
  tab[bs * 64 + p * 2 + 1] = sn;
}

// ---------- GEMM core: C[128x128] = A[128xK] * B[128xK]^T (NT, bf16, f32 acc)
// Prefetch double-buffered (stage kt+1 before computing kt, ONE barrier/step)
// + XOR-swizzled LDS (source-swizzled global_load_lds, swizzled ds_read_b128).
__device__ __forceinline__ void gemm_tile(const u16* __restrict__ A,
                                          const u16* __restrict__ Bm, int K,
                                          int rowBase, int colBase, u16* As,
                                          u16* Bs, f32x4 acc[4][4]) {
  const int tid = threadIdx.x;
  const int lane = tid & 63, wid = tid >> 6;
  const int wr = wid >> 1, wc = wid & 1;
  const int g = lane >> 4, r = lane & 15;

#pragma unroll
  for (int m = 0; m < 4; m++)
#pragma unroll
    for (int n = 0; n < 4; n++) acc[m][n] = (f32x4){0.f, 0.f, 0.f, 0.f};

#define GSTAGE(KT, BUF)                                                       \
  do {                                                                        \
    _Pragma("unroll") for (int i_ = 0; i_ < 4; ++i_) {                        \
      int c = i_ * 256 + tid;                                                 \
      int row = c >> 3, kc = (c & 7) ^ (row & 7);                             \
      async16(A + (size_t)(rowBase + row) * K + ((KT) << 6) + kc * 8,         \
              (char*)As + (BUF)*16384 + c * 16);                              \
    }                                                                         \
    _Pragma("unroll") for (int i_ = 0; i_ < 4; ++i_) {                        \
      int c = i_ * 256 + tid;                                                 \
      int row = c >> 3, kc = (c & 7) ^ (row & 7);                             \
      async16(Bm + (size_t)(colBase + row) * K + ((KT) << 6) + kc * 8,        \
              (char*)Bs + (BUF)*16384 + c * 16);                              \
    }                                                                         \
  } while (0)

  const int nkt = K >> 6;
  GSTAGE(0, 0);
  __syncthreads();
  for (int kt = 0; kt < nkt; ++kt) {
    const int cur = kt & 1;
    if (kt + 1 < nkt) GSTAGE(kt + 1, cur ^ 1);
    const u16* Ab = As + cur * 8192;
    const u16* Bb = Bs + cur * 8192;
#pragma unroll
    for (int ks = 0; ks < 2; ++ks) {
      short8 af[4], bfr[4];
#pragma unroll
      for (int m = 0; m < 4; m++) {
        int rr = wr * 64 + m * 16 + r;
        af[m] = *(const short8*)(Ab + rr * 64 + (((ks * 4 + g) ^ (rr & 7)) << 3));
      }
#pragma unroll
      for (int n = 0; n < 4; n++) {
        int rr = wc * 64 + n * 16 + r;
        bfr[n] = *(const short8*)(Bb + rr * 64 + (((ks * 4 + g) ^ (rr & 7)) << 3));
      }
#pragma unroll
      for (int m = 0; m < 4; m++)
#pragma unroll
        for (int n = 0; n < 4; n++)
          acc[m][n] = MFMA(af[m], bfr[n], acc[m][n]);
    }
    __syncthreads();  // drains vmcnt(0): prefetched buf ready; WAR-safe
  }
#undef GSTAGE
}

// ---------- 2b. fused QKV projection + RoPE epilogue (grid.z selects weight)
__global__ __launch_bounds__(256) void gemm_qkv(
    const u16* __restrict__ xb, const u16* __restrict__ wqb,
    const u16* __restrict__ wkb, const u16* __restrict__ wvb,
    const float* __restrict__ tab, u16* __restrict__ qb, u16* __restrict__ kb,
    u16* __restrict__ vt) {
  __shared__ u16 As[2][128 * 64], Bs[2][128 * 64];
  const int z = blockIdx.z;
  const u16* W = (z == 0) ? wqb : (z == 1) ? wkb : wvb;
  f32x4 acc[4][4];
  gemm_tile(xb, W, 1024, blockIdx.y * 128, blockIdx.x * 128, As[0], Bs[0], acc);

  const int lane = threadIdx.x & 63, wid = threadIdx.x >> 6;
  const int wr = wid >> 1, wc = wid & 1, g = lane >> 4, r = lane & 15;
  const int rowB = blockIdx.y * 128 + wr * 64;
  const int colB = blockIdx.x * 128 + wc * 64;
  if (z < 2) {
    // RoPE fused: pair (2p,2p+1) = adjacent cols = adjacent lanes (r, r^1).
    u16* dst = z ? kb : qb;
    const float qs = z ? 1.0f : QSCALE;
#pragma unroll
    for (int m = 0; m < 4; m++)
#pragma unroll
      for (int n = 0; n < 4; n++) {
        const int col = colB + n * 16 + r;
        const int p2 = (col >> 1) & 31;
        const bool odd = col & 1;
#pragma unroll
        for (int i = 0; i < 4; i++) {
          const int row = rowB + m * 16 + g * 4 + i;  // b*2048 + s
          float2 cssn = *(const float2*)(tab + row * 64 + p2 * 2);
          float v = acc[m][n][i];
          float part = __shfl_xor(v, 1);
          float res = odd ? (part * cssn.y + v * cssn.x)
                          : (v * cssn.x - part * cssn.y);
          dst[(size_t)row * 1024 + col] = f2bf(res * qs);
        }
      }
  } else {
#pragma unroll
    for (int m = 0; m < 4; m++)
#pragma unroll
      for (int n = 0; n < 4; n++)
#pragma unroll
        for (int i = 0; i < 4; i++) {
          int row = rowB + m * 16 + g * 4 + i;  // b*2048 + s
          int col = colB + n * 16 + r;          // h*64 + d
          int b = row >> 11, s = row & 2047;
          vt[(size_t)((b * 16 + (col >> 6)) * 64 + (col & 63)) * 2048 + s] =
              f2bf(acc[m][n][i]);
        }
  }
}

// ---------- 4. flash attention, causal-paired blocks ----------
// Block = (a, bh): q-tiles {a, 15-a} of 128 rows each. 8 waves; wave owns 16
// rows of each tile (grp 0 = lo, grp 1 = hi). Equal work per block (34
// grp-tiles). idx = a*32+bh puts same-bh blocks on one XCD (idx%8 = bh%8).
__global__ __launch_bounds__(512) void attn_kernel(const u16* __restrict__ qg,
                                                   const u16* __restrict__ kg,
                                                   const u16* __restrict__ vt,
                                                   u16* __restrict__ ab) {
  __shared__ u16 Ks[2][64 * 64];
  __shared__ u16 Vs[2][64 * 64];
  __shared__ u16 Ps[16][1024];  // [wid*2+grp][16 q x 64 kv]
  const int tid = threadIdx.x, wid = tid >> 6, lane = tid & 63;
  const int g = lane >> 4, r = lane & 15;
  const int a = blockIdx.x >> 5, bh = blockIdx.x & 31;
  const int b = bh >> 4, h = bh & 15;
  const int rb[2] = {(a << 7) + wid * 16, ((15 - a) << 7) + wid * 16};
  const int jend = 31 - 2 * a;

  // Q fragments per grp (B operand), Q pre-scaled by QSCALE
  short8 bq[2][2];
#pragma unroll
  for (int g2 = 0; g2 < 2; g2++) {
    const u16* qp =
        qg + (size_t)((b << 11) + rb[g2] + r) * 1024 + (h << 6) + g * 8;
    bq[g2][0] = *(const short8*)qp;
    bq[g2][1] = *(const short8*)(qp + 32);
  }

  f32x4 accO[2][4];
  float m_r[2] = {-1e30f, -1e30f}, l_r[2] = {0.f, 0.f};
#pragma unroll
  for (int g2 = 0; g2 < 2; g2++)
#pragma unroll
    for (int md = 0; md < 4; md++) accO[g2][md] = (f32x4){0.f, 0.f, 0.f, 0.f};

  // stage K tile [kv][d] and V^T tile [d][kv], source-XOR-swizzled chunks
#define STAGE(JT, BUF)                                                        \
  do {                                                                        \
    int c = tid;                                                              \
    int row = c >> 3, cc = (c & 7) ^ (row & 7);                               \
    async16(kg + (size_t)((b << 11) + ((JT) << 6) + row) * 1024 + (h << 6) +  \
                cc * 8,                                                       \
            (char*)Ks[BUF] + c * 16);                                         \
    async16(vt + (size_t)((bh << 6) + row) * 2048 + ((JT) << 6) + cc * 8,     \
            (char*)Vs[BUF] + c * 16);                                         \
  } while (0)

  STAGE(0, 0);
  __syncthreads();

  for (int j = 0; j <= jend; ++j) {
    const int cur = j & 1;
    if (j < jend) STAGE(j + 1, cur ^ 1);
    const bool act0 = (j <= (rb[0] >> 6));
    const bool act1 = (j <= (rb[1] >> 6));
    if (act0 | act1) {
      const u16* Kb = Ks[cur];
      const u16* Vb = Vs[cur];
      // K fragments (A operand), shared by both groups
      short8 kf[4][2];
#pragma unroll
      for (int mk = 0; mk < 4; mk++) {
        kf[mk][0] = *(const short8*)(Kb + (mk * 16 + r) * 64 + ((g) ^ (r & 7)) * 8);
        kf[mk][1] = *(const short8*)(Kb + (mk * 16 + r) * 64 + ((4 + g) ^ (r & 7)) * 8);
      }
      // QK^T + softmax per active group
#pragma unroll
      for (int g2 = 0; g2 < 2; g2++) {
        if (!(g2 ? act1 : act0)) continue;
        f32x4 accS[4];
#pragma unroll
        for (int mk = 0; mk < 4; mk++) {
          f32x4 z = {0.f, 0.f, 0.f, 0.f};
          z = MFMA(kf[mk][0], bq[g2][0], z);
          z = MFMA(kf[mk][1], bq[g2][1], z);
          accS[mk] = z;
        }
        const int qrow = rb[g2] + r;
        if (j == (rb[g2] >> 6)) {  // boundary tile: causal mask (wave-uniform)
#pragma unroll
          for (int mk = 0; mk < 4; mk++)
#pragma unroll
            for (int i = 0; i < 4; i++)
              if ((j << 6) + mk * 16 + g * 4 + i > qrow) accS[mk][i] = -1e30f;
        }
        float pmax = accS[0][0];
#pragma unroll
        for (int mk = 0; mk < 4; mk++)
#pragma unroll
          for (int i = 0; i < 4; i++) pmax = fmaxf(pmax, accS[mk][i]);
        pmax = fmaxf(pmax, __shfl_xor(pmax, 16));
        pmax = fmaxf(pmax, __shfl_xor(pmax, 32));
        float mnew = m_r[g2];
        if (!__all(pmax <= mnew + 8.0f)) {  // T13 defer-max
          mnew = fmaxf(mnew, pmax);
          float sc = exp2hw(m_r[g2] - mnew);
          l_r[g2] *= sc;
#pragma unroll
          for (int md = 0; md < 4; md++) accO[g2][md] *= sc;
          m_r[g2] = mnew;
        }
        float rs = 0.f;
        u16* pw = Ps[wid * 2 + g2];
#pragma unroll
        for (int mk = 0; mk < 4; mk++) {
          float p0 = exp2hw(accS[mk][0] - mnew);
          float p1 = exp2hw(accS[mk][1] - mnew);
          float p2 = exp2hw(accS[mk][2] - mnew);
          float p3 = exp2hw(accS[mk][3] - mnew);
          rs += (p0 + p1) + (p2 + p3);
          u32 d0 = cvtpk(p0, p1), d1 = cvtpk(p2, p3);
          uint2 dd = {d0, d1};
          *(uint2*)((char*)pw + r * 128 +
                    (((mk * 2 + (g >> 1)) ^ (r & 7)) << 4) + ((g & 1) << 3)) = dd;
        }
        rs += __shfl_xor(rs, 16);
        rs += __shfl_xor(rs, 32);
        l_r[g2] += rs;
      }
      // V fragments (A operand), shared by both groups
      asm volatile("s_waitcnt lgkmcnt(0)" ::: "memory");
      short8 vf[4][2];
#pragma unroll
      for (int md = 0; md < 4; md++) {
        vf[md][0] = *(const short8*)(Vb + (md * 16 + r) * 64 + ((g) ^ (r & 7)) * 8);
        vf[md][1] = *(const short8*)(Vb + (md * 16 + r) * 64 + ((4 + g) ^ (r & 7)) * 8);
      }
#pragma unroll
      for (int g2 = 0; g2 < 2; g2++) {
        if (!(g2 ? act1 : act0)) continue;
        const u16* pw = Ps[wid * 2 + g2];
        short8 pb0 = *(const short8*)((const char*)pw + r * 128 + (((g) ^ (r & 7)) << 4));
        short8 pb1 = *(const short8*)((const char*)pw + r * 128 + (((4 + g) ^ (r & 7)) << 4));
#pragma unroll
        for (int md = 0; md < 4; md++) {
          accO[g2][md] = MFMA(vf[md][0], pb0, accO[g2][md]);
          accO[g2][md] = MFMA(vf[md][1], pb1, accO[g2][md]);
        }
      }
    }
    __syncthreads();
  }
#undef STAGE

  // epilogue: ab[b, s=q, h*64+d] = O^T / l
#pragma unroll
  for (int g2 = 0; g2 < 2; g2++) {
    float inv = 1.0f / l_r[g2];
#pragma unroll
    for (int md = 0; md < 4; md++) {
      u16x4 o;
#pragma unroll
      for (int i = 0; i < 4; i++) o[i] = f2bf(accO[g2][md][i] * inv);
      *(u16x4*)(ab + (size_t)((b << 11) + rb[g2] + r) * 1024 + (h << 6) +
                md * 16 + g * 4) = o;
    }
  }
}

// ---------- 5. output projection: out = attn * wo^T (f32 out) ----------
__global__ __launch_bounds__(256) void gemm_ao(const u16* __restrict__ ab,
                                               const u16* __restrict__ wob,
                                               float* __restrict__ out) {
  __shared__ u16 As[2][128 * 64], Bs[2][128 * 64];
  f32x4 acc[4][4];
  gemm_tile(ab, wob, 1024, blockIdx.y * 128, blockIdx.x * 128, As[0], Bs[0], acc);
  const int lane = threadIdx.x & 63, wid = threadIdx.x >> 6;
  const int wr = wid >> 1, wc = wid & 1, g = lane >> 4, r = lane & 15;
  const int rowB = blockIdx.y * 128 + wr * 64;
  const int colB = blockIdx.x * 128 + wc * 64;
#pragma unroll
  for (int m = 0; m < 4; m++)
#pragma unroll
    for (int n = 0; n < 4; n++)
#pragma unroll
      for (int i = 0; i < 4; i++)
        out[(size_t)(rowB + m * 16 + g * 4 + i) * 1024 + colB + n * 16 + r] =
            acc[m][n][i];
}

extern "C" void kernel_launch(void* const* d_in, const int* in_sizes, int n_in,
                              void* d_out, int out_size, void* d_ws,
                              size_t ws_size, hipStream_t stream) {
  const float* x = (const float*)d_in[0];
  const int* tp = (const int*)d_in[1];
  const float* wq = (const float*)d_in[2];
  const float* wk = (const float*)d_in[3];
  const float* wv = (const float*)d_in[4];
  const float* wo = (const float*)d_in[5];
  float* out = (float*)d_out;

  u16* ws = (u16*)d_ws;
  u16* xb = ws;                   // 4194304
  u16* wqb = xb + 4194304;        // 1048576
  u16* wkb = wqb + 1048576;
  u16* wvb = wkb + 1048576;
  u16* wob = wvb + 1048576;
  u16* qb = wob + 1048576;        // 4194304
  u16* kb = qb + 4194304;
  u16* vtb = kb + 4194304;        // [b][h][d][s]
  u16* ab = vtb + 4194304;
  float* tab = (float*)ab;        // 1 MB, aliases ab (dead before attn writes)

  convert_kernel<<<4096, 256, 0, stream>>>(x, wq, wk, wv, wo, ws);
  rope_table<<<512, 256, 0, stream>>>(tp, tab);
  gemm_qkv<<<dim3(8, 32, 3), 256, 0, stream>>>(xb, wqb, wkb, wvb, tab, qb, kb,
                                               vtb);
  attn_kernel<<<256, 512, 0, stream>>>(qb, kb, vtb, ab);
  gemm_ao<<<dim3(8, 32), 256, 0, stream>>>(ab, wob, out);
}

// Round 5
// 131.156 us; speedup vs baseline: 2.5373x; 1.1218x over previous
//
#include <hip/hip_runtime.h>
#include <hip/hip_bf16.h>

typedef unsigned short u16;
typedef unsigned int u32;
typedef short short8 __attribute__((ext_vector_type(8)));
typedef u16 u16x8 __attribute__((ext_vector_type(8)));
typedef u16 u16x4 __attribute__((ext_vector_type(4)));
typedef float f32x4 __attribute__((ext_vector_type(4)));

#define MFMA(a, b, c) __builtin_amdgcn_mfma_f32_16x16x32_bf16((a), (b), (c), 0, 0, 0)

// log2(e)*0.125 folded into Q at projection time; softmax runs in exp2 domain.
#define QSCALE 0.18033688011112042f

// ---------- helpers ----------
__device__ __forceinline__ u16 f2bf(float f) {
  unsigned u = __float_as_uint(f);
  unsigned r = (u + 0x7fffu + ((u >> 16) & 1u)) >> 16;  // RNE
  return (u16)r;
}
__device__ __forceinline__ float bf2f(u16 h) {
  return __uint_as_float(((unsigned)h) << 16);
}
__device__ __forceinline__ float exp2hw(float x) {
  float r;
  asm("v_exp_f32 %0, %1" : "=v"(r) : "v"(x));
  return r;
}
__device__ __forceinline__ u32 cvtpk(float lo, float hi) {
  u32 d;
  asm("v_cvt_pk_bf16_f32 %0, %1, %2" : "=v"(d) : "v"(lo), "v"(hi));
  return d;
}
__device__ __forceinline__ void async16(const void* g, void* l) {
  __builtin_amdgcn_global_load_lds(
      (const __attribute__((address_space(1))) void*)g,
      (__attribute__((address_space(3))) void*)l, 16, 0, 0);
}
// counted waits (T4): keep prefetch loads in flight across barriers
#define WAITV(N) asm volatile("s_waitcnt vmcnt(" #N ")" ::: "memory")
#define WAITL0() asm volatile("s_waitcnt lgkmcnt(0)" ::: "memory")
#define BAR() __builtin_amdgcn_s_barrier()

// ---------- 1. f32 -> bf16 convert (x, wq, wk, wv, wo) ----------
__global__ __launch_bounds__(256) void convert_kernel(
    const float* __restrict__ x, const float* __restrict__ wq,
    const float* __restrict__ wk, const float* __restrict__ wv,
    const float* __restrict__ wo, u16* __restrict__ ws) {
  int blk = blockIdx.x;
  const float* src; u16* dst;
  if (blk < 2048)      { src = x;  dst = ws; }
  else if (blk < 2560) { src = wq; dst = ws + 4194304;               blk -= 2048; }
  else if (blk < 3072) { src = wk; dst = ws + 4194304 + 1048576;     blk -= 2560; }
  else if (blk < 3584) { src = wv; dst = ws + 4194304 + 2 * 1048576; blk -= 3072; }
  else                 { src = wo; dst = ws + 4194304 + 3 * 1048576; blk -= 3584; }
  int idx = (blk * 256 + threadIdx.x) * 8;
  float4 v0 = *(const float4*)(src + idx);
  float4 v1 = *(const float4*)(src + idx + 4);
  u16x8 o;
  o[0] = f2bf(v0.x); o[1] = f2bf(v0.y); o[2] = f2bf(v0.z); o[3] = f2bf(v0.w);
  o[4] = f2bf(v1.x); o[5] = f2bf(v1.y); o[6] = f2bf(v1.z); o[7] = f2bf(v1.w);
  *(u16x8*)(dst + idx) = o;
}

// ---------- 2a. cos/sin table: tab[bs*64 + p*2 + {0,1}] = cos/sin(tp[bs]*freq_p)
__global__ __launch_bounds__(256) void rope_table(const int* __restrict__ tp,
                                                  float* __restrict__ tab) {
  int t = blockIdx.x * 256 + threadIdx.x;  // 131072
  int bs = t >> 5, p = t & 31;
  float freq = exp2hw(-(float)p * 0.4152410118609203f);
  float ang = (float)tp[bs] * freq;
  float sn, cs;
  sincosf(ang, &sn, &cs);
  tab[bs * 64 + p * 2] = cs;
  tab[bs * 64 + p * 2 + 1] = sn;
}

// ---------- GEMM core: C[128x128] = A[128xK] * B[128xK]^T (NT, bf16, f32 acc)
// Double-buffered, XOR-swizzled LDS, COUNTED vmcnt (T4): prefetch survives
// both barriers; only the bottom barrier waits lgkmcnt (WAR on LDS).
__device__ __forceinline__ void gemm_tile(const u16* __restrict__ A,
                                          const u16* __restrict__ Bm, int K,
                                          int rowBase, int colBase, u16* As,
                                          u16* Bs, f32x4 acc[4][4]) {
  const int tid = threadIdx.x;
  const int lane = tid & 63, wid = tid >> 6;
  const int wr = wid >> 1, wc = wid & 1;
  const int g = lane >> 4, r = lane & 15;

#pragma unroll
  for (int m = 0; m < 4; m++)
#pragma unroll
    for (int n = 0; n < 4; n++) acc[m][n] = (f32x4){0.f, 0.f, 0.f, 0.f};

#define GSTAGE(KT, BUF)                                                       \
  do {                                                                        \
    _Pragma("unroll") for (int i_ = 0; i_ < 4; ++i_) {                        \
      int c = i_ * 256 + tid;                                                 \
      int row = c >> 3, kc = (c & 7) ^ (row & 7);                             \
      async16(A + (size_t)(rowBase + row) * K + ((KT) << 6) + kc * 8,         \
              (char*)As + (BUF)*16384 + c * 16);                              \
    }                                                                         \
    _Pragma("unroll") for (int i_ = 0; i_ < 4; ++i_) {                        \
      int c = i_ * 256 + tid;                                                 \
      int row = c >> 3, kc = (c & 7) ^ (row & 7);                             \
      async16(Bm + (size_t)(colBase + row) * K + ((KT) << 6) + kc * 8,        \
              (char*)Bs + (BUF)*16384 + c * 16);                              \
    }                                                                         \
  } while (0)

  const int nkt = K >> 6;
  GSTAGE(0, 0);
  for (int kt = 0; kt < nkt; ++kt) {
    const int cur = kt & 1;
    if (kt + 1 < nkt) {
      GSTAGE(kt + 1, cur ^ 1);  // 16 outstanding; wait oldest 8 (= tile kt)
      WAITV(8);
    } else {
      WAITV(0);                 // last tile: wait own loads
    }
    BAR();                      // all waves' tile-kt loads landed
    const u16* Ab = As + cur * 8192;
    const u16* Bb = Bs + cur * 8192;
#pragma unroll
    for (int ks = 0; ks < 2; ++ks) {
      short8 af[4], bfr[4];
#pragma unroll
      for (int m = 0; m < 4; m++) {
        int rr = wr * 64 + m * 16 + r;
        af[m] = *(const short8*)(Ab + rr * 64 + (((ks * 4 + g) ^ (rr & 7)) << 3));
      }
#pragma unroll
      for (int n = 0; n < 4; n++) {
        int rr = wc * 64 + n * 16 + r;
        bfr[n] = *(const short8*)(Bb + rr * 64 + (((ks * 4 + g) ^ (rr & 7)) << 3));
      }
#pragma unroll
      for (int m = 0; m < 4; m++)
#pragma unroll
        for (int n = 0; n < 4; n++)
          acc[m][n] = MFMA(af[m], bfr[n], acc[m][n]);
    }
    WAITL0();                   // own ds_reads done -> WAR-safe
    BAR();                      // NO vmcnt drain here: prefetch stays in flight
  }
#undef GSTAGE
}

// ---------- 2b. fused QKV projection + RoPE epilogue (grid.z selects weight)
__global__ __launch_bounds__(256) void gemm_qkv(
    const u16* __restrict__ xb, const u16* __restrict__ wqb,
    const u16* __restrict__ wkb, const u16* __restrict__ wvb,
    const float* __restrict__ tab, u16* __restrict__ qb, u16* __restrict__ kb,
    u16* __restrict__ vt) {
  __shared__ u16 As[2][128 * 64], Bs[2][128 * 64];
  const int z = blockIdx.z;
  const u16* W = (z == 0) ? wqb : (z == 1) ? wkb : wvb;
  f32x4 acc[4][4];
  gemm_tile(xb, W, 1024, blockIdx.y * 128, blockIdx.x * 128, As[0], Bs[0], acc);

  const int lane = threadIdx.x & 63, wid = threadIdx.x >> 6;
  const int wr = wid >> 1, wc = wid & 1, g = lane >> 4, r = lane & 15;
  const int rowB = blockIdx.y * 128 + wr * 64;
  const int colB = blockIdx.x * 128 + wc * 64;
  if (z < 2) {
    // RoPE fused: pair (2p,2p+1) = adjacent cols = adjacent lanes (r, r^1).
    u16* dst = z ? kb : qb;
    const float qs = z ? 1.0f : QSCALE;
#pragma unroll
    for (int m = 0; m < 4; m++)
#pragma unroll
      for (int n = 0; n < 4; n++) {
        const int col = colB + n * 16 + r;
        const int p2 = (col >> 1) & 31;
        const bool odd = col & 1;
#pragma unroll
        for (int i = 0; i < 4; i++) {
          const int row = rowB + m * 16 + g * 4 + i;  // b*2048 + s
          float2 cssn = *(const float2*)(tab + row * 64 + p2 * 2);
          float v = acc[m][n][i];
          float part = __shfl_xor(v, 1);
          float res = odd ? (part * cssn.y + v * cssn.x)
                          : (v * cssn.x - part * cssn.y);
          dst[(size_t)row * 1024 + col] = f2bf(res * qs);
        }
      }
  } else {
#pragma unroll
    for (int m = 0; m < 4; m++)
#pragma unroll
      for (int n = 0; n < 4; n++)
#pragma unroll
        for (int i = 0; i < 4; i++) {
          int row = rowB + m * 16 + g * 4 + i;  // b*2048 + s
          int col = colB + n * 16 + r;          // h*64 + d
          int b = row >> 11, s = row & 2047;
          vt[(size_t)((b * 16 + (col >> 6)) * 64 + (col & 63)) * 2048 + s] =
              f2bf(acc[m][n][i]);
        }
  }
}

// ---------- 4. flash attention, causal-paired blocks, counted vmcnt ----------
__global__ __launch_bounds__(512) void attn_kernel(const u16* __restrict__ qg,
                                                   const u16* __restrict__ kg,
                                                   const u16* __restrict__ vt,
                                                   u16* __restrict__ ab) {
  __shared__ u16 Ks[2][64 * 64];
  __shared__ u16 Vs[2][64 * 64];
  __shared__ u16 Ps[16][1024];  // [wid*2+grp][16 q x 64 kv]
  const int tid = threadIdx.x, wid = tid >> 6, lane = tid & 63;
  const int g = lane >> 4, r = lane & 15;
  const int a = blockIdx.x >> 5, bh = blockIdx.x & 31;
  const int b = bh >> 4, h = bh & 15;
  const int rb[2] = {(a << 7) + wid * 16, ((15 - a) << 7) + wid * 16};
  const int jend = 31 - 2 * a;

  // Q fragments per grp (B operand), Q pre-scaled by QSCALE
  short8 bq[2][2];
#pragma unroll
  for (int g2 = 0; g2 < 2; g2++) {
    const u16* qp =
        qg + (size_t)((b << 11) + rb[g2] + r) * 1024 + (h << 6) + g * 8;
    bq[g2][0] = *(const short8*)qp;
    bq[g2][1] = *(const short8*)(qp + 32);
  }

  f32x4 accO[2][4];
  float m_r[2] = {-1e30f, -1e30f}, l_r[2] = {0.f, 0.f};
#pragma unroll
  for (int g2 = 0; g2 < 2; g2++)
#pragma unroll
    for (int md = 0; md < 4; md++) accO[g2][md] = (f32x4){0.f, 0.f, 0.f, 0.f};

  // stage K tile [kv][d] and V^T tile [d][kv], source-XOR-swizzled chunks
#define STAGE(JT, BUF)                                                        \
  do {                                                                        \
    int c = tid;                                                              \
    int row = c >> 3, cc = (c & 7) ^ (row & 7);                               \
    async16(kg + (size_t)((b << 11) + ((JT) << 6) + row) * 1024 + (h << 6) +  \
                cc * 8,                                                       \
            (char*)Ks[BUF] + c * 16);                                         \
    async16(vt + (size_t)((bh << 6) + row) * 2048 + ((JT) << 6) + cc * 8,     \
            (char*)Vs[BUF] + c * 16);                                         \
  } while (0)

  STAGE(0, 0);

  for (int j = 0; j <= jend; ++j) {
    const int cur = j & 1;
    if (j < jend) {
      STAGE(j + 1, cur ^ 1);  // 4 outstanding; wait oldest 2 (= tile j)
      WAITV(2);
    } else {
      WAITV(0);
    }
    BAR();                    // tile j staged by all waves
    const bool act0 = (j <= (rb[0] >> 6));
    const bool act1 = (j <= (rb[1] >> 6));
    if (act0 | act1) {
      const u16* Kb = Ks[cur];
      const u16* Vb = Vs[cur];
      // K fragments (A operand), shared by both groups
      short8 kf[4][2];
#pragma unroll
      for (int mk = 0; mk < 4; mk++) {
        kf[mk][0] = *(const short8*)(Kb + (mk * 16 + r) * 64 + ((g) ^ (r & 7)) * 8);
        kf[mk][1] = *(const short8*)(Kb + (mk * 16 + r) * 64 + ((4 + g) ^ (r & 7)) * 8);
      }
      // QK^T + softmax per active group
#pragma unroll
      for (int g2 = 0; g2 < 2; g2++) {
        if (!(g2 ? act1 : act0)) continue;
        f32x4 accS[4];
#pragma unroll
        for (int mk = 0; mk < 4; mk++) {
          f32x4 z = {0.f, 0.f, 0.f, 0.f};
          z = MFMA(kf[mk][0], bq[g2][0], z);
          z = MFMA(kf[mk][1], bq[g2][1], z);
          accS[mk] = z;
        }
        const int qrow = rb[g2] + r;
        if (j == (rb[g2] >> 6)) {  // boundary tile: causal mask (wave-uniform)
#pragma unroll
          for (int mk = 0; mk < 4; mk++)
#pragma unroll
            for (int i = 0; i < 4; i++)
              if ((j << 6) + mk * 16 + g * 4 + i > qrow) accS[mk][i] = -1e30f;
        }
        float pmax = accS[0][0];
#pragma unroll
        for (int mk = 0; mk < 4; mk++)
#pragma unroll
          for (int i = 0; i < 4; i++) pmax = fmaxf(pmax, accS[mk][i]);
        pmax = fmaxf(pmax, __shfl_xor(pmax, 16));
        pmax = fmaxf(pmax, __shfl_xor(pmax, 32));
        float mnew = m_r[g2];
        if (!__all(pmax <= mnew + 8.0f)) {  // T13 defer-max
          mnew = fmaxf(mnew, pmax);
          float sc = exp2hw(m_r[g2] - mnew);
          l_r[g2] *= sc;
#pragma unroll
          for (int md = 0; md < 4; md++) accO[g2][md] *= sc;
          m_r[g2] = mnew;
        }
        float rs = 0.f;
        u16* pw = Ps[wid * 2 + g2];
#pragma unroll
        for (int mk = 0; mk < 4; mk++) {
          float p0 = exp2hw(accS[mk][0] - mnew);
          float p1 = exp2hw(accS[mk][1] - mnew);
          float p2 = exp2hw(accS[mk][2] - mnew);
          float p3 = exp2hw(accS[mk][3] - mnew);
          rs += (p0 + p1) + (p2 + p3);
          u32 d0 = cvtpk(p0, p1), d1 = cvtpk(p2, p3);
          uint2 dd = {d0, d1};
          *(uint2*)((char*)pw + r * 128 +
                    (((mk * 2 + (g >> 1)) ^ (r & 7)) << 4) + ((g & 1) << 3)) = dd;
        }
        rs += __shfl_xor(rs, 16);
        rs += __shfl_xor(rs, 32);
        l_r[g2] += rs;
      }
      // V fragments (A operand), shared by both groups
      WAITL0();
      short8 vf[4][2];
#pragma unroll
      for (int md = 0; md < 4; md++) {
        vf[md][0] = *(const short8*)(Vb + (md * 16 + r) * 64 + ((g) ^ (r & 7)) * 8);
        vf[md][1] = *(const short8*)(Vb + (md * 16 + r) * 64 + ((4 + g) ^ (r & 7)) * 8);
      }
#pragma unroll
      for (int g2 = 0; g2 < 2; g2++) {
        if (!(g2 ? act1 : act0)) continue;
        const u16* pw = Ps[wid * 2 + g2];
        short8 pb0 = *(const short8*)((const char*)pw + r * 128 + (((g) ^ (r & 7)) << 4));
        short8 pb1 = *(const short8*)((const char*)pw + r * 128 + (((4 + g) ^ (r & 7)) << 4));
#pragma unroll
        for (int md = 0; md < 4; md++) {
          accO[g2][md] = MFMA(vf[md][0], pb0, accO[g2][md]);
          accO[g2][md] = MFMA(vf[md][1], pb1, accO[g2][md]);
        }
      }
    }
    WAITL0();                  // own LDS reads done -> WAR-safe
    BAR();                     // no vmcnt drain: prefetch stays in flight
  }
#undef STAGE

  // epilogue: ab[b, s=q, h*64+d] = O^T / l
#pragma unroll
  for (int g2 = 0; g2 < 2; g2++) {
    float inv = 1.0f / l_r[g2];
#pragma unroll
    for (int md = 0; md < 4; md++) {
      u16x4 o;
#pragma unroll
      for (int i = 0; i < 4; i++) o[i] = f2bf(accO[g2][md][i] * inv);
      *(u16x4*)(ab + (size_t)((b << 11) + rb[g2] + r) * 1024 + (h << 6) +
                md * 16 + g * 4) = o;
    }
  }
}

// ---------- 5. output projection: out = attn * wo^T (f32 out) ----------
__global__ __launch_bounds__(256) void gemm_ao(const u16* __restrict__ ab,
                                               const u16* __restrict__ wob,
                                               float* __restrict__ out) {
  __shared__ u16 As[2][128 * 64], Bs[2][128 * 64];
  f32x4 acc[4][4];
  gemm_tile(ab, wob, 1024, blockIdx.y * 128, blockIdx.x * 128, As[0], Bs[0], acc);
  const int lane = threadIdx.x & 63, wid = threadIdx.x >> 6;
  const int wr = wid >> 1, wc = wid & 1, g = lane >> 4, r = lane & 15;
  const int rowB = blockIdx.y * 128 + wr * 64;
  const int colB = blockIdx.x * 128 + wc * 64;
#pragma unroll
  for (int m = 0; m < 4; m++)
#pragma unroll
    for (int n = 0; n < 4; n++)
#pragma unroll
      for (int i = 0; i < 4; i++)
        out[(size_t)(rowB + m * 16 + g * 4 + i) * 1024 + colB + n * 16 + r] =
            acc[m][n][i];
}

extern "C" void kernel_launch(void* const* d_in, const int* in_sizes, int n_in,
                              void* d_out, int out_size, void* d_ws,
                              size_t ws_size, hipStream_t stream) {
  const float* x = (const float*)d_in[0];
  const int* tp = (const int*)d_in[1];
  const float* wq = (const float*)d_in[2];
  const float* wk = (const float*)d_in[3];
  const float* wv = (const float*)d_in[4];
  const float* wo = (const float*)d_in[5];
  float* out = (float*)d_out;

  u16* ws = (u16*)d_ws;
  u16* xb = ws;                   // 4194304
  u16* wqb = xb + 4194304;        // 1048576
  u16* wkb = wqb + 1048576;
  u16* wvb = wkb + 1048576;
  u16* wob = wvb + 1048576;
  u16* qb = wob + 1048576;        // 4194304
  u16* kb = qb + 4194304;
  u16* vtb = kb + 4194304;        // [b][h][d][s]
  u16* ab = vtb + 4194304;
  float* tab = (float*)ab;        // 1 MB, aliases ab (dead before attn writes)

  convert_kernel<<<4096, 256, 0, stream>>>(x, wq, wk, wv, wo, ws);
  rope_table<<<512, 256, 0, stream>>>(tp, tab);
  gemm_qkv<<<dim3(8, 32, 3), 256, 0, stream>>>(xb, wqb, wkb, wvb, tab, qb, kb,
                                               vtb);
  attn_kernel<<<256, 512, 0, stream>>>(qb, kb, vtb, ab);
  gemm_ao<<<dim3(8, 32), 256, 0, stream>>>(ab, wob, out);
}

// Round 6
// 124.915 us; speedup vs baseline: 2.6640x; 1.0500x over previous
//
#include <hip/hip_runtime.h>
#include <hip/hip_bf16.h>

typedef unsigned short u16;
typedef unsigned int u32;
typedef short short8 __attribute__((ext_vector_type(8)));
typedef u16 u16x8 __attribute__((ext_vector_type(8)));
typedef u16 u16x4 __attribute__((ext_vector_type(4)));
typedef float f32x4 __attribute__((ext_vector_type(4)));

#define MFMA(a, b, c) __builtin_amdgcn_mfma_f32_16x16x32_bf16((a), (b), (c), 0, 0, 0)

// log2(e)*0.125 folded into Q at projection time; softmax runs in exp2 domain.
#define QSCALE 0.18033688011112042f

// ---------- helpers ----------
__device__ __forceinline__ u16 f2bf(float f) {
  unsigned u = __float_as_uint(f);
  unsigned r = (u + 0x7fffu + ((u >> 16) & 1u)) >> 16;  // RNE
  return (u16)r;
}
__device__ __forceinline__ float bf2f(u16 h) {
  return __uint_as_float(((unsigned)h) << 16);
}
__device__ __forceinline__ float exp2hw(float x) {
  float r;
  asm("v_exp_f32 %0, %1" : "=v"(r) : "v"(x));
  return r;
}
__device__ __forceinline__ u32 cvtpk(float lo, float hi) {
  u32 d;
  asm("v_cvt_pk_bf16_f32 %0, %1, %2" : "=v"(d) : "v"(lo), "v"(hi));
  return d;
}
__device__ __forceinline__ void async16(const void* g, void* l) {
  __builtin_amdgcn_global_load_lds(
      (const __attribute__((address_space(1))) void*)g,
      (__attribute__((address_space(3))) void*)l, 16, 0, 0);
}
// counted waits (T4): keep prefetch loads in flight across barriers
#define WAITV(N) asm volatile("s_waitcnt vmcnt(" #N ")" ::: "memory")
#define WAITL0() asm volatile("s_waitcnt lgkmcnt(0)" ::: "memory")
#define BAR() __builtin_amdgcn_s_barrier()
#define PRIO1 __builtin_amdgcn_s_setprio(1)
#define PRIO0 __builtin_amdgcn_s_setprio(0)

// ---------- 1. f32 -> bf16 convert (x, wq, wk, wv, wo) ----------
__global__ __launch_bounds__(256) void convert_kernel(
    const float* __restrict__ x, const float* __restrict__ wq,
    const float* __restrict__ wk, const float* __restrict__ wv,
    const float* __restrict__ wo, u16* __restrict__ ws) {
  int blk = blockIdx.x;
  const float* src; u16* dst;
  if (blk < 2048)      { src = x;  dst = ws; }
  else if (blk < 2560) { src = wq; dst = ws + 4194304;               blk -= 2048; }
  else if (blk < 3072) { src = wk; dst = ws + 4194304 + 1048576;     blk -= 2560; }
  else if (blk < 3584) { src = wv; dst = ws + 4194304 + 2 * 1048576; blk -= 3072; }
  else                 { src = wo; dst = ws + 4194304 + 3 * 1048576; blk -= 3584; }
  int idx = (blk * 256 + threadIdx.x) * 8;
  float4 v0 = *(const float4*)(src + idx);
  float4 v1 = *(const float4*)(src + idx + 4);
  u16x8 o;
  o[0] = f2bf(v0.x); o[1] = f2bf(v0.y); o[2] = f2bf(v0.z); o[3] = f2bf(v0.w);
  o[4] = f2bf(v1.x); o[5] = f2bf(v1.y); o[6] = f2bf(v1.z); o[7] = f2bf(v1.w);
  *(u16x8*)(dst + idx) = o;
}

// ---------- 2a. cos/sin table: tab[bs*64 + p*2 + {0,1}] = cos/sin(tp[bs]*freq_p)
__global__ __launch_bounds__(256) void rope_table(const int* __restrict__ tp,
                                                  float* __restrict__ tab) {
  int t = blockIdx.x * 256 + threadIdx.x;  // 131072
  int bs = t >> 5, p = t & 31;
  float freq = exp2hw(-(float)p * 0.4152410118609203f);
  float ang = (float)tp[bs] * freq;
  float sn, cs;
  sincosf(ang, &sn, &cs);
  tab[bs * 64 + p * 2] = cs;
  tab[bs * 64 + p * 2 + 1] = sn;
}

// ---------- 2b. QKV projection: 256x256 8-phase schedule (T3+T4+T5+T2) ----
// 8 waves (2M x 4N), per-wave 128x64 output, BK=64, 2 tile-buffers (128 KB).
// Per K-tile 4 phases = C-quadrants; B(t+1) staged at q0(t), A(t+2) at q3(t);
// single WAITV(4) per tile at q3 keeps the new A-pair in flight.
__global__ __launch_bounds__(512, 2) void gemm_qkv256(
    const u16* __restrict__ xb, const u16* __restrict__ wqb,
    const u16* __restrict__ wkb, const u16* __restrict__ wvb,
    const float* __restrict__ tab, u16* __restrict__ qb, u16* __restrict__ kb,
    u16* __restrict__ vt) {
  __shared__ u16 As[2][2][8192];  // [tile-buf][half: rows 0-127 / 128-255][128x64]
  __shared__ u16 Bs[2][2][8192];
  const int tid = threadIdx.x, lane = tid & 63, wid = tid >> 6;
  const int wm = wid >> 2, wn = wid & 3;
  const int g = lane >> 4, r = lane & 15;
  const int z = blockIdx.z;
  const u16* Ag = xb;
  const u16* Bg = (z == 0) ? wqb : (z == 1) ? wkb : wvb;
  const int rowBase = blockIdx.y << 8, colBase = blockIdx.x << 8;

  // staging geometry: 1024 chunks of 16B per half-tile, 2 per thread,
  // inverse-swizzled source so LDS stays linear (G21)
  const int c0 = tid, c1 = tid + 512;
  const int sr0 = c0 >> 3, sk0 = ((c0 & 7) ^ (sr0 & 7)) * 8;
  const int sr1 = c1 >> 3, sk1 = ((c1 & 7) ^ (sr1 & 7)) * 8;

#define STG_A(BUF, H, T)                                                      \
  do {                                                                        \
    async16(Ag + (size_t)(rowBase + (H)*128 + sr0) * 1024 + (T)*64 + sk0,     \
            (char*)As[BUF][H] + c0 * 16);                                     \
    async16(Ag + (size_t)(rowBase + (H)*128 + sr1) * 1024 + (T)*64 + sk1,     \
            (char*)As[BUF][H] + c1 * 16);                                     \
  } while (0)
#define STG_B(BUF, H, T)                                                      \
  do {                                                                        \
    async16(Bg + (size_t)(colBase + (H)*128 + sr0) * 1024 + (T)*64 + sk0,     \
            (char*)Bs[BUF][H] + c0 * 16);                                     \
    async16(Bg + (size_t)(colBase + (H)*128 + sr1) * 1024 + (T)*64 + sk1,     \
            (char*)Bs[BUF][H] + c1 * 16);                                     \
  } while (0)

  f32x4 acc[8][4];
#pragma unroll
  for (int m = 0; m < 8; m++)
#pragma unroll
    for (int n = 0; n < 4; n++) acc[m][n] = (f32x4){0.f, 0.f, 0.f, 0.f};
  short8 af[4][2], bfr[2][2];

#define RD_A(CUR, MH)                                                         \
  do {                                                                        \
    _Pragma("unroll") for (int mi = 0; mi < 4; mi++) {                        \
      int ra = (MH)*64 + mi * 16 + r;                                         \
      const u16* p = As[CUR][wm] + ra * 64;                                   \
      int sw = (ra & 7) << 3;                                                 \
      af[mi][0] = *(const short8*)(p + ((g << 3) ^ sw));                      \
      af[mi][1] = *(const short8*)(p + (((4 + g) << 3) ^ sw));                \
    }                                                                         \
  } while (0)
#define RD_B(CUR, NP)                                                         \
  do {                                                                        \
    _Pragma("unroll") for (int ni = 0; ni < 2; ni++) {                        \
      int cb = wn * 64 + ((NP)*2 + ni) * 16 + r;                              \
      const u16* p = Bs[CUR][cb >> 7] + (cb & 127) * 64;                      \
      int sw = (cb & 7) << 3;                                                 \
      bfr[ni][0] = *(const short8*)(p + ((g << 3) ^ sw));                     \
      bfr[ni][1] = *(const short8*)(p + (((4 + g) << 3) ^ sw));               \
    }                                                                         \
  } while (0)
#define MM16(MH, NP)                                                          \
  do {                                                                        \
    _Pragma("unroll") for (int mi = 0; mi < 4; mi++)                          \
        _Pragma("unroll") for (int ni = 0; ni < 2; ni++) {                    \
      acc[(MH)*4 + mi][(NP)*2 + ni] =                                         \
          MFMA(af[mi][0], bfr[ni][0], acc[(MH)*4 + mi][(NP)*2 + ni]);         \
      acc[(MH)*4 + mi][(NP)*2 + ni] =                                         \
          MFMA(af[mi][1], bfr[ni][1], acc[(MH)*4 + mi][(NP)*2 + ni]);         \
    }                                                                         \
  } while (0)

  // prologue: tile0 (A+B) + A(1); leave A(1) in flight
  STG_A(0, 0, 0); STG_A(0, 1, 0); STG_B(0, 0, 0); STG_B(0, 1, 0);
  STG_A(1, 0, 1); STG_A(1, 1, 1);
  WAITV(4);
  BAR();

  for (int t = 0; t < 16; ++t) {
    const int cur = t & 1, nxt = cur ^ 1;
    // q0: quadrant (m0-3, n0-1); stage B(t+1)
    RD_A(cur, 0); RD_B(cur, 0);
    if (t < 15) { STG_B(nxt, 0, t + 1); STG_B(nxt, 1, t + 1); }
    BAR(); WAITL0();
    PRIO1; MM16(0, 0); PRIO0; BAR();
    // q1: (m0-3, n2-3), reuse af
    RD_B(cur, 1);
    BAR(); WAITL0();
    PRIO1; MM16(0, 1); PRIO0; BAR();
    // q2: (m4-7, n2-3), reuse bfr
    RD_A(cur, 1);
    BAR(); WAITL0();
    PRIO1; MM16(1, 1); PRIO0; BAR();
    // q3: (m4-7, n0-1); stage A(t+2) into just-freed A slot; counted wait
    RD_B(cur, 0);
    if (t < 14) {
      STG_A(cur, 0, t + 2); STG_A(cur, 1, t + 2);
      WAITV(4);  // A(t+1), B(t+1) landed; A(t+2) stays in flight
    } else {
      WAITV(0);
    }
    BAR(); WAITL0();
    PRIO1; MM16(1, 0); PRIO0; BAR();
  }
#undef STG_A
#undef STG_B
#undef RD_A
#undef RD_B
#undef MM16

  // epilogue
  if (z < 2) {
    // RoPE fused: pair (2p,2p+1) = adjacent cols = adjacent lanes (r, r^1)
    u16* dst = z ? kb : qb;
    const float qs = z ? 1.0f : QSCALE;
#pragma unroll
    for (int m = 0; m < 8; m++)
#pragma unroll
      for (int n = 0; n < 4; n++) {
        const int col = colBase + wn * 64 + n * 16 + r;
        const int p2 = (col >> 1) & 31;
        const bool odd = col & 1;
#pragma unroll
        for (int i = 0; i < 4; i++) {
          const int row = rowBase + wm * 128 + m * 16 + g * 4 + i;  // b*2048+s
          float2 cssn = *(const float2*)(tab + row * 64 + p2 * 2);
          float v = acc[m][n][i];
          float part = __shfl_xor(v, 1);
          float res = odd ? (part * cssn.y + v * cssn.x)
                          : (v * cssn.x - part * cssn.y);
          dst[(size_t)row * 1024 + col] = f2bf(res * qs);
        }
      }
  } else {
#pragma unroll
    for (int m = 0; m < 8; m++)
#pragma unroll
      for (int n = 0; n < 4; n++)
#pragma unroll
        for (int i = 0; i < 4; i++) {
          int row = rowBase + wm * 128 + m * 16 + g * 4 + i;  // b*2048 + s
          int col = colBase + wn * 64 + n * 16 + r;           // h*64 + d
          int b = row >> 11, s = row & 2047;
          vt[(size_t)((b * 16 + (col >> 6)) * 64 + (col & 63)) * 2048 + s] =
              f2bf(acc[m][n][i]);
        }
  }
}

// ---------- GEMM core (128x128, counted vmcnt) — used by gemm_ao ----------
__device__ __forceinline__ void gemm_tile(const u16* __restrict__ A,
                                          const u16* __restrict__ Bm, int K,
                                          int rowBase, int colBase, u16* As,
                                          u16* Bs, f32x4 acc[4][4]) {
  const int tid = threadIdx.x;
  const int lane = tid & 63, wid = tid >> 6;
  const int wr = wid >> 1, wc = wid & 1;
  const int g = lane >> 4, r = lane & 15;

#pragma unroll
  for (int m = 0; m < 4; m++)
#pragma unroll
    for (int n = 0; n < 4; n++) acc[m][n] = (f32x4){0.f, 0.f, 0.f, 0.f};

#define GSTAGE(KT, BUF)                                                       \
  do {                                                                        \
    _Pragma("unroll") for (int i_ = 0; i_ < 4; ++i_) {                        \
      int c = i_ * 256 + tid;                                                 \
      int row = c >> 3, kc = (c & 7) ^ (row & 7);                             \
      async16(A + (size_t)(rowBase + row) * K + ((KT) << 6) + kc * 8,         \
              (char*)As + (BUF)*16384 + c * 16);                              \
    }                                                                         \
    _Pragma("unroll") for (int i_ = 0; i_ < 4; ++i_) {                        \
      int c = i_ * 256 + tid;                                                 \
      int row = c >> 3, kc = (c & 7) ^ (row & 7);                             \
      async16(Bm + (size_t)(colBase + row) * K + ((KT) << 6) + kc * 8,        \
              (char*)Bs + (BUF)*16384 + c * 16);                              \
    }                                                                         \
  } while (0)

  const int nkt = K >> 6;
  GSTAGE(0, 0);
  for (int kt = 0; kt < nkt; ++kt) {
    const int cur = kt & 1;
    if (kt + 1 < nkt) {
      GSTAGE(kt + 1, cur ^ 1);
      WAITV(8);
    } else {
      WAITV(0);
    }
    BAR();
    const u16* Ab = As + cur * 8192;
    const u16* Bb = Bs + cur * 8192;
#pragma unroll
    for (int ks = 0; ks < 2; ++ks) {
      short8 af[4], bfr[4];
#pragma unroll
      for (int m = 0; m < 4; m++) {
        int rr = wr * 64 + m * 16 + r;
        af[m] = *(const short8*)(Ab + rr * 64 + (((ks * 4 + g) ^ (rr & 7)) << 3));
      }
#pragma unroll
      for (int n = 0; n < 4; n++) {
        int rr = wc * 64 + n * 16 + r;
        bfr[n] = *(const short8*)(Bb + rr * 64 + (((ks * 4 + g) ^ (rr & 7)) << 3));
      }
#pragma unroll
      for (int m = 0; m < 4; m++)
#pragma unroll
        for (int n = 0; n < 4; n++)
          acc[m][n] = MFMA(af[m], bfr[n], acc[m][n]);
    }
    WAITL0();
    BAR();
  }
#undef GSTAGE
}

// ---------- 4. flash attention, causal-paired blocks, counted vmcnt ----------
__global__ __launch_bounds__(512) void attn_kernel(const u16* __restrict__ qg,
                                                   const u16* __restrict__ kg,
                                                   const u16* __restrict__ vt,
                                                   u16* __restrict__ ab) {
  __shared__ u16 Ks[2][64 * 64];
  __shared__ u16 Vs[2][64 * 64];
  __shared__ u16 Ps[16][1024];  // [wid*2+grp][16 q x 64 kv]
  const int tid = threadIdx.x, wid = tid >> 6, lane = tid & 63;
  const int g = lane >> 4, r = lane & 15;
  const int a = blockIdx.x >> 5, bh = blockIdx.x & 31;
  const int b = bh >> 4, h = bh & 15;
  const int rb[2] = {(a << 7) + wid * 16, ((15 - a) << 7) + wid * 16};
  const int jend = 31 - 2 * a;

  short8 bq[2][2];
#pragma unroll
  for (int g2 = 0; g2 < 2; g2++) {
    const u16* qp =
        qg + (size_t)((b << 11) + rb[g2] + r) * 1024 + (h << 6) + g * 8;
    bq[g2][0] = *(const short8*)qp;
    bq[g2][1] = *(const short8*)(qp + 32);
  }

  f32x4 accO[2][4];
  float m_r[2] = {-1e30f, -1e30f}, l_r[2] = {0.f, 0.f};
#pragma unroll
  for (int g2 = 0; g2 < 2; g2++)
#pragma unroll
    for (int md = 0; md < 4; md++) accO[g2][md] = (f32x4){0.f, 0.f, 0.f, 0.f};

#define STAGE(JT, BUF)                                                        \
  do {                                                                        \
    int c = tid;                                                              \
    int row = c >> 3, cc = (c & 7) ^ (row & 7);                               \
    async16(kg + (size_t)((b << 11) + ((JT) << 6) + row) * 1024 + (h << 6) +  \
                cc * 8,                                                       \
            (char*)Ks[BUF] + c * 16);                                         \
    async16(vt + (size_t)((bh << 6) + row) * 2048 + ((JT) << 6) + cc * 8,     \
            (char*)Vs[BUF] + c * 16);                                         \
  } while (0)

  STAGE(0, 0);

  for (int j = 0; j <= jend; ++j) {
    const int cur = j & 1;
    if (j < jend) {
      STAGE(j + 1, cur ^ 1);
      WAITV(2);
    } else {
      WAITV(0);
    }
    BAR();
    const bool act0 = (j <= (rb[0] >> 6));
    const bool act1 = (j <= (rb[1] >> 6));
    if (act0 | act1) {
      const u16* Kb = Ks[cur];
      const u16* Vb = Vs[cur];
      short8 kf[4][2];
#pragma unroll
      for (int mk = 0; mk < 4; mk++) {
        kf[mk][0] = *(const short8*)(Kb + (mk * 16 + r) * 64 + ((g) ^ (r & 7)) * 8);
        kf[mk][1] = *(const short8*)(Kb + (mk * 16 + r) * 64 + ((4 + g) ^ (r & 7)) * 8);
      }
#pragma unroll
      for (int g2 = 0; g2 < 2; g2++) {
        if (!(g2 ? act1 : act0)) continue;
        f32x4 accS[4];
#pragma unroll
        for (int mk = 0; mk < 4; mk++) {
          f32x4 z = {0.f, 0.f, 0.f, 0.f};
          z = MFMA(kf[mk][0], bq[g2][0], z);
          z = MFMA(kf[mk][1], bq[g2][1], z);
          accS[mk] = z;
        }
        const int qrow = rb[g2] + r;
        if (j == (rb[g2] >> 6)) {
#pragma unroll
          for (int mk = 0; mk < 4; mk++)
#pragma unroll
            for (int i = 0; i < 4; i++)
              if ((j << 6) + mk * 16 + g * 4 + i > qrow) accS[mk][i] = -1e30f;
        }
        float pmax = accS[0][0];
#pragma unroll
        for (int mk = 0; mk < 4; mk++)
#pragma unroll
          for (int i = 0; i < 4; i++) pmax = fmaxf(pmax, accS[mk][i]);
        pmax = fmaxf(pmax, __shfl_xor(pmax, 16));
        pmax = fmaxf(pmax, __shfl_xor(pmax, 32));
        float mnew = m_r[g2];
        if (!__all(pmax <= mnew + 8.0f)) {  // T13 defer-max
          mnew = fmaxf(mnew, pmax);
          float sc = exp2hw(m_r[g2] - mnew);
          l_r[g2] *= sc;
#pragma unroll
          for (int md = 0; md < 4; md++) accO[g2][md] *= sc;
          m_r[g2] = mnew;
        }
        float rs = 0.f;
        u16* pw = Ps[wid * 2 + g2];
#pragma unroll
        for (int mk = 0; mk < 4; mk++) {
          float p0 = exp2hw(accS[mk][0] - mnew);
          float p1 = exp2hw(accS[mk][1] - mnew);
          float p2 = exp2hw(accS[mk][2] - mnew);
          float p3 = exp2hw(accS[mk][3] - mnew);
          rs += (p0 + p1) + (p2 + p3);
          u32 d0 = cvtpk(p0, p1), d1 = cvtpk(p2, p3);
          uint2 dd = {d0, d1};
          *(uint2*)((char*)pw + r * 128 +
                    (((mk * 2 + (g >> 1)) ^ (r & 7)) << 4) + ((g & 1) << 3)) = dd;
        }
        rs += __shfl_xor(rs, 16);
        rs += __shfl_xor(rs, 32);
        l_r[g2] += rs;
      }
      WAITL0();
      short8 vf[4][2];
#pragma unroll
      for (int md = 0; md < 4; md++) {
        vf[md][0] = *(const short8*)(Vb + (md * 16 + r) * 64 + ((g) ^ (r & 7)) * 8);
        vf[md][1] = *(const short8*)(Vb + (md * 16 + r) * 64 + ((4 + g) ^ (r & 7)) * 8);
      }
#pragma unroll
      for (int g2 = 0; g2 < 2; g2++) {
        if (!(g2 ? act1 : act0)) continue;
        const u16* pw = Ps[wid * 2 + g2];
        short8 pb0 = *(const short8*)((const char*)pw + r * 128 + (((g) ^ (r & 7)) << 4));
        short8 pb1 = *(const short8*)((const char*)pw + r * 128 + (((4 + g) ^ (r & 7)) << 4));
#pragma unroll
        for (int md = 0; md < 4; md++) {
          accO[g2][md] = MFMA(vf[md][0], pb0, accO[g2][md]);
          accO[g2][md] = MFMA(vf[md][1], pb1, accO[g2][md]);
        }
      }
    }
    WAITL0();
    BAR();
  }
#undef STAGE

#pragma unroll
  for (int g2 = 0; g2 < 2; g2++) {
    float inv = 1.0f / l_r[g2];
#pragma unroll
    for (int md = 0; md < 4; md++) {
      u16x4 o;
#pragma unroll
      for (int i = 0; i < 4; i++) o[i] = f2bf(accO[g2][md][i] * inv);
      *(u16x4*)(ab + (size_t)((b << 11) + rb[g2] + r) * 1024 + (h << 6) +
                md * 16 + g * 4) = o;
    }
  }
}

// ---------- 5. output projection: out = attn * wo^T (f32 out) ----------
__global__ __launch_bounds__(256) void gemm_ao(const u16* __restrict__ ab,
                                               const u16* __restrict__ wob,
                                               float* __restrict__ out) {
  __shared__ u16 As[2][128 * 64], Bs[2][128 * 64];
  f32x4 acc[4][4];
  gemm_tile(ab, wob, 1024, blockIdx.y * 128, blockIdx.x * 128, As[0], Bs[0], acc);
  const int lane = threadIdx.x & 63, wid = threadIdx.x >> 6;
  const int wr = wid >> 1, wc = wid & 1, g = lane >> 4, r = lane & 15;
  const int rowB = blockIdx.y * 128 + wr * 64;
  const int colB = blockIdx.x * 128 + wc * 64;
#pragma unroll
  for (int m = 0; m < 4; m++)
#pragma unroll
    for (int n = 0; n < 4; n++)
#pragma unroll
      for (int i = 0; i < 4; i++)
        out[(size_t)(rowB + m * 16 + g * 4 + i) * 1024 + colB + n * 16 + r] =
            acc[m][n][i];
}

extern "C" void kernel_launch(void* const* d_in, const int* in_sizes, int n_in,
                              void* d_out, int out_size, void* d_ws,
                              size_t ws_size, hipStream_t stream) {
  const float* x = (const float*)d_in[0];
  const int* tp = (const int*)d_in[1];
  const float* wq = (const float*)d_in[2];
  const float* wk = (const float*)d_in[3];
  const float* wv = (const float*)d_in[4];
  const float* wo = (const float*)d_in[5];
  float* out = (float*)d_out;

  u16* ws = (u16*)d_ws;
  u16* xb = ws;                   // 4194304
  u16* wqb = xb + 4194304;        // 1048576
  u16* wkb = wqb + 1048576;
  u16* wvb = wkb + 1048576;
  u16* wob = wvb + 1048576;
  u16* qb = wob + 1048576;        // 4194304
  u16* kb = qb + 4194304;
  u16* vtb = kb + 4194304;        // [b][h][d][s]
  u16* ab = vtb + 4194304;
  float* tab = (float*)ab;        // 1 MB, aliases ab (dead before attn writes)

  convert_kernel<<<4096, 256, 0, stream>>>(x, wq, wk, wv, wo, ws);
  rope_table<<<512, 256, 0, stream>>>(tp, tab);
  gemm_qkv256<<<dim3(4, 16, 3), 512, 0, stream>>>(xb, wqb, wkb, wvb, tab, qb,
                                                  kb, vtb);
  attn_kernel<<<256, 512, 0, stream>>>(qb, kb, vtb, ab);
  gemm_ao<<<dim3(8, 32), 256, 0, stream>>>(ab, wob, out);
}

// Round 7
// 124.785 us; speedup vs baseline: 2.6668x; 1.0010x over previous
//
#include <hip/hip_runtime.h>
#include <hip/hip_bf16.h>

typedef unsigned short u16;
typedef unsigned int u32;
typedef short short8 __attribute__((ext_vector_type(8)));
typedef u16 u16x8 __attribute__((ext_vector_type(8)));
typedef u16 u16x4 __attribute__((ext_vector_type(4)));
typedef float f32x4 __attribute__((ext_vector_type(4)));

#define MFMA(a, b, c) __builtin_amdgcn_mfma_f32_16x16x32_bf16((a), (b), (c), 0, 0, 0)

// log2(e)*0.125 folded into Q at projection time; softmax runs in exp2 domain.
#define QSCALE 0.18033688011112042f

// ---------- helpers ----------
__device__ __forceinline__ u16 f2bf(float f) {
  unsigned u = __float_as_uint(f);
  unsigned r = (u + 0x7fffu + ((u >> 16) & 1u)) >> 16;  // RNE
  return (u16)r;
}
__device__ __forceinline__ float bf2f(u16 h) {
  return __uint_as_float(((unsigned)h) << 16);
}
__device__ __forceinline__ float exp2hw(float x) {
  float r;
  asm("v_exp_f32 %0, %1" : "=v"(r) : "v"(x));
  return r;
}
__device__ __forceinline__ u32 cvtpk(float lo, float hi) {
  u32 d;
  asm("v_cvt_pk_bf16_f32 %0, %1, %2" : "=v"(d) : "v"(lo), "v"(hi));
  return d;
}
__device__ __forceinline__ void async16(const void* g, void* l) {
  __builtin_amdgcn_global_load_lds(
      (const __attribute__((address_space(1))) void*)g,
      (__attribute__((address_space(3))) void*)l, 16, 0, 0);
}
// counted waits (T4): keep prefetch loads in flight across barriers
#define WAITV(N) asm volatile("s_waitcnt vmcnt(" #N ")" ::: "memory")
#define WAITL0() asm volatile("s_waitcnt lgkmcnt(0)" ::: "memory")
#define BAR() __builtin_amdgcn_s_barrier()
#define PRIO1 __builtin_amdgcn_s_setprio(1)
#define PRIO0 __builtin_amdgcn_s_setprio(0)

// ---------- 1. f32 -> bf16 convert (x, wq, wk, wv, wo) ----------
__global__ __launch_bounds__(256) void convert_kernel(
    const float* __restrict__ x, const float* __restrict__ wq,
    const float* __restrict__ wk, const float* __restrict__ wv,
    const float* __restrict__ wo, u16* __restrict__ ws) {
  int blk = blockIdx.x;
  const float* src; u16* dst;
  if (blk < 2048)      { src = x;  dst = ws; }
  else if (blk < 2560) { src = wq; dst = ws + 4194304;               blk -= 2048; }
  else if (blk < 3072) { src = wk; dst = ws + 4194304 + 1048576;     blk -= 2560; }
  else if (blk < 3584) { src = wv; dst = ws + 4194304 + 2 * 1048576; blk -= 3072; }
  else                 { src = wo; dst = ws + 4194304 + 3 * 1048576; blk -= 3584; }
  int idx = (blk * 256 + threadIdx.x) * 8;
  float4 v0 = *(const float4*)(src + idx);
  float4 v1 = *(const float4*)(src + idx + 4);
  u16x8 o;
  o[0] = f2bf(v0.x); o[1] = f2bf(v0.y); o[2] = f2bf(v0.z); o[3] = f2bf(v0.w);
  o[4] = f2bf(v1.x); o[5] = f2bf(v1.y); o[6] = f2bf(v1.z); o[7] = f2bf(v1.w);
  *(u16x8*)(dst + idx) = o;
}

// ---------- 2a. cos/sin table: tab[bs*64 + p*2 + {0,1}] = cos/sin(tp[bs]*freq_p)
__global__ __launch_bounds__(256) void rope_table(const int* __restrict__ tp,
                                                  float* __restrict__ tab) {
  int t = blockIdx.x * 256 + threadIdx.x;  // 131072
  int bs = t >> 5, p = t & 31;
  float freq = exp2hw(-(float)p * 0.4152410118609203f);
  float ang = (float)tp[bs] * freq;
  float sn, cs;
  sincosf(ang, &sn, &cs);
  tab[bs * 64 + p * 2] = cs;
  tab[bs * 64 + p * 2 + 1] = sn;
}

// ---------- 2b. QKV projection: 256x256 8-phase schedule (T3+T4+T5+T2) ----
__global__ __launch_bounds__(512, 2) void gemm_qkv256(
    const u16* __restrict__ xb, const u16* __restrict__ wqb,
    const u16* __restrict__ wkb, const u16* __restrict__ wvb,
    const float* __restrict__ tab, u16* __restrict__ qb, u16* __restrict__ kb,
    u16* __restrict__ vt) {
  __shared__ u16 As[2][2][8192];  // [tile-buf][half: rows 0-127 / 128-255][128x64]
  __shared__ u16 Bs[2][2][8192];
  const int tid = threadIdx.x, lane = tid & 63, wid = tid >> 6;
  const int wm = wid >> 2, wn = wid & 3;
  const int g = lane >> 4, r = lane & 15;
  const int z = blockIdx.z;
  const u16* Ag = xb;
  const u16* Bg = (z == 0) ? wqb : (z == 1) ? wkb : wvb;
  const int rowBase = blockIdx.y << 8, colBase = blockIdx.x << 8;

  const int c0 = tid, c1 = tid + 512;
  const int sr0 = c0 >> 3, sk0 = ((c0 & 7) ^ (sr0 & 7)) * 8;
  const int sr1 = c1 >> 3, sk1 = ((c1 & 7) ^ (sr1 & 7)) * 8;

#define STG_A(BUF, H, T)                                                      \
  do {                                                                        \
    async16(Ag + (size_t)(rowBase + (H)*128 + sr0) * 1024 + (T)*64 + sk0,     \
            (char*)As[BUF][H] + c0 * 16);                                     \
    async16(Ag + (size_t)(rowBase + (H)*128 + sr1) * 1024 + (T)*64 + sk1,     \
            (char*)As[BUF][H] + c1 * 16);                                     \
  } while (0)
#define STG_B(BUF, H, T)                                                      \
  do {                                                                        \
    async16(Bg + (size_t)(colBase + (H)*128 + sr0) * 1024 + (T)*64 + sk0,     \
            (char*)Bs[BUF][H] + c0 * 16);                                     \
    async16(Bg + (size_t)(colBase + (H)*128 + sr1) * 1024 + (T)*64 + sk1,     \
            (char*)Bs[BUF][H] + c1 * 16);                                     \
  } while (0)

  f32x4 acc[8][4];
#pragma unroll
  for (int m = 0; m < 8; m++)
#pragma unroll
    for (int n = 0; n < 4; n++) acc[m][n] = (f32x4){0.f, 0.f, 0.f, 0.f};
  short8 af[4][2], bfr[2][2];

#define RD_A(CUR, MH)                                                         \
  do {                                                                        \
    _Pragma("unroll") for (int mi = 0; mi < 4; mi++) {                        \
      int ra = (MH)*64 + mi * 16 + r;                                         \
      const u16* p = As[CUR][wm] + ra * 64;                                   \
      int sw = (ra & 7) << 3;                                                 \
      af[mi][0] = *(const short8*)(p + ((g << 3) ^ sw));                      \
      af[mi][1] = *(const short8*)(p + (((4 + g) << 3) ^ sw));                \
    }                                                                         \
  } while (0)
#define RD_B(CUR, NP)                                                         \
  do {                                                                        \
    _Pragma("unroll") for (int ni = 0; ni < 2; ni++) {                        \
      int cb = wn * 64 + ((NP)*2 + ni) * 16 + r;                              \
      const u16* p = Bs[CUR][cb >> 7] + (cb & 127) * 64;                      \
      int sw = (cb & 7) << 3;                                                 \
      bfr[ni][0] = *(const short8*)(p + ((g << 3) ^ sw));                     \
      bfr[ni][1] = *(const short8*)(p + (((4 + g) << 3) ^ sw));               \
    }                                                                         \
  } while (0)
#define MM16(MH, NP)                                                          \
  do {                                                                        \
    _Pragma("unroll") for (int mi = 0; mi < 4; mi++)                          \
        _Pragma("unroll") for (int ni = 0; ni < 2; ni++) {                    \
      acc[(MH)*4 + mi][(NP)*2 + ni] =                                         \
          MFMA(af[mi][0], bfr[ni][0], acc[(MH)*4 + mi][(NP)*2 + ni]);         \
      acc[(MH)*4 + mi][(NP)*2 + ni] =                                         \
          MFMA(af[mi][1], bfr[ni][1], acc[(MH)*4 + mi][(NP)*2 + ni]);         \
    }                                                                         \
  } while (0)

  STG_A(0, 0, 0); STG_A(0, 1, 0); STG_B(0, 0, 0); STG_B(0, 1, 0);
  STG_A(1, 0, 1); STG_A(1, 1, 1);
  WAITV(4);
  BAR();

  for (int t = 0; t < 16; ++t) {
    const int cur = t & 1, nxt = cur ^ 1;
    RD_A(cur, 0); RD_B(cur, 0);
    if (t < 15) { STG_B(nxt, 0, t + 1); STG_B(nxt, 1, t + 1); }
    BAR(); WAITL0();
    PRIO1; MM16(0, 0); PRIO0; BAR();
    RD_B(cur, 1);
    BAR(); WAITL0();
    PRIO1; MM16(0, 1); PRIO0; BAR();
    RD_A(cur, 1);
    BAR(); WAITL0();
    PRIO1; MM16(1, 1); PRIO0; BAR();
    RD_B(cur, 0);
    if (t < 14) {
      STG_A(cur, 0, t + 2); STG_A(cur, 1, t + 2);
      WAITV(4);
    } else {
      WAITV(0);
    }
    BAR(); WAITL0();
    PRIO1; MM16(1, 0); PRIO0; BAR();
  }
#undef STG_A
#undef STG_B
#undef RD_A
#undef RD_B
#undef MM16

  if (z < 2) {
    u16* dst = z ? kb : qb;
    const float qs = z ? 1.0f : QSCALE;
#pragma unroll
    for (int m = 0; m < 8; m++)
#pragma unroll
      for (int n = 0; n < 4; n++) {
        const int col = colBase + wn * 64 + n * 16 + r;
        const int p2 = (col >> 1) & 31;
        const bool odd = col & 1;
#pragma unroll
        for (int i = 0; i < 4; i++) {
          const int row = rowBase + wm * 128 + m * 16 + g * 4 + i;  // b*2048+s
          float2 cssn = *(const float2*)(tab + row * 64 + p2 * 2);
          float v = acc[m][n][i];
          float part = __shfl_xor(v, 1);
          float res = odd ? (part * cssn.y + v * cssn.x)
                          : (v * cssn.x - part * cssn.y);
          dst[(size_t)row * 1024 + col] = f2bf(res * qs);
        }
      }
  } else {
#pragma unroll
    for (int m = 0; m < 8; m++)
#pragma unroll
      for (int n = 0; n < 4; n++)
#pragma unroll
        for (int i = 0; i < 4; i++) {
          int row = rowBase + wm * 128 + m * 16 + g * 4 + i;  // b*2048 + s
          int col = colBase + wn * 64 + n * 16 + r;           // h*64 + d
          int b = row >> 11, s = row & 2047;
          vt[(size_t)((b * 16 + (col >> 6)) * 64 + (col & 63)) * 2048 + s] =
              f2bf(acc[m][n][i]);
        }
  }
}

// ---------- GEMM core (128x128, counted vmcnt) — used by gemm_ao ----------
__device__ __forceinline__ void gemm_tile(const u16* __restrict__ A,
                                          const u16* __restrict__ Bm, int K,
                                          int rowBase, int colBase, u16* As,
                                          u16* Bs, f32x4 acc[4][4]) {
  const int tid = threadIdx.x;
  const int lane = tid & 63, wid = tid >> 6;
  const int wr = wid >> 1, wc = wid & 1;
  const int g = lane >> 4, r = lane & 15;

#pragma unroll
  for (int m = 0; m < 4; m++)
#pragma unroll
    for (int n = 0; n < 4; n++) acc[m][n] = (f32x4){0.f, 0.f, 0.f, 0.f};

#define GSTAGE(KT, BUF)                                                       \
  do {                                                                        \
    _Pragma("unroll") for (int i_ = 0; i_ < 4; ++i_) {                        \
      int c = i_ * 256 + tid;                                                 \
      int row = c >> 3, kc = (c & 7) ^ (row & 7);                             \
      async16(A + (size_t)(rowBase + row) * K + ((KT) << 6) + kc * 8,         \
              (char*)As + (BUF)*16384 + c * 16);                              \
    }                                                                         \
    _Pragma("unroll") for (int i_ = 0; i_ < 4; ++i_) {                        \
      int c = i_ * 256 + tid;                                                 \
      int row = c >> 3, kc = (c & 7) ^ (row & 7);                             \
      async16(Bm + (size_t)(colBase + row) * K + ((KT) << 6) + kc * 8,        \
              (char*)Bs + (BUF)*16384 + c * 16);                              \
    }                                                                         \
  } while (0)

  const int nkt = K >> 6;
  GSTAGE(0, 0);
  for (int kt = 0; kt < nkt; ++kt) {
    const int cur = kt & 1;
    if (kt + 1 < nkt) {
      GSTAGE(kt + 1, cur ^ 1);
      WAITV(8);
    } else {
      WAITV(0);
    }
    BAR();
    const u16* Ab = As + cur * 8192;
    const u16* Bb = Bs + cur * 8192;
#pragma unroll
    for (int ks = 0; ks < 2; ++ks) {
      short8 af[4], bfr[4];
#pragma unroll
      for (int m = 0; m < 4; m++) {
        int rr = wr * 64 + m * 16 + r;
        af[m] = *(const short8*)(Ab + rr * 64 + (((ks * 4 + g) ^ (rr & 7)) << 3));
      }
#pragma unroll
      for (int n = 0; n < 4; n++) {
        int rr = wc * 64 + n * 16 + r;
        bfr[n] = *(const short8*)(Bb + rr * 64 + (((ks * 4 + g) ^ (rr & 7)) << 3));
      }
#pragma unroll
      for (int m = 0; m < 4; m++)
#pragma unroll
        for (int n = 0; n < 4; n++)
          acc[m][n] = MFMA(af[m], bfr[n], acc[m][n]);
    }
    WAITL0();
    BAR();
  }
#undef GSTAGE
}

// ---------- 4. flash attention, causal-paired split blocks ----------
// Block = (a, k, bh): rows [k*64,k*64+64) of q-tiles {a, 15-a}. 4 waves; wave
// owns 16 rows of each tile. 512 blocks, 48 KB LDS -> 2+ blocks/CU = two
// independent barrier domains per CU (latency overlap). idx%32 = bh for XCD
// L2 locality.
__global__ __launch_bounds__(256) void attn_kernel(const u16* __restrict__ qg,
                                                   const u16* __restrict__ kg,
                                                   const u16* __restrict__ vt,
                                                   u16* __restrict__ ab) {
  __shared__ u16 Ks[2][64 * 64];
  __shared__ u16 Vs[2][64 * 64];
  __shared__ u16 Ps[8][1024];  // [wid*2+grp][16 q x 64 kv]
  const int tid = threadIdx.x, wid = tid >> 6, lane = tid & 63;
  const int g = lane >> 4, r = lane & 15;
  const int ak = blockIdx.x >> 5, bh = blockIdx.x & 31;
  const int a = ak >> 1, k = ak & 1;
  const int b = bh >> 4, h = bh & 15;
  const int rb[2] = {(a << 7) + (k << 6) + wid * 16,
                     ((15 - a) << 7) + (k << 6) + wid * 16};
  const int jend = 30 - 2 * a + k;

  short8 bq[2][2];
#pragma unroll
  for (int g2 = 0; g2 < 2; g2++) {
    const u16* qp =
        qg + (size_t)((b << 11) + rb[g2] + r) * 1024 + (h << 6) + g * 8;
    bq[g2][0] = *(const short8*)qp;
    bq[g2][1] = *(const short8*)(qp + 32);
  }

  f32x4 accO[2][4];
  float m_r[2] = {-1e30f, -1e30f}, l_r[2] = {0.f, 0.f};
#pragma unroll
  for (int g2 = 0; g2 < 2; g2++)
#pragma unroll
    for (int md = 0; md < 4; md++) accO[g2][md] = (f32x4){0.f, 0.f, 0.f, 0.f};

  // stage K tile [kv][d] + V^T tile [d][kv]: 512 chunks each, 2/thread/buf
#define STAGE(JT, BUF)                                                        \
  do {                                                                        \
    _Pragma("unroll") for (int i_ = 0; i_ < 2; i_++) {                        \
      int c = i_ * 256 + tid;                                                 \
      int row = c >> 3, cc = (c & 7) ^ (row & 7);                             \
      async16(kg + (size_t)((b << 11) + ((JT) << 6) + row) * 1024 +           \
                  (h << 6) + cc * 8,                                          \
              (char*)Ks[BUF] + c * 16);                                       \
      async16(vt + (size_t)((bh << 6) + row) * 2048 + ((JT) << 6) + cc * 8,   \
              (char*)Vs[BUF] + c * 16);                                       \
    }                                                                         \
  } while (0)

  STAGE(0, 0);

  for (int j = 0; j <= jend; ++j) {
    const int cur = j & 1;
    if (j < jend) {
      STAGE(j + 1, cur ^ 1);  // 8 outstanding; wait oldest 4 (= tile j)
      WAITV(4);
    } else {
      WAITV(0);
    }
    BAR();
    const bool act0 = (j <= (rb[0] >> 6));
    const bool act1 = (j <= (rb[1] >> 6));
    if (act0 | act1) {
      const u16* Kb = Ks[cur];
      const u16* Vb = Vs[cur];
      short8 kf[4][2];
#pragma unroll
      for (int mk = 0; mk < 4; mk++) {
        kf[mk][0] = *(const short8*)(Kb + (mk * 16 + r) * 64 + ((g) ^ (r & 7)) * 8);
        kf[mk][1] = *(const short8*)(Kb + (mk * 16 + r) * 64 + ((4 + g) ^ (r & 7)) * 8);
      }
#pragma unroll
      for (int g2 = 0; g2 < 2; g2++) {
        if (!(g2 ? act1 : act0)) continue;
        f32x4 accS[4];
        PRIO1;
#pragma unroll
        for (int mk = 0; mk < 4; mk++) {
          f32x4 z = {0.f, 0.f, 0.f, 0.f};
          z = MFMA(kf[mk][0], bq[g2][0], z);
          z = MFMA(kf[mk][1], bq[g2][1], z);
          accS[mk] = z;
        }
        PRIO0;
        const int qrow = rb[g2] + r;
        if (j == (rb[g2] >> 6)) {
#pragma unroll
          for (int mk = 0; mk < 4; mk++)
#pragma unroll
            for (int i = 0; i < 4; i++)
              if ((j << 6) + mk * 16 + g * 4 + i > qrow) accS[mk][i] = -1e30f;
        }
        float pmax = accS[0][0];
#pragma unroll
        for (int mk = 0; mk < 4; mk++)
#pragma unroll
          for (int i = 0; i < 4; i++) pmax = fmaxf(pmax, accS[mk][i]);
        pmax = fmaxf(pmax, __shfl_xor(pmax, 16));
        pmax = fmaxf(pmax, __shfl_xor(pmax, 32));
        float mnew = m_r[g2];
        if (!__all(pmax <= mnew + 8.0f)) {  // T13 defer-max
          mnew = fmaxf(mnew, pmax);
          float sc = exp2hw(m_r[g2] - mnew);
          l_r[g2] *= sc;
#pragma unroll
          for (int md = 0; md < 4; md++) accO[g2][md] *= sc;
          m_r[g2] = mnew;
        }
        float rs = 0.f;
        u16* pw = Ps[wid * 2 + g2];
#pragma unroll
        for (int mk = 0; mk < 4; mk++) {
          float p0 = exp2hw(accS[mk][0] - mnew);
          float p1 = exp2hw(accS[mk][1] - mnew);
          float p2 = exp2hw(accS[mk][2] - mnew);
          float p3 = exp2hw(accS[mk][3] - mnew);
          rs += (p0 + p1) + (p2 + p3);
          u32 d0 = cvtpk(p0, p1), d1 = cvtpk(p2, p3);
          uint2 dd = {d0, d1};
          *(uint2*)((char*)pw + r * 128 +
                    (((mk * 2 + (g >> 1)) ^ (r & 7)) << 4) + ((g & 1) << 3)) = dd;
        }
        rs += __shfl_xor(rs, 16);
        rs += __shfl_xor(rs, 32);
        l_r[g2] += rs;
      }
      WAITL0();
      short8 vf[4][2];
#pragma unroll
      for (int md = 0; md < 4; md++) {
        vf[md][0] = *(const short8*)(Vb + (md * 16 + r) * 64 + ((g) ^ (r & 7)) * 8);
        vf[md][1] = *(const short8*)(Vb + (md * 16 + r) * 64 + ((4 + g) ^ (r & 7)) * 8);
      }
      PRIO1;
#pragma unroll
      for (int g2 = 0; g2 < 2; g2++) {
        if (!(g2 ? act1 : act0)) continue;
        const u16* pw = Ps[wid * 2 + g2];
        short8 pb0 = *(const short8*)((const char*)pw + r * 128 + (((g) ^ (r & 7)) << 4));
        short8 pb1 = *(const short8*)((const char*)pw + r * 128 + (((4 + g) ^ (r & 7)) << 4));
#pragma unroll
        for (int md = 0; md < 4; md++) {
          accO[g2][md] = MFMA(vf[md][0], pb0, accO[g2][md]);
          accO[g2][md] = MFMA(vf[md][1], pb1, accO[g2][md]);
        }
      }
      PRIO0;
    }
    WAITL0();
    BAR();
  }
#undef STAGE

#pragma unroll
  for (int g2 = 0; g2 < 2; g2++) {
    float inv = 1.0f / l_r[g2];
#pragma unroll
    for (int md = 0; md < 4; md++) {
      u16x4 o;
#pragma unroll
      for (int i = 0; i < 4; i++) o[i] = f2bf(accO[g2][md][i] * inv);
      *(u16x4*)(ab + (size_t)((b << 11) + rb[g2] + r) * 1024 + (h << 6) +
                md * 16 + g * 4) = o;
    }
  }
}

// ---------- 5. output projection: out = attn * wo^T (f32 out) ----------
__global__ __launch_bounds__(256) void gemm_ao(const u16* __restrict__ ab,
                                               const u16* __restrict__ wob,
                                               float* __restrict__ out) {
  __shared__ u16 As[2][128 * 64], Bs[2][128 * 64];
  f32x4 acc[4][4];
  gemm_tile(ab, wob, 1024, blockIdx.y * 128, blockIdx.x * 128, As[0], Bs[0], acc);
  const int lane = threadIdx.x & 63, wid = threadIdx.x >> 6;
  const int wr = wid >> 1, wc = wid & 1, g = lane >> 4, r = lane & 15;
  const int rowB = blockIdx.y * 128 + wr * 64;
  const int colB = blockIdx.x * 128 + wc * 64;
#pragma unroll
  for (int m = 0; m < 4; m++)
#pragma unroll
    for (int n = 0; n < 4; n++)
#pragma unroll
      for (int i = 0; i < 4; i++)
        out[(size_t)(rowB + m * 16 + g * 4 + i) * 1024 + colB + n * 16 + r] =
            acc[m][n][i];
}

extern "C" void kernel_launch(void* const* d_in, const int* in_sizes, int n_in,
                              void* d_out, int out_size, void* d_ws,
                              size_t ws_size, hipStream_t stream) {
  const float* x = (const float*)d_in[0];
  const int* tp = (const int*)d_in[1];
  const float* wq = (const float*)d_in[2];
  const float* wk = (const float*)d_in[3];
  const float* wv = (const float*)d_in[4];
  const float* wo = (const float*)d_in[5];
  float* out = (float*)d_out;

  u16* ws = (u16*)d_ws;
  u16* xb = ws;                   // 4194304
  u16* wqb = xb + 4194304;        // 1048576
  u16* wkb = wqb + 1048576;
  u16* wvb = wkb + 1048576;
  u16* wob = wvb + 1048576;
  u16* qb = wob + 1048576;        // 4194304
  u16* kb = qb + 4194304;
  u16* vtb = kb + 4194304;        // [b][h][d][s]
  u16* ab = vtb + 4194304;
  float* tab = (float*)ab;        // 1 MB, aliases ab (dead before attn writes)

  convert_kernel<<<4096, 256, 0, stream>>>(x, wq, wk, wv, wo, ws);
  rope_table<<<512, 256, 0, stream>>>(tp, tab);
  gemm_qkv256<<<dim3(4, 16, 3), 512, 0, stream>>>(xb, wqb, wkb, wvb, tab, qb,
                                                  kb, vtb);
  attn_kernel<<<512, 256, 0, stream>>>(qb, kb, vtb, ab);
  gemm_ao<<<dim3(8, 32), 256, 0, stream>>>(ab, wob, out);
}

// Round 8
// 124.080 us; speedup vs baseline: 2.6819x; 1.0057x over previous
//
#include <hip/hip_runtime.h>
#include <hip/hip_bf16.h>

typedef unsigned short u16;
typedef unsigned int u32;
typedef short short8 __attribute__((ext_vector_type(8)));
typedef u16 u16x8 __attribute__((ext_vector_type(8)));
typedef u16 u16x4 __attribute__((ext_vector_type(4)));
typedef u32 u32x4 __attribute__((ext_vector_type(4)));
typedef float f32x4 __attribute__((ext_vector_type(4)));
typedef float f32x16 __attribute__((ext_vector_type(16)));

#define MFMA(a, b, c) __builtin_amdgcn_mfma_f32_16x16x32_bf16((a), (b), (c), 0, 0, 0)
#define MFMA32(a, b, c) __builtin_amdgcn_mfma_f32_32x32x16_bf16((a), (b), (c), 0, 0, 0)

// log2(e)*0.125 folded into Q at projection time; softmax runs in exp2 domain.
#define QSCALE 0.18033688011112042f

// ---------- helpers ----------
__device__ __forceinline__ u16 f2bf(float f) {
  unsigned u = __float_as_uint(f);
  unsigned r = (u + 0x7fffu + ((u >> 16) & 1u)) >> 16;  // RNE
  return (u16)r;
}
__device__ __forceinline__ float bf2f(u16 h) {
  return __uint_as_float(((unsigned)h) << 16);
}
__device__ __forceinline__ float exp2hw(float x) {
  float r;
  asm("v_exp_f32 %0, %1" : "=v"(r) : "v"(x));
  return r;
}
__device__ __forceinline__ u32 cvtpk(float lo, float hi) {
  u32 d;
  asm("v_cvt_pk_bf16_f32 %0, %1, %2" : "=v"(d) : "v"(lo), "v"(hi));
  return d;
}
// v_permlane32_swap: a[32:63] <-> b[0:31]; both registers updated.
__device__ __forceinline__ void plswap(u32& a, u32& b) {
  asm volatile("v_permlane32_swap_b32 %0, %1" : "+v"(a), "+v"(b));
}
__device__ __forceinline__ void async16(const void* g, void* l) {
  __builtin_amdgcn_global_load_lds(
      (const __attribute__((address_space(1))) void*)g,
      (__attribute__((address_space(3))) void*)l, 16, 0, 0);
}
__device__ __forceinline__ f32x16 zero16() {
  f32x16 z;
#pragma unroll
  for (int i = 0; i < 16; i++) z[i] = 0.f;
  return z;
}
// counted waits (T4): keep prefetch loads in flight across barriers
#define WAITV(N) asm volatile("s_waitcnt vmcnt(" #N ")" ::: "memory")
#define WAITL0() asm volatile("s_waitcnt lgkmcnt(0)" ::: "memory")
#define BAR() __builtin_amdgcn_s_barrier()
#define PRIO1 __builtin_amdgcn_s_setprio(1)
#define PRIO0 __builtin_amdgcn_s_setprio(0)

// ---------- 1. f32 -> bf16 convert (x, wq, wk, wv, wo) ----------
__global__ __launch_bounds__(256) void convert_kernel(
    const float* __restrict__ x, const float* __restrict__ wq,
    const float* __restrict__ wk, const float* __restrict__ wv,
    const float* __restrict__ wo, u16* __restrict__ ws) {
  int blk = blockIdx.x;
  const float* src; u16* dst;
  if (blk < 2048)      { src = x;  dst = ws; }
  else if (blk < 2560) { src = wq; dst = ws + 4194304;               blk -= 2048; }
  else if (blk < 3072) { src = wk; dst = ws + 4194304 + 1048576;     blk -= 2560; }
  else if (blk < 3584) { src = wv; dst = ws + 4194304 + 2 * 1048576; blk -= 3072; }
  else                 { src = wo; dst = ws + 4194304 + 3 * 1048576; blk -= 3584; }
  int idx = (blk * 256 + threadIdx.x) * 8;
  float4 v0 = *(const float4*)(src + idx);
  float4 v1 = *(const float4*)(src + idx + 4);
  u16x8 o;
  o[0] = f2bf(v0.x); o[1] = f2bf(v0.y); o[2] = f2bf(v0.z); o[3] = f2bf(v0.w);
  o[4] = f2bf(v1.x); o[5] = f2bf(v1.y); o[6] = f2bf(v1.z); o[7] = f2bf(v1.w);
  *(u16x8*)(dst + idx) = o;
}

// ---------- 2a. cos/sin table: tab[bs*64 + p*2 + {0,1}] = cos/sin(tp[bs]*freq_p)
__global__ __launch_bounds__(256) void rope_table(const int* __restrict__ tp,
                                                  float* __restrict__ tab) {
  int t = blockIdx.x * 256 + threadIdx.x;  // 131072
  int bs = t >> 5, p = t & 31;
  float freq = exp2hw(-(float)p * 0.4152410118609203f);
  float ang = (float)tp[bs] * freq;
  float sn, cs;
  sincosf(ang, &sn, &cs);
  tab[bs * 64 + p * 2] = cs;
  tab[bs * 64 + p * 2 + 1] = sn;
}

// ---------- 2b. QKV projection: 256x256, 2-phase/K-tile, counted vmcnt ----
__global__ __launch_bounds__(512, 2) void gemm_qkv256(
    const u16* __restrict__ xb, const u16* __restrict__ wqb,
    const u16* __restrict__ wkb, const u16* __restrict__ wvb,
    const float* __restrict__ tab, u16* __restrict__ qb, u16* __restrict__ kb,
    u16* __restrict__ vt) {
  __shared__ u16 As[2][2][8192];  // [tile-buf][half: rows 0-127 / 128-255][128x64]
  __shared__ u16 Bs[2][2][8192];
  const int tid = threadIdx.x, lane = tid & 63, wid = tid >> 6;
  const int wm = wid >> 2, wn = wid & 3;
  const int g = lane >> 4, r = lane & 15;
  const int z = blockIdx.z;
  const u16* Ag = xb;
  const u16* Bg = (z == 0) ? wqb : (z == 1) ? wkb : wvb;
  const int rowBase = blockIdx.y << 8, colBase = blockIdx.x << 8;

  const int c0 = tid, c1 = tid + 512;
  const int sr0 = c0 >> 3, sk0 = ((c0 & 7) ^ (sr0 & 7)) * 8;
  const int sr1 = c1 >> 3, sk1 = ((c1 & 7) ^ (sr1 & 7)) * 8;

#define STG_A(BUF, H, T)                                                      \
  do {                                                                        \
    async16(Ag + (size_t)(rowBase + (H)*128 + sr0) * 1024 + (T)*64 + sk0,     \
            (char*)As[BUF][H] + c0 * 16);                                     \
    async16(Ag + (size_t)(rowBase + (H)*128 + sr1) * 1024 + (T)*64 + sk1,     \
            (char*)As[BUF][H] + c1 * 16);                                     \
  } while (0)
#define STG_B(BUF, H, T)                                                      \
  do {                                                                        \
    async16(Bg + (size_t)(colBase + (H)*128 + sr0) * 1024 + (T)*64 + sk0,     \
            (char*)Bs[BUF][H] + c0 * 16);                                     \
    async16(Bg + (size_t)(colBase + (H)*128 + sr1) * 1024 + (T)*64 + sk1,     \
            (char*)Bs[BUF][H] + c1 * 16);                                     \
  } while (0)

  f32x4 acc[8][4];
#pragma unroll
  for (int m = 0; m < 8; m++)
#pragma unroll
    for (int n = 0; n < 4; n++) acc[m][n] = (f32x4){0.f, 0.f, 0.f, 0.f};
  short8 af[4][2], bfr[4][2];

#define RD_A(CUR, MH)                                                         \
  do {                                                                        \
    _Pragma("unroll") for (int mi = 0; mi < 4; mi++) {                        \
      int ra = (MH)*64 + mi * 16 + r;                                         \
      const u16* p = As[CUR][wm] + ra * 64;                                   \
      int sw = (ra & 7) << 3;                                                 \
      af[mi][0] = *(const short8*)(p + ((g << 3) ^ sw));                      \
      af[mi][1] = *(const short8*)(p + (((4 + g) << 3) ^ sw));                \
    }                                                                         \
  } while (0)
#define RD_B(CUR, NP)                                                         \
  do {                                                                        \
    _Pragma("unroll") for (int ni = 0; ni < 2; ni++) {                        \
      int cb = wn * 64 + ((NP)*2 + ni) * 16 + r;                              \
      const u16* p = Bs[CUR][cb >> 7] + (cb & 127) * 64;                      \
      int sw = (cb & 7) << 3;                                                 \
      bfr[(NP)*2 + ni][0] = *(const short8*)(p + ((g << 3) ^ sw));            \
      bfr[(NP)*2 + ni][1] = *(const short8*)(p + (((4 + g) << 3) ^ sw));      \
    }                                                                         \
  } while (0)
#define MM16(MH, NP)                                                          \
  do {                                                                        \
    _Pragma("unroll") for (int mi = 0; mi < 4; mi++)                          \
        _Pragma("unroll") for (int ni = 0; ni < 2; ni++) {                    \
      acc[(MH)*4 + mi][(NP)*2 + ni] = MFMA(af[mi][0], bfr[(NP)*2 + ni][0],    \
                                           acc[(MH)*4 + mi][(NP)*2 + ni]);    \
      acc[(MH)*4 + mi][(NP)*2 + ni] = MFMA(af[mi][1], bfr[(NP)*2 + ni][1],    \
                                           acc[(MH)*4 + mi][(NP)*2 + ni]);    \
    }                                                                         \
  } while (0)

  // prologue: tile0 (A+B) + A(1); leave A(1) in flight
  STG_A(0, 0, 0); STG_A(0, 1, 0); STG_B(0, 0, 0); STG_B(0, 1, 0);
  STG_A(1, 0, 1); STG_A(1, 1, 1);
  WAITV(4);
  BAR();

  for (int t = 0; t < 16; ++t) {
    const int cur = t & 1, nxt = cur ^ 1;
    // P0: A-half0 + all B; stage B(t+1)
    RD_A(cur, 0);
    RD_B(cur, 0); RD_B(cur, 1);
    if (t < 15) { STG_B(nxt, 0, t + 1); STG_B(nxt, 1, t + 1); }
    BAR(); WAITL0();
    PRIO1; MM16(0, 0); MM16(0, 1); PRIO0; BAR();
    // P1: A-half1 (B frags reused); stage A(t+2); counted wait
    RD_A(cur, 1);
    if (t < 14) {
      STG_A(cur, 0, t + 2); STG_A(cur, 1, t + 2);
      WAITV(4);  // drains A(t+1)+B(t+1); A(t+2) stays in flight
    } else {
      WAITV(0);  // drain everything before the final tiles' reads
    }
    BAR(); WAITL0();
    PRIO1; MM16(1, 0); MM16(1, 1); PRIO0; BAR();
  }
#undef STG_A
#undef STG_B
#undef RD_A
#undef RD_B
#undef MM16

  if (z < 2) {
    // RoPE fused: pair (2p,2p+1) = adjacent cols = adjacent lanes (r, r^1)
    u16* dst = z ? kb : qb;
    const float qs = z ? 1.0f : QSCALE;
#pragma unroll
    for (int m = 0; m < 8; m++)
#pragma unroll
      for (int n = 0; n < 4; n++) {
        const int col = colBase + wn * 64 + n * 16 + r;
        const int p2 = (col >> 1) & 31;
        const bool odd = col & 1;
#pragma unroll
        for (int i = 0; i < 4; i++) {
          const int row = rowBase + wm * 128 + m * 16 + g * 4 + i;  // b*2048+s
          float2 cssn = *(const float2*)(tab + row * 64 + p2 * 2);
          float v = acc[m][n][i];
          float part = __shfl_xor(v, 1);
          float res = odd ? (part * cssn.y + v * cssn.x)
                          : (v * cssn.x - part * cssn.y);
          dst[(size_t)row * 1024 + col] = f2bf(res * qs);
        }
      }
  } else {
#pragma unroll
    for (int m = 0; m < 8; m++)
#pragma unroll
      for (int n = 0; n < 4; n++)
#pragma unroll
        for (int i = 0; i < 4; i++) {
          int row = rowBase + wm * 128 + m * 16 + g * 4 + i;  // b*2048 + s
          int col = colBase + wn * 64 + n * 16 + r;           // h*64 + d
          int b = row >> 11, s = row & 2047;
          vt[(size_t)((b * 16 + (col >> 6)) * 64 + (col & 63)) * 2048 + s] =
              f2bf(acc[m][n][i]);
        }
  }
}

// ---------- GEMM core (128x128, counted vmcnt) — used by gemm_ao ----------
__device__ __forceinline__ void gemm_tile(const u16* __restrict__ A,
                                          const u16* __restrict__ Bm, int K,
                                          int rowBase, int colBase, u16* As,
                                          u16* Bs, f32x4 acc[4][4]) {
  const int tid = threadIdx.x;
  const int lane = tid & 63, wid = tid >> 6;
  const int wr = wid >> 1, wc = wid & 1;
  const int g = lane >> 4, r = lane & 15;

#pragma unroll
  for (int m = 0; m < 4; m++)
#pragma unroll
    for (int n = 0; n < 4; n++) acc[m][n] = (f32x4){0.f, 0.f, 0.f, 0.f};

#define GSTAGE(KT, BUF)                                                       \
  do {                                                                        \
    _Pragma("unroll") for (int i_ = 0; i_ < 4; ++i_) {                        \
      int c = i_ * 256 + tid;                                                 \
      int row = c >> 3, kc = (c & 7) ^ (row & 7);                             \
      async16(A + (size_t)(rowBase + row) * K + ((KT) << 6) + kc * 8,         \
              (char*)As + (BUF)*16384 + c * 16);                              \
    }                                                                         \
    _Pragma("unroll") for (int i_ = 0; i_ < 4; ++i_) {                        \
      int c = i_ * 256 + tid;                                                 \
      int row = c >> 3, kc = (c & 7) ^ (row & 7);                             \
      async16(Bm + (size_t)(colBase + row) * K + ((KT) << 6) + kc * 8,        \
              (char*)Bs + (BUF)*16384 + c * 16);                              \
    }                                                                         \
  } while (0)

  const int nkt = K >> 6;
  GSTAGE(0, 0);
  for (int kt = 0; kt < nkt; ++kt) {
    const int cur = kt & 1;
    if (kt + 1 < nkt) {
      GSTAGE(kt + 1, cur ^ 1);
      WAITV(8);
    } else {
      WAITV(0);
    }
    BAR();
    const u16* Ab = As + cur * 8192;
    const u16* Bb = Bs + cur * 8192;
#pragma unroll
    for (int ks = 0; ks < 2; ++ks) {
      short8 af[4], bfr[4];
#pragma unroll
      for (int m = 0; m < 4; m++) {
        int rr = wr * 64 + m * 16 + r;
        af[m] = *(const short8*)(Ab + rr * 64 + (((ks * 4 + g) ^ (rr & 7)) << 3));
      }
#pragma unroll
      for (int n = 0; n < 4; n++) {
        int rr = wc * 64 + n * 16 + r;
        bfr[n] = *(const short8*)(Bb + rr * 64 + (((ks * 4 + g) ^ (rr & 7)) << 3));
      }
#pragma unroll
      for (int m = 0; m < 4; m++)
#pragma unroll
        for (int n = 0; n < 4; n++)
          acc[m][n] = MFMA(af[m], bfr[n], acc[m][n]);
    }
    WAITL0();
    BAR();
  }
#undef GSTAGE
}

// ---------- 4. flash attention: 32x32 MFMA, fully in-register softmax/P ----
// Block = (a, k, bh), 4 waves of 32 q-rows: waves 0-1 -> tile a, 2-3 -> tile
// 15-a (balanced causal pairing). Swapped QK^T (mfma32(K, Q^T)): lane owns one
// q-row (col = lane&31); P redistributed to the PV B-fragment with
// v_permlane32_swap (no LDS round trip). K/V staged dbuf + counted vmcnt.
__global__ __launch_bounds__(256, 2) void attn_kernel(
    const u16* __restrict__ qg, const u16* __restrict__ kg,
    const u16* __restrict__ vt, u16* __restrict__ ab) {
  __shared__ u16 Ks[2][64 * 64];
  __shared__ u16 Vs[2][64 * 64];
  const int tid = threadIdx.x, wid = tid >> 6, lane = tid & 63;
  const int q5 = lane & 31, hi = lane >> 5;
  const int ak = blockIdx.x >> 5, bh = blockIdx.x & 31;
  const int a = ak >> 1, k = ak & 1;
  const int b = bh >> 4, h = bh & 15;
  const int base = (wid < 2) ? a : (15 - a);
  const int rb = base * 128 + k * 64 + (wid & 1) * 32;  // wave q base
  const int cmax = rb >> 5;          // last active 32-kv chunk index
  const int jend = 30 - 2 * a + k;   // block-uniform KV-tile count - 1
  const int qrow = (b << 11) + rb + q5;

  // Q B-fragments: bq[kk] = row qrow, d = kk*16 + hi*8 + {0..7}
  short8 bq[4];
  {
    const u16* qp = qg + (size_t)qrow * 1024 + (h << 6) + hi * 8;
    bq[0] = *(const short8*)(qp);
    bq[1] = *(const short8*)(qp + 16);
    bq[2] = *(const short8*)(qp + 32);
    bq[3] = *(const short8*)(qp + 48);
  }
  f32x16 accO0 = zero16(), accO1 = zero16();  // d 0-31 / 32-63
  float m_r = -1e30f, l_r = 0.f;

#define STAGE(JT, BUF)                                                        \
  do {                                                                        \
    _Pragma("unroll") for (int i_ = 0; i_ < 2; i_++) {                        \
      int c = i_ * 256 + tid;                                                 \
      int row = c >> 3, cc = (c & 7) ^ (row & 7);                             \
      async16(kg + (size_t)((b << 11) + ((JT) << 6) + row) * 1024 +           \
                  (h << 6) + cc * 8,                                          \
              (char*)Ks[BUF] + c * 16);                                       \
      async16(vt + (size_t)((bh << 6) + row) * 2048 + ((JT) << 6) + cc * 8,   \
              (char*)Vs[BUF] + c * 16);                                       \
    }                                                                         \
  } while (0)

  STAGE(0, 0);

  for (int j = 0; j <= jend; ++j) {
    const int cur = j & 1;
    if (j < jend) {
      STAGE(j + 1, cur ^ 1);  // 8 outstanding; drain oldest 4 (= tile j)
      WAITV(4);
    } else {
      WAITV(0);
    }
    BAR();
    if (2 * j <= cmax) {  // wave-uniform activity
      const u16* Kb = Ks[cur];
      const u16* Vb = Vs[cur];
      const bool has1 = (2 * j + 1 <= cmax);
      const int rsw = (q5 & 7) << 3;
      // ---- QK^T: S^T chunks (kv 0-31, 32-63), col = q
      f32x16 s0 = zero16(), s1 = zero16();
      PRIO1;
#pragma unroll
      for (int kk = 0; kk < 4; kk++) {
        short8 kf =
            *(const short8*)(Kb + q5 * 64 + ((((kk << 1) + hi) << 3) ^ rsw));
        s0 = MFMA32(kf, bq[kk], s0);
      }
      PRIO0;
      if (has1) {
        PRIO1;
#pragma unroll
        for (int kk = 0; kk < 4; kk++) {
          short8 kf = *(const short8*)(Kb + (32 + q5) * 64 +
                                       ((((kk << 1) + hi) << 3) ^ rsw));
          s1 = MFMA32(kf, bq[kk], s1);
        }
        PRIO0;
      }
      // ---- causal mask on the boundary chunk (rowk > q5)
      if (2 * j == cmax) {
#pragma unroll
        for (int rg = 0; rg < 16; rg++) {
          int rowk = (rg & 3) + 8 * (rg >> 2) + 4 * hi;
          if (rowk > q5) s0[rg] = -1e30f;
        }
      } else if (2 * j + 1 == cmax) {
#pragma unroll
        for (int rg = 0; rg < 16; rg++) {
          int rowk = (rg & 3) + 8 * (rg >> 2) + 4 * hi;
          if (rowk > q5) s1[rg] = -1e30f;
        }
      }
      // ---- online softmax (lane owns one q-row; partner = lane^32)
      float pmax = s0[0];
#pragma unroll
      for (int rg = 1; rg < 16; rg++) pmax = fmaxf(pmax, s0[rg]);
      if (has1) {
#pragma unroll
        for (int rg = 0; rg < 16; rg++) pmax = fmaxf(pmax, s1[rg]);
      }
      pmax = fmaxf(pmax, __shfl_xor(pmax, 32));
      if (!__all(pmax <= m_r + 8.0f)) {  // T13 defer-max
        float mn = fmaxf(m_r, pmax);
        float sc = exp2hw(m_r - mn);
        l_r *= sc;
#pragma unroll
        for (int rg = 0; rg < 16; rg++) {
          accO0[rg] *= sc;
          accO1[rg] *= sc;
        }
        m_r = mn;
      }
      // ---- exp + pack + permlane-swap into PV B-fragments
      float rs = 0.f;
      u32 pw00[4], pw01[4], pw10[4], pw11[4];
#define PACK(SREG, OUT, S16)                                                  \
  do {                                                                        \
    float p0 = exp2hw(SREG[(S16)*8 + 0] - m_r);                               \
    float p1 = exp2hw(SREG[(S16)*8 + 1] - m_r);                               \
    float p2 = exp2hw(SREG[(S16)*8 + 2] - m_r);                               \
    float p3 = exp2hw(SREG[(S16)*8 + 3] - m_r);                               \
    float p4 = exp2hw(SREG[(S16)*8 + 4] - m_r);                               \
    float p5 = exp2hw(SREG[(S16)*8 + 5] - m_r);                               \
    float p6 = exp2hw(SREG[(S16)*8 + 6] - m_r);                               \
    float p7 = exp2hw(SREG[(S16)*8 + 7] - m_r);                               \
    rs += ((p0 + p1) + (p2 + p3)) + ((p4 + p5) + (p6 + p7));                  \
    u32 X = cvtpk(p0, p1), Y = cvtpk(p2, p3);                                 \
    u32 U = cvtpk(p4, p5), W = cvtpk(p6, p7);                                 \
    plswap(X, U);                                                             \
    plswap(Y, W);                                                             \
    OUT[0] = X; OUT[1] = Y; OUT[2] = U; OUT[3] = W;                           \
  } while (0)
      PACK(s0, pw00, 0);
      PACK(s0, pw01, 1);
      if (has1) {
        PACK(s1, pw10, 0);
        PACK(s1, pw11, 1);
      }
#undef PACK
      rs += __shfl_xor(rs, 32);
      l_r += rs;
      // ---- PV: O^T += V^T * P  (A = V^T from LDS, B = packed P frags)
#define PVSTEP(PW, CH)                                                        \
  do {                                                                        \
    u32x4 pv_ = {PW[0], PW[1], PW[2], PW[3]};                                 \
    short8 pb_ = __builtin_bit_cast(short8, pv_);                             \
    short8 v0_ =                                                              \
        *(const short8*)(Vb + q5 * 64 + ((((CH) + hi) << 3) ^ rsw));          \
    short8 v1_ = *(const short8*)(Vb + (32 + q5) * 64 +                       \
                                  ((((CH) + hi) << 3) ^ rsw));                \
    accO0 = MFMA32(v0_, pb_, accO0);                                          \
    accO1 = MFMA32(v1_, pb_, accO1);                                          \
  } while (0)
      PRIO1;
      PVSTEP(pw00, 0);
      PVSTEP(pw01, 2);
      if (has1) {
        PVSTEP(pw10, 4);
        PVSTEP(pw11, 6);
      }
      PRIO0;
#undef PVSTEP
    }
    WAITL0();
    BAR();
  }
#undef STAGE

  // epilogue: ab[qrow][h*64 + d] = O^T / l ; d = md*32 + qd*8 + hi*4 + {0..3}
  float inv = 1.0f / l_r;
#pragma unroll
  for (int qd = 0; qd < 4; qd++) {
    u16x4 o0, o1;
#pragma unroll
    for (int e = 0; e < 4; e++) {
      o0[e] = f2bf(accO0[qd * 4 + e] * inv);
      o1[e] = f2bf(accO1[qd * 4 + e] * inv);
    }
    u16* op = ab + (size_t)qrow * 1024 + (h << 6) + qd * 8 + hi * 4;
    *(u16x4*)(op) = o0;
    *(u16x4*)(op + 32) = o1;
  }
}

// ---------- 5. output projection: out = attn * wo^T (f32 out) ----------
__global__ __launch_bounds__(256) void gemm_ao(const u16* __restrict__ ab,
                                               const u16* __restrict__ wob,
                                               float* __restrict__ out) {
  __shared__ u16 As[2][128 * 64], Bs[2][128 * 64];
  f32x4 acc[4][4];
  gemm_tile(ab, wob, 1024, blockIdx.y * 128, blockIdx.x * 128, As[0], Bs[0], acc);
  const int lane = threadIdx.x & 63, wid = threadIdx.x >> 6;
  const int wr = wid >> 1, wc = wid & 1, g = lane >> 4, r = lane & 15;
  const int rowB = blockIdx.y * 128 + wr * 64;
  const int colB = blockIdx.x * 128 + wc * 64;
#pragma unroll
  for (int m = 0; m < 4; m++)
#pragma unroll
    for (int n = 0; n < 4; n++)
#pragma unroll
      for (int i = 0; i < 4; i++)
        out[(size_t)(rowB + m * 16 + g * 4 + i) * 1024 + colB + n * 16 + r] =
            acc[m][n][i];
}

extern "C" void kernel_launch(void* const* d_in, const int* in_sizes, int n_in,
                              void* d_out, int out_size, void* d_ws,
                              size_t ws_size, hipStream_t stream) {
  const float* x = (const float*)d_in[0];
  const int* tp = (const int*)d_in[1];
  const float* wq = (const float*)d_in[2];
  const float* wk = (const float*)d_in[3];
  const float* wv = (const float*)d_in[4];
  const float* wo = (const float*)d_in[5];
  float* out = (float*)d_out;

  u16* ws = (u16*)d_ws;
  u16* xb = ws;                   // 4194304
  u16* wqb = xb + 4194304;        // 1048576
  u16* wkb = wqb + 1048576;
  u16* wvb = wkb + 1048576;
  u16* wob = wvb + 1048576;
  u16* qb = wob + 1048576;        // 4194304
  u16* kb = qb + 4194304;
  u16* vtb = kb + 4194304;        // [b][h][d][s]
  u16* ab = vtb + 4194304;
  float* tab = (float*)ab;        // 1 MB, aliases ab (dead before attn writes)

  convert_kernel<<<4096, 256, 0, stream>>>(x, wq, wk, wv, wo, ws);
  rope_table<<<512, 256, 0, stream>>>(tp, tab);
  gemm_qkv256<<<dim3(4, 16, 3), 512, 0, stream>>>(xb, wqb, wkb, wvb, tab, qb,
                                                  kb, vtb);
  attn_kernel<<<512, 256, 0, stream>>>(qb, kb, vtb, ab);
  gemm_ao<<<dim3(8, 32), 256, 0, stream>>>(ab, wob, out);
}

// Round 9
// 117.982 us; speedup vs baseline: 2.8206x; 1.0517x over previous
//
#include <hip/hip_runtime.h>
#include <hip/hip_bf16.h>

typedef unsigned short u16;
typedef unsigned int u32;
typedef short short8 __attribute__((ext_vector_type(8)));
typedef u16 u16x8 __attribute__((ext_vector_type(8)));
typedef u16 u16x4 __attribute__((ext_vector_type(4)));
typedef u32 u32x4 __attribute__((ext_vector_type(4)));
typedef float f32x4 __attribute__((ext_vector_type(4)));
typedef float f32x16 __attribute__((ext_vector_type(16)));

#define MFMA(a, b, c) __builtin_amdgcn_mfma_f32_16x16x32_bf16((a), (b), (c), 0, 0, 0)
#define MFMA32(a, b, c) __builtin_amdgcn_mfma_f32_32x32x16_bf16((a), (b), (c), 0, 0, 0)

// log2(e)*0.125 folded into Q at projection time; softmax runs in exp2 domain.
#define QSCALE 0.18033688011112042f

// ---------- helpers ----------
__device__ __forceinline__ u16 f2bf(float f) {
  unsigned u = __float_as_uint(f);
  unsigned r = (u + 0x7fffu + ((u >> 16) & 1u)) >> 16;  // RNE
  return (u16)r;
}
__device__ __forceinline__ float bf2f(u16 h) {
  return __uint_as_float(((unsigned)h) << 16);
}
__device__ __forceinline__ float exp2hw(float x) {
  float r;
  asm("v_exp_f32 %0, %1" : "=v"(r) : "v"(x));
  return r;
}
__device__ __forceinline__ u32 cvtpk(float lo, float hi) {
  u32 d;
  asm("v_cvt_pk_bf16_f32 %0, %1, %2" : "=v"(d) : "v"(lo), "v"(hi));
  return d;
}
// v_permlane32_swap: a[32:63] <-> b[0:31]; both registers updated.
__device__ __forceinline__ void plswap(u32& a, u32& b) {
  asm volatile("v_permlane32_swap_b32 %0, %1" : "+v"(a), "+v"(b));
}
__device__ __forceinline__ void async16(const void* g, void* l) {
  __builtin_amdgcn_global_load_lds(
      (const __attribute__((address_space(1))) void*)g,
      (__attribute__((address_space(3))) void*)l, 16, 0, 0);
}
__device__ __forceinline__ f32x16 zero16() {
  f32x16 z;
#pragma unroll
  for (int i = 0; i < 16; i++) z[i] = 0.f;
  return z;
}
// counted waits (T4): keep prefetch loads in flight across barriers
#define WAITV(N) asm volatile("s_waitcnt vmcnt(" #N ")" ::: "memory")
#define WAITL0() asm volatile("s_waitcnt lgkmcnt(0)" ::: "memory")
#define BAR() __builtin_amdgcn_s_barrier()
#define PRIO1 __builtin_amdgcn_s_setprio(1)
#define PRIO0 __builtin_amdgcn_s_setprio(0)

// ---------- 1. f32 -> bf16 convert (x, wq, wk, wv, wo) ----------
__global__ __launch_bounds__(256) void convert_kernel(
    const float* __restrict__ x, const float* __restrict__ wq,
    const float* __restrict__ wk, const float* __restrict__ wv,
    const float* __restrict__ wo, u16* __restrict__ ws) {
  int blk = blockIdx.x;
  const float* src; u16* dst;
  if (blk < 2048)      { src = x;  dst = ws; }
  else if (blk < 2560) { src = wq; dst = ws + 4194304;               blk -= 2048; }
  else if (blk < 3072) { src = wk; dst = ws + 4194304 + 1048576;     blk -= 2560; }
  else if (blk < 3584) { src = wv; dst = ws + 4194304 + 2 * 1048576; blk -= 3072; }
  else                 { src = wo; dst = ws + 4194304 + 3 * 1048576; blk -= 3584; }
  int idx = (blk * 256 + threadIdx.x) * 8;
  float4 v0 = *(const float4*)(src + idx);
  float4 v1 = *(const float4*)(src + idx + 4);
  u16x8 o;
  o[0] = f2bf(v0.x); o[1] = f2bf(v0.y); o[2] = f2bf(v0.z); o[3] = f2bf(v0.w);
  o[4] = f2bf(v1.x); o[5] = f2bf(v1.y); o[6] = f2bf(v1.z); o[7] = f2bf(v1.w);
  *(u16x8*)(dst + idx) = o;
}

// ---------- 2a. cos/sin table: tab[bs*64 + p*2 + {0,1}] = cos/sin(tp[bs]*freq_p)
__global__ __launch_bounds__(256) void rope_table(const int* __restrict__ tp,
                                                  float* __restrict__ tab) {
  int t = blockIdx.x * 256 + threadIdx.x;  // 131072
  int bs = t >> 5, p = t & 31;
  float freq = exp2hw(-(float)p * 0.4152410118609203f);
  float ang = (float)tp[bs] * freq;
  float sn, cs;
  sincosf(ang, &sn, &cs);
  tab[bs * 64 + p * 2] = cs;
  tab[bs * 64 + p * 2 + 1] = sn;
}

// ---------- 2b. QKV projection: 256x256, 2-phase/K-tile, counted vmcnt ----
__global__ __launch_bounds__(512, 2) void gemm_qkv256(
    const u16* __restrict__ xb, const u16* __restrict__ wqb,
    const u16* __restrict__ wkb, const u16* __restrict__ wvb,
    const float* __restrict__ tab, u16* __restrict__ qb, u16* __restrict__ kb,
    u16* __restrict__ vt) {
  __shared__ u16 As[2][2][8192];  // [tile-buf][half: rows 0-127 / 128-255][128x64]
  __shared__ u16 Bs[2][2][8192];
  const int tid = threadIdx.x, lane = tid & 63, wid = tid >> 6;
  const int wm = wid >> 2, wn = wid & 3;
  const int g = lane >> 4, r = lane & 15;
  const int z = blockIdx.z;
  const u16* Ag = xb;
  const u16* Bg = (z == 0) ? wqb : (z == 1) ? wkb : wvb;
  const int rowBase = blockIdx.y << 8, colBase = blockIdx.x << 8;

  const int c0 = tid, c1 = tid + 512;
  const int sr0 = c0 >> 3, sk0 = ((c0 & 7) ^ (sr0 & 7)) * 8;
  const int sr1 = c1 >> 3, sk1 = ((c1 & 7) ^ (sr1 & 7)) * 8;

#define STG_A(BUF, H, T)                                                      \
  do {                                                                        \
    async16(Ag + (size_t)(rowBase + (H)*128 + sr0) * 1024 + (T)*64 + sk0,     \
            (char*)As[BUF][H] + c0 * 16);                                     \
    async16(Ag + (size_t)(rowBase + (H)*128 + sr1) * 1024 + (T)*64 + sk1,     \
            (char*)As[BUF][H] + c1 * 16);                                     \
  } while (0)
#define STG_B(BUF, H, T)                                                      \
  do {                                                                        \
    async16(Bg + (size_t)(colBase + (H)*128 + sr0) * 1024 + (T)*64 + sk0,     \
            (char*)Bs[BUF][H] + c0 * 16);                                     \
    async16(Bg + (size_t)(colBase + (H)*128 + sr1) * 1024 + (T)*64 + sk1,     \
            (char*)Bs[BUF][H] + c1 * 16);                                     \
  } while (0)

  f32x4 acc[8][4];
#pragma unroll
  for (int m = 0; m < 8; m++)
#pragma unroll
    for (int n = 0; n < 4; n++) acc[m][n] = (f32x4){0.f, 0.f, 0.f, 0.f};
  short8 af[4][2], bfr[4][2];

#define RD_A(CUR, MH)                                                         \
  do {                                                                        \
    _Pragma("unroll") for (int mi = 0; mi < 4; mi++) {                        \
      int ra = (MH)*64 + mi * 16 + r;                                         \
      const u16* p = As[CUR][wm] + ra * 64;                                   \
      int sw = (ra & 7) << 3;                                                 \
      af[mi][0] = *(const short8*)(p + ((g << 3) ^ sw));                      \
      af[mi][1] = *(const short8*)(p + (((4 + g) << 3) ^ sw));                \
    }                                                                         \
  } while (0)
#define RD_B(CUR, NP)                                                         \
  do {                                                                        \
    _Pragma("unroll") for (int ni = 0; ni < 2; ni++) {                        \
      int cb = wn * 64 + ((NP)*2 + ni) * 16 + r;                              \
      const u16* p = Bs[CUR][cb >> 7] + (cb & 127) * 64;                      \
      int sw = (cb & 7) << 3;                                                 \
      bfr[(NP)*2 + ni][0] = *(const short8*)(p + ((g << 3) ^ sw));            \
      bfr[(NP)*2 + ni][1] = *(const short8*)(p + (((4 + g) << 3) ^ sw));      \
    }                                                                         \
  } while (0)
#define MM16(MH, NP)                                                          \
  do {                                                                        \
    _Pragma("unroll") for (int mi = 0; mi < 4; mi++)                          \
        _Pragma("unroll") for (int ni = 0; ni < 2; ni++) {                    \
      acc[(MH)*4 + mi][(NP)*2 + ni] = MFMA(af[mi][0], bfr[(NP)*2 + ni][0],    \
                                           acc[(MH)*4 + mi][(NP)*2 + ni]);    \
      acc[(MH)*4 + mi][(NP)*2 + ni] = MFMA(af[mi][1], bfr[(NP)*2 + ni][1],    \
                                           acc[(MH)*4 + mi][(NP)*2 + ni]);    \
    }                                                                         \
  } while (0)

  // prologue: tile0 (A+B) + A(1); leave A(1) in flight
  STG_A(0, 0, 0); STG_A(0, 1, 0); STG_B(0, 0, 0); STG_B(0, 1, 0);
  STG_A(1, 0, 1); STG_A(1, 1, 1);
  WAITV(4);
  BAR();

  for (int t = 0; t < 16; ++t) {
    const int cur = t & 1, nxt = cur ^ 1;
    // P0: A-half0 + all B; stage B(t+1)
    RD_A(cur, 0);
    RD_B(cur, 0); RD_B(cur, 1);
    if (t < 15) { STG_B(nxt, 0, t + 1); STG_B(nxt, 1, t + 1); }
    BAR(); WAITL0();
    PRIO1; MM16(0, 0); MM16(0, 1); PRIO0; BAR();
    // P1: A-half1 (B frags reused); stage A(t+2); counted wait
    RD_A(cur, 1);
    if (t < 14) {
      STG_A(cur, 0, t + 2); STG_A(cur, 1, t + 2);
      WAITV(4);  // drains A(t+1)+B(t+1); A(t+2) stays in flight
    } else {
      WAITV(0);  // drain everything before the final tiles' reads
    }
    BAR(); WAITL0();
    PRIO1; MM16(1, 0); MM16(1, 1); PRIO0; BAR();
  }
#undef STG_A
#undef STG_B
#undef RD_A
#undef RD_B
#undef MM16

  if (z < 2) {
    // RoPE fused: pair (2p,2p+1) = adjacent cols = adjacent lanes (r, r^1)
    u16* dst = z ? kb : qb;
    const float qs = z ? 1.0f : QSCALE;
#pragma unroll
    for (int m = 0; m < 8; m++)
#pragma unroll
      for (int n = 0; n < 4; n++) {
        const int col = colBase + wn * 64 + n * 16 + r;
        const int p2 = (col >> 1) & 31;
        const bool odd = col & 1;
#pragma unroll
        for (int i = 0; i < 4; i++) {
          const int row = rowBase + wm * 128 + m * 16 + g * 4 + i;  // b*2048+s
          float2 cssn = *(const float2*)(tab + row * 64 + p2 * 2);
          float v = acc[m][n][i];
          float part = __shfl_xor(v, 1);
          float res = odd ? (part * cssn.y + v * cssn.x)
                          : (v * cssn.x - part * cssn.y);
          dst[(size_t)row * 1024 + col] = f2bf(res * qs);
        }
      }
  } else {
#pragma unroll
    for (int m = 0; m < 8; m++)
#pragma unroll
      for (int n = 0; n < 4; n++)
#pragma unroll
        for (int i = 0; i < 4; i++) {
          int row = rowBase + wm * 128 + m * 16 + g * 4 + i;  // b*2048 + s
          int col = colBase + wn * 64 + n * 16 + r;           // h*64 + d
          int b = row >> 11, s = row & 2047;
          vt[(size_t)((b * 16 + (col >> 6)) * 64 + (col & 63)) * 2048 + s] =
              f2bf(acc[m][n][i]);
        }
  }
}

// ---------- GEMM core (128x128, counted vmcnt) — used by gemm_ao ----------
__device__ __forceinline__ void gemm_tile(const u16* __restrict__ A,
                                          const u16* __restrict__ Bm, int K,
                                          int rowBase, int colBase, u16* As,
                                          u16* Bs, f32x4 acc[4][4]) {
  const int tid = threadIdx.x;
  const int lane = tid & 63, wid = tid >> 6;
  const int wr = wid >> 1, wc = wid & 1;
  const int g = lane >> 4, r = lane & 15;

#pragma unroll
  for (int m = 0; m < 4; m++)
#pragma unroll
    for (int n = 0; n < 4; n++) acc[m][n] = (f32x4){0.f, 0.f, 0.f, 0.f};

#define GSTAGE(KT, BUF)                                                       \
  do {                                                                        \
    _Pragma("unroll") for (int i_ = 0; i_ < 4; ++i_) {                        \
      int c = i_ * 256 + tid;                                                 \
      int row = c >> 3, kc = (c & 7) ^ (row & 7);                             \
      async16(A + (size_t)(rowBase + row) * K + ((KT) << 6) + kc * 8,         \
              (char*)As + (BUF)*16384 + c * 16);                              \
    }                                                                         \
    _Pragma("unroll") for (int i_ = 0; i_ < 4; ++i_) {                        \
      int c = i_ * 256 + tid;                                                 \
      int row = c >> 3, kc = (c & 7) ^ (row & 7);                             \
      async16(Bm + (size_t)(colBase + row) * K + ((KT) << 6) + kc * 8,        \
              (char*)Bs + (BUF)*16384 + c * 16);                              \
    }                                                                         \
  } while (0)

  const int nkt = K >> 6;
  GSTAGE(0, 0);
  for (int kt = 0; kt < nkt; ++kt) {
    const int cur = kt & 1;
    if (kt + 1 < nkt) {
      GSTAGE(kt + 1, cur ^ 1);
      WAITV(8);
    } else {
      WAITV(0);
    }
    BAR();
    const u16* Ab = As + cur * 8192;
    const u16* Bb = Bs + cur * 8192;
#pragma unroll
    for (int ks = 0; ks < 2; ++ks) {
      short8 af[4], bfr[4];
#pragma unroll
      for (int m = 0; m < 4; m++) {
        int rr = wr * 64 + m * 16 + r;
        af[m] = *(const short8*)(Ab + rr * 64 + (((ks * 4 + g) ^ (rr & 7)) << 3));
      }
#pragma unroll
      for (int n = 0; n < 4; n++) {
        int rr = wc * 64 + n * 16 + r;
        bfr[n] = *(const short8*)(Bb + rr * 64 + (((ks * 4 + g) ^ (rr & 7)) << 3));
      }
#pragma unroll
      for (int m = 0; m < 4; m++)
#pragma unroll
        for (int n = 0; n < 4; n++)
          acc[m][n] = MFMA(af[m], bfr[n], acc[m][n]);
    }
    WAITL0();
    BAR();
  }
#undef GSTAGE
}

// ---------- 4a. flash attention pass 1: KV-split (flash-decode style) ----
// Block = (a, k, c, bh): rows [k*64,k*64+64) of q-tiles {a, 15-a}, KV tiles
// j = c (mod 2) only. 1024 blocks x 4 waves -> 4 blocks/CU = 16 waves/CU.
// Writes UNNORMALIZED partial O (bf16; c=0 -> p0, c=1 -> p1) + per-row m,l.
__global__ __launch_bounds__(256, 4) void attn_kernel(
    const u16* __restrict__ qg, const u16* __restrict__ kg,
    const u16* __restrict__ vt, u16* __restrict__ p0, u16* __restrict__ p1,
    float* __restrict__ mbuf, float* __restrict__ lbuf) {
  __shared__ u16 Ks[2][64 * 64];
  __shared__ u16 Vs[2][64 * 64];
  const int tid = threadIdx.x, wid = tid >> 6, lane = tid & 63;
  const int q5 = lane & 31, hi = lane >> 5;
  const int akc = blockIdx.x >> 5, bh = blockIdx.x & 31;
  const int a = akc >> 2, k = (akc >> 1) & 1, c = akc & 1;
  const int b = bh >> 4, h = bh & 15;
  const int base = (wid < 2) ? a : (15 - a);
  const int rb = base * 128 + k * 64 + (wid & 1) * 32;  // wave q base
  const int cmax = rb >> 5;          // last active 32-kv chunk index
  const int jend = 30 - 2 * a + k;   // block-uniform last KV-tile
  const int qrow = (b << 11) + rb + q5;

  // Q B-fragments: bq[kk] = row qrow, d = kk*16 + hi*8 + {0..7}
  short8 bq[4];
  {
    const u16* qp = qg + (size_t)qrow * 1024 + (h << 6) + hi * 8;
    bq[0] = *(const short8*)(qp);
    bq[1] = *(const short8*)(qp + 16);
    bq[2] = *(const short8*)(qp + 32);
    bq[3] = *(const short8*)(qp + 48);
  }
  f32x16 accO0 = zero16(), accO1 = zero16();  // d 0-31 / 32-63
  float m_r = -1e30f, l_r = 0.f;

#define STAGE(JT, BUF)                                                        \
  do {                                                                        \
    _Pragma("unroll") for (int i_ = 0; i_ < 2; i_++) {                        \
      int cc_ = i_ * 256 + tid;                                               \
      int row = cc_ >> 3, cc = (cc_ & 7) ^ (row & 7);                         \
      async16(kg + (size_t)((b << 11) + ((JT) << 6) + row) * 1024 +           \
                  (h << 6) + cc * 8,                                          \
              (char*)Ks[BUF] + cc_ * 16);                                     \
      async16(vt + (size_t)((bh << 6) + row) * 2048 + ((JT) << 6) + cc * 8,   \
              (char*)Vs[BUF] + cc_ * 16);                                     \
    }                                                                         \
  } while (0)

  if (c <= jend) STAGE(c, 0);

  for (int jj = c; jj <= jend; jj += 2) {
    const int cur = ((jj - c) >> 1) & 1;
    if (jj + 2 <= jend) {
      STAGE(jj + 2, cur ^ 1);  // 8 outstanding; drain oldest 4 (= tile jj)
      WAITV(4);
    } else {
      WAITV(0);
    }
    BAR();
    if (2 * jj <= cmax) {  // wave-uniform activity
      const u16* Kb = Ks[cur];
      const u16* Vb = Vs[cur];
      const bool has1 = (2 * jj + 1 <= cmax);
      const int rsw = (q5 & 7) << 3;
      // ---- QK^T: S^T chunks (kv 0-31, 32-63), col = q
      f32x16 s0 = zero16(), s1 = zero16();
      PRIO1;
#pragma unroll
      for (int kk = 0; kk < 4; kk++) {
        short8 kf =
            *(const short8*)(Kb + q5 * 64 + ((((kk << 1) + hi) << 3) ^ rsw));
        s0 = MFMA32(kf, bq[kk], s0);
      }
      PRIO0;
      if (has1) {
        PRIO1;
#pragma unroll
        for (int kk = 0; kk < 4; kk++) {
          short8 kf = *(const short8*)(Kb + (32 + q5) * 64 +
                                       ((((kk << 1) + hi) << 3) ^ rsw));
          s1 = MFMA32(kf, bq[kk], s1);
        }
        PRIO0;
      }
      // ---- causal mask on the boundary chunk (rowk > q5)
      if (2 * jj == cmax) {
#pragma unroll
        for (int rg = 0; rg < 16; rg++) {
          int rowk = (rg & 3) + 8 * (rg >> 2) + 4 * hi;
          if (rowk > q5) s0[rg] = -1e30f;
        }
      } else if (2 * jj + 1 == cmax) {
#pragma unroll
        for (int rg = 0; rg < 16; rg++) {
          int rowk = (rg & 3) + 8 * (rg >> 2) + 4 * hi;
          if (rowk > q5) s1[rg] = -1e30f;
        }
      }
      // ---- online softmax (lane owns one q-row; partner = lane^32)
      float pmax = s0[0];
#pragma unroll
      for (int rg = 1; rg < 16; rg++) pmax = fmaxf(pmax, s0[rg]);
      if (has1) {
#pragma unroll
        for (int rg = 0; rg < 16; rg++) pmax = fmaxf(pmax, s1[rg]);
      }
      pmax = fmaxf(pmax, __shfl_xor(pmax, 32));
      if (!__all(pmax <= m_r + 8.0f)) {  // T13 defer-max
        float mn = fmaxf(m_r, pmax);
        float sc = exp2hw(m_r - mn);
        l_r *= sc;
#pragma unroll
        for (int rg = 0; rg < 16; rg++) {
          accO0[rg] *= sc;
          accO1[rg] *= sc;
        }
        m_r = mn;
      }
      // ---- exp + pack + permlane-swap into PV B-fragments
      float rs = 0.f;
      u32 pw00[4], pw01[4], pw10[4], pw11[4];
#define PACK(SREG, OUT, S16)                                                  \
  do {                                                                        \
    float pp0 = exp2hw(SREG[(S16)*8 + 0] - m_r);                              \
    float pp1 = exp2hw(SREG[(S16)*8 + 1] - m_r);                              \
    float pp2 = exp2hw(SREG[(S16)*8 + 2] - m_r);                              \
    float pp3 = exp2hw(SREG[(S16)*8 + 3] - m_r);                              \
    float pp4 = exp2hw(SREG[(S16)*8 + 4] - m_r);                              \
    float pp5 = exp2hw(SREG[(S16)*8 + 5] - m_r);                              \
    float pp6 = exp2hw(SREG[(S16)*8 + 6] - m_r);                              \
    float pp7 = exp2hw(SREG[(S16)*8 + 7] - m_r);                              \
    rs += ((pp0 + pp1) + (pp2 + pp3)) + ((pp4 + pp5) + (pp6 + pp7));          \
    u32 X = cvtpk(pp0, pp1), Y = cvtpk(pp2, pp3);                             \
    u32 U = cvtpk(pp4, pp5), W = cvtpk(pp6, pp7);                             \
    plswap(X, U);                                                             \
    plswap(Y, W);                                                             \
    OUT[0] = X; OUT[1] = Y; OUT[2] = U; OUT[3] = W;                           \
  } while (0)
      PACK(s0, pw00, 0);
      PACK(s0, pw01, 1);
      if (has1) {
        PACK(s1, pw10, 0);
        PACK(s1, pw11, 1);
      }
#undef PACK
      rs += __shfl_xor(rs, 32);
      l_r += rs;
      // ---- PV: O^T += V^T * P  (A = V^T from LDS, B = packed P frags)
#define PVSTEP(PW, CH)                                                        \
  do {                                                                        \
    u32x4 pv_ = {PW[0], PW[1], PW[2], PW[3]};                                 \
    short8 pb_ = __builtin_bit_cast(short8, pv_);                             \
    short8 v0_ =                                                              \
        *(const short8*)(Vb + q5 * 64 + ((((CH) + hi) << 3) ^ rsw));          \
    short8 v1_ = *(const short8*)(Vb + (32 + q5) * 64 +                       \
                                  ((((CH) + hi) << 3) ^ rsw));                \
    accO0 = MFMA32(v0_, pb_, accO0);                                          \
    accO1 = MFMA32(v1_, pb_, accO1);                                          \
  } while (0)
      PRIO1;
      PVSTEP(pw00, 0);
      PVSTEP(pw01, 2);
      if (has1) {
        PVSTEP(pw10, 4);
        PVSTEP(pw11, 6);
      }
      PRIO0;
#undef PVSTEP
    }
    WAITL0();
    BAR();
  }
#undef STAGE

  // epilogue: write UNNORMALIZED partial; d = qd*8 + hi*4 + {0..3} (+32)
  u16* pout = c ? p1 : p0;
#pragma unroll
  for (int qd = 0; qd < 4; qd++) {
    u16x4 o0, o1;
#pragma unroll
    for (int e = 0; e < 4; e++) {
      o0[e] = f2bf(accO0[qd * 4 + e]);
      o1[e] = f2bf(accO1[qd * 4 + e]);
    }
    u16* op = pout + (size_t)qrow * 1024 + (h << 6) + qd * 8 + hi * 4;
    *(u16x4*)(op) = o0;
    *(u16x4*)(op + 32) = o1;
  }
  if (hi == 0) {
    int mli = c * 65536 + (bh << 11) + rb + q5;
    mbuf[mli] = m_r;
    lbuf[mli] = l_r;
  }
}

// ---------- 4b. merge the two KV-split partials: ab = (O0 w0 + O1 w1)/l ----
__global__ __launch_bounds__(256) void attn_merge(const u16* __restrict__ p1,
                                                  const float* __restrict__ mbuf,
                                                  const float* __restrict__ lbuf,
                                                  u16* __restrict__ ab) {
  int t = blockIdx.x * 256 + threadIdx.x;  // 524288
  int dg = t & 7, row = t >> 3;            // row in [0, 65536)
  int bh = row >> 11, s = row & 2047;
  int b = bh >> 4, h = bh & 15;
  size_t addr = (size_t)((b << 11) + s) * 1024 + (h << 6) + dg * 8;
  float m0 = mbuf[row], m1 = mbuf[65536 + row];
  float l0 = lbuf[row], l1 = lbuf[65536 + row];
  float m = fmaxf(m0, m1);
  float w0 = exp2hw(m0 - m), w1 = exp2hw(m1 - m);
  float inv = 1.0f / (l0 * w0 + l1 * w1);
  u16x8 o0 = *(const u16x8*)(ab + addr);
  u16x8 o1 = *(const u16x8*)(p1 + addr);
  u16x8 o;
#pragma unroll
  for (int i = 0; i < 8; i++)
    o[i] = f2bf((bf2f(o0[i]) * w0 + bf2f(o1[i]) * w1) * inv);
  *(u16x8*)(ab + addr) = o;
}

// ---------- 5. output projection: out = attn * wo^T (f32 out) ----------
__global__ __launch_bounds__(256) void gemm_ao(const u16* __restrict__ ab,
                                               const u16* __restrict__ wob,
                                               float* __restrict__ out) {
  __shared__ u16 As[2][128 * 64], Bs[2][128 * 64];
  f32x4 acc[4][4];
  gemm_tile(ab, wob, 1024, blockIdx.y * 128, blockIdx.x * 128, As[0], Bs[0], acc);
  const int lane = threadIdx.x & 63, wid = threadIdx.x >> 6;
  const int wr = wid >> 1, wc = wid & 1, g = lane >> 4, r = lane & 15;
  const int rowB = blockIdx.y * 128 + wr * 64;
  const int colB = blockIdx.x * 128 + wc * 64;
#pragma unroll
  for (int m = 0; m < 4; m++)
#pragma unroll
    for (int n = 0; n < 4; n++)
#pragma unroll
      for (int i = 0; i < 4; i++)
        out[(size_t)(rowB + m * 16 + g * 4 + i) * 1024 + colB + n * 16 + r] =
            acc[m][n][i];
}

extern "C" void kernel_launch(void* const* d_in, const int* in_sizes, int n_in,
                              void* d_out, int out_size, void* d_ws,
                              size_t ws_size, hipStream_t stream) {
  const float* x = (const float*)d_in[0];
  const int* tp = (const int*)d_in[1];
  const float* wq = (const float*)d_in[2];
  const float* wk = (const float*)d_in[3];
  const float* wv = (const float*)d_in[4];
  const float* wo = (const float*)d_in[5];
  float* out = (float*)d_out;

  u16* ws = (u16*)d_ws;
  u16* xb = ws;                   // 4194304 (partial-1 O after qkv256)
  u16* wqb = xb + 4194304;        // 1048576 (m-buffer after qkv256)
  u16* wkb = wqb + 1048576;       //         (l-buffer after qkv256)
  u16* wvb = wkb + 1048576;
  u16* wob = wvb + 1048576;
  u16* qb = wob + 1048576;        // 4194304
  u16* kb = qb + 4194304;
  u16* vtb = kb + 4194304;        // [b][h][d][s]
  u16* ab = vtb + 4194304;        // partial-0 O, then merged attn out
  float* tab = (float*)ab;        // 1 MB, aliases ab (dead before attn writes)
  float* mbuf = (float*)wqb;      // 512 KB (wq weights dead after qkv256)
  float* lbuf = (float*)wkb;      // 512 KB (wk weights dead after qkv256)

  convert_kernel<<<4096, 256, 0, stream>>>(x, wq, wk, wv, wo, ws);
  rope_table<<<512, 256, 0, stream>>>(tp, tab);
  gemm_qkv256<<<dim3(4, 16, 3), 512, 0, stream>>>(xb, wqb, wkb, wvb, tab, qb,
                                                  kb, vtb);
  attn_kernel<<<1024, 256, 0, stream>>>(qb, kb, vtb, ab, xb, mbuf, lbuf);
  attn_merge<<<2048, 256, 0, stream>>>(xb, mbuf, lbuf, ab);
  gemm_ao<<<dim3(8, 32), 256, 0, stream>>>(ab, wob, out);
}

// Round 10
// 115.502 us; speedup vs baseline: 2.8811x; 1.0215x over previous
//
#include <hip/hip_runtime.h>
#include <hip/hip_bf16.h>

typedef unsigned short u16;
typedef unsigned int u32;
typedef short short8 __attribute__((ext_vector_type(8)));
typedef u16 u16x8 __attribute__((ext_vector_type(8)));
typedef u16 u16x4 __attribute__((ext_vector_type(4)));
typedef u32 u32x4 __attribute__((ext_vector_type(4)));
typedef float f32x4 __attribute__((ext_vector_type(4)));
typedef float f32x16 __attribute__((ext_vector_type(16)));

#define MFMA(a, b, c) __builtin_amdgcn_mfma_f32_16x16x32_bf16((a), (b), (c), 0, 0, 0)
#define MFMA32(a, b, c) __builtin_amdgcn_mfma_f32_32x32x16_bf16((a), (b), (c), 0, 0, 0)

// log2(e)*0.125 folded into Q at projection time; softmax runs in exp2 domain.
#define QSCALE 0.18033688011112042f

// ---------- helpers ----------
__device__ __forceinline__ u16 f2bf(float f) {
  unsigned u = __float_as_uint(f);
  unsigned r = (u + 0x7fffu + ((u >> 16) & 1u)) >> 16;  // RNE
  return (u16)r;
}
__device__ __forceinline__ float bf2f(u16 h) {
  return __uint_as_float(((unsigned)h) << 16);
}
__device__ __forceinline__ float exp2hw(float x) {
  float r;
  asm("v_exp_f32 %0, %1" : "=v"(r) : "v"(x));
  return r;
}
__device__ __forceinline__ u32 cvtpk(float lo, float hi) {
  u32 d;
  asm("v_cvt_pk_bf16_f32 %0, %1, %2" : "=v"(d) : "v"(lo), "v"(hi));
  return d;
}
// v_permlane32_swap: a[32:63] <-> b[0:31]; both registers updated.
__device__ __forceinline__ void plswap(u32& a, u32& b) {
  asm volatile("v_permlane32_swap_b32 %0, %1" : "+v"(a), "+v"(b));
}
__device__ __forceinline__ void async16(const void* g, void* l) {
  __builtin_amdgcn_global_load_lds(
      (const __attribute__((address_space(1))) void*)g,
      (__attribute__((address_space(3))) void*)l, 16, 0, 0);
}
__device__ __forceinline__ f32x16 zero16() {
  f32x16 z;
#pragma unroll
  for (int i = 0; i < 16; i++) z[i] = 0.f;
  return z;
}
// counted waits (T4): keep prefetch loads in flight across barriers
#define WAITV(N) asm volatile("s_waitcnt vmcnt(" #N ")" ::: "memory")
#define WAITL0() asm volatile("s_waitcnt lgkmcnt(0)" ::: "memory")
#define BAR() __builtin_amdgcn_s_barrier()
#define PRIO1 __builtin_amdgcn_s_setprio(1)
#define PRIO0 __builtin_amdgcn_s_setprio(0)

// ---------- 1. f32 -> bf16 convert (x, wq, wk, wv, wo) ----------
__global__ __launch_bounds__(256) void convert_kernel(
    const float* __restrict__ x, const float* __restrict__ wq,
    const float* __restrict__ wk, const float* __restrict__ wv,
    const float* __restrict__ wo, u16* __restrict__ ws) {
  int blk = blockIdx.x;
  const float* src; u16* dst;
  if (blk < 2048)      { src = x;  dst = ws; }
  else if (blk < 2560) { src = wq; dst = ws + 4194304;               blk -= 2048; }
  else if (blk < 3072) { src = wk; dst = ws + 4194304 + 1048576;     blk -= 2560; }
  else if (blk < 3584) { src = wv; dst = ws + 4194304 + 2 * 1048576; blk -= 3072; }
  else                 { src = wo; dst = ws + 4194304 + 3 * 1048576; blk -= 3584; }
  int idx = (blk * 256 + threadIdx.x) * 8;
  float4 v0 = *(const float4*)(src + idx);
  float4 v1 = *(const float4*)(src + idx + 4);
  u16x8 o;
  o[0] = f2bf(v0.x); o[1] = f2bf(v0.y); o[2] = f2bf(v0.z); o[3] = f2bf(v0.w);
  o[4] = f2bf(v1.x); o[5] = f2bf(v1.y); o[6] = f2bf(v1.z); o[7] = f2bf(v1.w);
  *(u16x8*)(dst + idx) = o;
}

// ---------- 2a. cos/sin table: tab[bs*64 + p*2 + {0,1}] = cos/sin(tp[bs]*freq_p)
__global__ __launch_bounds__(256) void rope_table(const int* __restrict__ tp,
                                                  float* __restrict__ tab) {
  int t = blockIdx.x * 256 + threadIdx.x;  // 131072
  int bs = t >> 5, p = t & 31;
  float freq = exp2hw(-(float)p * 0.4152410118609203f);
  float ang = (float)tp[bs] * freq;
  float sn, cs;
  sincosf(ang, &sn, &cs);
  tab[bs * 64 + p * 2] = cs;
  tab[bs * 64 + p * 2 + 1] = sn;
}

// ---------- 2b. fused QKV projection: ONE GEMM, M=4096 N=3072 (wq|wk|wv
// contiguous), tile 256x192 -> grid 16x16 = 256 blocks = 100% CU fill.
// 8 waves (2M x 4N), per-wave 128x48, BK=64, 2-phase + counted vmcnt (T4).
__global__ __launch_bounds__(512, 2) void gemm_qkv256(
    const u16* __restrict__ xb, const u16* __restrict__ Wg,
    const float* __restrict__ tab, u16* __restrict__ qb, u16* __restrict__ kb,
    u16* __restrict__ vt) {
  __shared__ u16 As[2][16384];  // [tile-buf][256 x 64]
  __shared__ u16 Bs[2][12288];  // [tile-buf][192 x 64]
  const int tid = threadIdx.x, lane = tid & 63, wid = tid >> 6;
  const int wm = wid >> 2, wn = wid & 3;
  const int g = lane >> 4, r = lane & 15;
  const int rowBase = blockIdx.y << 8;       // M tile (256)
  const int colBase = blockIdx.x * 192;      // N tile (192) in [0, 3072)

  // staging: A = 2048 chunks (4/thread), B = 1536 chunks (3/thread);
  // inverse-swizzled source so LDS stays linear (G21)
#define STG_A(BUF, T)                                                         \
  do {                                                                        \
    _Pragma("unroll") for (int i_ = 0; i_ < 4; ++i_) {                        \
      int c = i_ * 512 + tid;                                                 \
      int row = c >> 3, kc = ((c & 7) ^ (row & 7)) * 8;                       \
      async16(xb + (size_t)(rowBase + row) * 1024 + (T)*64 + kc,              \
              (char*)As[BUF] + c * 16);                                       \
    }                                                                         \
  } while (0)
#define STG_B(BUF, T)                                                         \
  do {                                                                        \
    _Pragma("unroll") for (int i_ = 0; i_ < 3; ++i_) {                        \
      int c = i_ * 512 + tid;                                                 \
      int row = c >> 3, kc = ((c & 7) ^ (row & 7)) * 8;                       \
      async16(Wg + (size_t)(colBase + row) * 1024 + (T)*64 + kc,              \
              (char*)Bs[BUF] + c * 16);                                       \
    }                                                                         \
  } while (0)

  f32x4 acc[8][3];
#pragma unroll
  for (int m = 0; m < 8; m++)
#pragma unroll
    for (int n = 0; n < 3; n++) acc[m][n] = (f32x4){0.f, 0.f, 0.f, 0.f};
  short8 af[4][2], bfr[3][2];

#define RD_A(CUR, MH)                                                         \
  do {                                                                        \
    _Pragma("unroll") for (int mi = 0; mi < 4; mi++) {                        \
      int ra = wm * 128 + (MH)*64 + mi * 16 + r;                              \
      const u16* p = As[CUR] + ra * 64;                                       \
      int sw = (ra & 7) << 3;                                                 \
      af[mi][0] = *(const short8*)(p + ((g << 3) ^ sw));                      \
      af[mi][1] = *(const short8*)(p + (((4 + g) << 3) ^ sw));                \
    }                                                                         \
  } while (0)
#define RD_B(CUR)                                                             \
  do {                                                                        \
    _Pragma("unroll") for (int ni = 0; ni < 3; ni++) {                        \
      int cb = wn * 48 + ni * 16 + r;                                         \
      const u16* p = Bs[CUR] + cb * 64;                                       \
      int sw = (cb & 7) << 3;                                                 \
      bfr[ni][0] = *(const short8*)(p + ((g << 3) ^ sw));                     \
      bfr[ni][1] = *(const short8*)(p + (((4 + g) << 3) ^ sw));               \
    }                                                                         \
  } while (0)
#define MM24(MH)                                                              \
  do {                                                                        \
    _Pragma("unroll") for (int mi = 0; mi < 4; mi++)                          \
        _Pragma("unroll") for (int ni = 0; ni < 3; ni++) {                    \
      acc[(MH)*4 + mi][ni] = MFMA(af[mi][0], bfr[ni][0], acc[(MH)*4 + mi][ni]); \
      acc[(MH)*4 + mi][ni] = MFMA(af[mi][1], bfr[ni][1], acc[(MH)*4 + mi][ni]); \
    }                                                                         \
  } while (0)

  // prologue: tile0 (A+B) + A(1); WAITV(4) leaves A(1) in flight
  STG_A(0, 0); STG_B(0, 0);
  STG_A(1, 1);
  WAITV(4);
  BAR();

  for (int t = 0; t < 16; ++t) {
    const int cur = t & 1, nxt = cur ^ 1;
    // P0: A-half0 + all B; stage B(t+1)
    RD_A(cur, 0);
    RD_B(cur);
    if (t < 15) STG_B(nxt, t + 1);
    BAR(); WAITL0();
    PRIO1; MM24(0); PRIO0; BAR();
    // P1: A-half1 (B frags reused); stage A(t+2) into freed slot; counted wait
    RD_A(cur, 1);
    if (t < 14) {
      STG_A(cur, t + 2);
      WAITV(4);  // drains A(t+1)+B(t+1); A(t+2)'s 4 loads stay in flight
    } else {
      WAITV(0);  // drain everything before the final tiles' reads
    }
    BAR(); WAITL0();
    PRIO1; MM24(1); PRIO0; BAR();
  }
#undef STG_A
#undef STG_B
#undef RD_A
#undef RD_B
#undef MM24

  // epilogue: fragment column range never straddles a 1024-col weight
  // boundary (bases are multiples of 16) -> z = col>>10 is wave-uniform.
  const int colF = colBase + wn * 48;
#pragma unroll
  for (int n = 0; n < 3; n++) {
    const int col3 = colF + n * 16 + r;
    const int z = col3 >> 10;
    const int col = col3 & 1023;
    if (z < 2) {
      // RoPE fused: pair (2p,2p+1) = adjacent cols = adjacent lanes (r, r^1)
      u16* dst = z ? kb : qb;
      const float qs = z ? 1.0f : QSCALE;
      const int p2 = (col >> 1) & 31;
      const bool odd = col & 1;
#pragma unroll
      for (int m = 0; m < 8; m++)
#pragma unroll
        for (int i = 0; i < 4; i++) {
          const int row = rowBase + wm * 128 + m * 16 + g * 4 + i;  // b*2048+s
          float2 cssn = *(const float2*)(tab + row * 64 + p2 * 2);
          float v = acc[m][n][i];
          float part = __shfl_xor(v, 1);
          float res = odd ? (part * cssn.y + v * cssn.x)
                          : (v * cssn.x - part * cssn.y);
          dst[(size_t)row * 1024 + col] = f2bf(res * qs);
        }
    } else {
#pragma unroll
      for (int m = 0; m < 8; m++)
#pragma unroll
        for (int i = 0; i < 4; i++) {
          const int row = rowBase + wm * 128 + m * 16 + g * 4 + i;
          const int bb = row >> 11, s = row & 2047;
          vt[(size_t)((bb * 16 + (col >> 6)) * 64 + (col & 63)) * 2048 + s] =
              f2bf(acc[m][n][i]);
        }
    }
  }
}

// ---------- GEMM core (128x128, counted vmcnt) — used by gemm_ao ----------
__device__ __forceinline__ void gemm_tile(const u16* __restrict__ A,
                                          const u16* __restrict__ Bm, int K,
                                          int rowBase, int colBase, u16* As,
                                          u16* Bs, f32x4 acc[4][4]) {
  const int tid = threadIdx.x;
  const int lane = tid & 63, wid = tid >> 6;
  const int wr = wid >> 1, wc = wid & 1;
  const int g = lane >> 4, r = lane & 15;

#pragma unroll
  for (int m = 0; m < 4; m++)
#pragma unroll
    for (int n = 0; n < 4; n++) acc[m][n] = (f32x4){0.f, 0.f, 0.f, 0.f};

#define GSTAGE(KT, BUF)                                                       \
  do {                                                                        \
    _Pragma("unroll") for (int i_ = 0; i_ < 4; ++i_) {                        \
      int c = i_ * 256 + tid;                                                 \
      int row = c >> 3, kc = (c & 7) ^ (row & 7);                             \
      async16(A + (size_t)(rowBase + row) * K + ((KT) << 6) + kc * 8,         \
              (char*)As + (BUF)*16384 + c * 16);                              \
    }                                                                         \
    _Pragma("unroll") for (int i_ = 0; i_ < 4; ++i_) {                        \
      int c = i_ * 256 + tid;                                                 \
      int row = c >> 3, kc = (c & 7) ^ (row & 7);                             \
      async16(Bm + (size_t)(colBase + row) * K + ((KT) << 6) + kc * 8,        \
              (char*)Bs + (BUF)*16384 + c * 16);                              \
    }                                                                         \
  } while (0)

  const int nkt = K >> 6;
  GSTAGE(0, 0);
  for (int kt = 0; kt < nkt; ++kt) {
    const int cur = kt & 1;
    if (kt + 1 < nkt) {
      GSTAGE(kt + 1, cur ^ 1);
      WAITV(8);
    } else {
      WAITV(0);
    }
    BAR();
    const u16* Ab = As + cur * 8192;
    const u16* Bb = Bs + cur * 8192;
#pragma unroll
    for (int ks = 0; ks < 2; ++ks) {
      short8 af[4], bfr[4];
#pragma unroll
      for (int m = 0; m < 4; m++) {
        int rr = wr * 64 + m * 16 + r;
        af[m] = *(const short8*)(Ab + rr * 64 + (((ks * 4 + g) ^ (rr & 7)) << 3));
      }
#pragma unroll
      for (int n = 0; n < 4; n++) {
        int rr = wc * 64 + n * 16 + r;
        bfr[n] = *(const short8*)(Bb + rr * 64 + (((ks * 4 + g) ^ (rr & 7)) << 3));
      }
#pragma unroll
      for (int m = 0; m < 4; m++)
#pragma unroll
        for (int n = 0; n < 4; n++)
          acc[m][n] = MFMA(af[m], bfr[n], acc[m][n]);
    }
    WAITL0();
    BAR();
  }
#undef GSTAGE
}

// ---------- 4a. flash attention pass 1: KV-split (flash-decode style) ----
// Block = (a, k, c, bh): rows [k*64,k*64+64) of q-tiles {a, 15-a}, KV tiles
// j = c (mod 2) only. 1024 blocks x 4 waves -> 4 blocks/CU = 16 waves/CU.
// Writes UNNORMALIZED partial O (bf16; c=0 -> p0, c=1 -> p1) + per-row m,l.
__global__ __launch_bounds__(256, 4) void attn_kernel(
    const u16* __restrict__ qg, const u16* __restrict__ kg,
    const u16* __restrict__ vt, u16* __restrict__ p0, u16* __restrict__ p1,
    float* __restrict__ mbuf, float* __restrict__ lbuf) {
  __shared__ u16 Ks[2][64 * 64];
  __shared__ u16 Vs[2][64 * 64];
  const int tid = threadIdx.x, wid = tid >> 6, lane = tid & 63;
  const int q5 = lane & 31, hi = lane >> 5;
  const int akc = blockIdx.x >> 5, bh = blockIdx.x & 31;
  const int a = akc >> 2, k = (akc >> 1) & 1, c = akc & 1;
  const int b = bh >> 4, h = bh & 15;
  const int base = (wid < 2) ? a : (15 - a);
  const int rb = base * 128 + k * 64 + (wid & 1) * 32;  // wave q base
  const int cmax = rb >> 5;          // last active 32-kv chunk index
  const int jend = 30 - 2 * a + k;   // block-uniform last KV-tile
  const int qrow = (b << 11) + rb + q5;

  // Q B-fragments: bq[kk] = row qrow, d = kk*16 + hi*8 + {0..7}
  short8 bq[4];
  {
    const u16* qp = qg + (size_t)qrow * 1024 + (h << 6) + hi * 8;
    bq[0] = *(const short8*)(qp);
    bq[1] = *(const short8*)(qp + 16);
    bq[2] = *(const short8*)(qp + 32);
    bq[3] = *(const short8*)(qp + 48);
  }
  f32x16 accO0 = zero16(), accO1 = zero16();  // d 0-31 / 32-63
  float m_r = -1e30f, l_r = 0.f;

#define STAGE(JT, BUF)                                                        \
  do {                                                                        \
    _Pragma("unroll") for (int i_ = 0; i_ < 2; i_++) {                        \
      int cc_ = i_ * 256 + tid;                                               \
      int row = cc_ >> 3, cc = (cc_ & 7) ^ (row & 7);                         \
      async16(kg + (size_t)((b << 11) + ((JT) << 6) + row) * 1024 +           \
                  (h << 6) + cc * 8,                                          \
              (char*)Ks[BUF] + cc_ * 16);                                     \
      async16(vt + (size_t)((bh << 6) + row) * 2048 + ((JT) << 6) + cc * 8,   \
              (char*)Vs[BUF] + cc_ * 16);                                     \
    }                                                                         \
  } while (0)

  if (c <= jend) STAGE(c, 0);

  for (int jj = c; jj <= jend; jj += 2) {
    const int cur = ((jj - c) >> 1) & 1;
    if (jj + 2 <= jend) {
      STAGE(jj + 2, cur ^ 1);  // 8 outstanding; drain oldest 4 (= tile jj)
      WAITV(4);
    } else {
      WAITV(0);
    }
    BAR();
    if (2 * jj <= cmax) {  // wave-uniform activity
      const u16* Kb = Ks[cur];
      const u16* Vb = Vs[cur];
      const bool has1 = (2 * jj + 1 <= cmax);
      const int rsw = (q5 & 7) << 3;
      // ---- QK^T: S^T chunks (kv 0-31, 32-63), col = q
      f32x16 s0 = zero16(), s1 = zero16();
      PRIO1;
#pragma unroll
      for (int kk = 0; kk < 4; kk++) {
        short8 kf =
            *(const short8*)(Kb + q5 * 64 + ((((kk << 1) + hi) << 3) ^ rsw));
        s0 = MFMA32(kf, bq[kk], s0);
      }
      PRIO0;
      if (has1) {
        PRIO1;
#pragma unroll
        for (int kk = 0; kk < 4; kk++) {
          short8 kf = *(const short8*)(Kb + (32 + q5) * 64 +
                                       ((((kk << 1) + hi) << 3) ^ rsw));
          s1 = MFMA32(kf, bq[kk], s1);
        }
        PRIO0;
      }
      // ---- causal mask on the boundary chunk (rowk > q5)
      if (2 * jj == cmax) {
#pragma unroll
        for (int rg = 0; rg < 16; rg++) {
          int rowk = (rg & 3) + 8 * (rg >> 2) + 4 * hi;
          if (rowk > q5) s0[rg] = -1e30f;
        }
      } else if (2 * jj + 1 == cmax) {
#pragma unroll
        for (int rg = 0; rg < 16; rg++) {
          int rowk = (rg & 3) + 8 * (rg >> 2) + 4 * hi;
          if (rowk > q5) s1[rg] = -1e30f;
        }
      }
      // ---- online softmax (lane owns one q-row; partner = lane^32)
      float pmax = s0[0];
#pragma unroll
      for (int rg = 1; rg < 16; rg++) pmax = fmaxf(pmax, s0[rg]);
      if (has1) {
#pragma unroll
        for (int rg = 0; rg < 16; rg++) pmax = fmaxf(pmax, s1[rg]);
      }
      pmax = fmaxf(pmax, __shfl_xor(pmax, 32));
      if (!__all(pmax <= m_r + 8.0f)) {  // T13 defer-max
        float mn = fmaxf(m_r, pmax);
        float sc = exp2hw(m_r - mn);
        l_r *= sc;
#pragma unroll
        for (int rg = 0; rg < 16; rg++) {
          accO0[rg] *= sc;
          accO1[rg] *= sc;
        }
        m_r = mn;
      }
      // ---- exp + pack + permlane-swap into PV B-fragments
      float rs = 0.f;
      u32 pw00[4], pw01[4], pw10[4], pw11[4];
#define PACK(SREG, OUT, S16)                                                  \
  do {                                                                        \
    float pp0 = exp2hw(SREG[(S16)*8 + 0] - m_r);                              \
    float pp1 = exp2hw(SREG[(S16)*8 + 1] - m_r);                              \
    float pp2 = exp2hw(SREG[(S16)*8 + 2] - m_r);                              \
    float pp3 = exp2hw(SREG[(S16)*8 + 3] - m_r);                              \
    float pp4 = exp2hw(SREG[(S16)*8 + 4] - m_r);                              \
    float pp5 = exp2hw(SREG[(S16)*8 + 5] - m_r);                              \
    float pp6 = exp2hw(SREG[(S16)*8 + 6] - m_r);                              \
    float pp7 = exp2hw(SREG[(S16)*8 + 7] - m_r);                              \
    rs += ((pp0 + pp1) + (pp2 + pp3)) + ((pp4 + pp5) + (pp6 + pp7));          \
    u32 X = cvtpk(pp0, pp1), Y = cvtpk(pp2, pp3);                             \
    u32 U = cvtpk(pp4, pp5), W = cvtpk(pp6, pp7);                             \
    plswap(X, U);                                                             \
    plswap(Y, W);                                                             \
    OUT[0] = X; OUT[1] = Y; OUT[2] = U; OUT[3] = W;                           \
  } while (0)
      PACK(s0, pw00, 0);
      PACK(s0, pw01, 1);
      if (has1) {
        PACK(s1, pw10, 0);
        PACK(s1, pw11, 1);
      }
#undef PACK
      rs += __shfl_xor(rs, 32);
      l_r += rs;
      // ---- PV: O^T += V^T * P  (A = V^T from LDS, B = packed P frags)
#define PVSTEP(PW, CH)                                                        \
  do {                                                                        \
    u32x4 pv_ = {PW[0], PW[1], PW[2], PW[3]};                                 \
    short8 pb_ = __builtin_bit_cast(short8, pv_);                             \
    short8 v0_ =                                                              \
        *(const short8*)(Vb + q5 * 64 + ((((CH) + hi) << 3) ^ rsw));          \
    short8 v1_ = *(const short8*)(Vb + (32 + q5) * 64 +                       \
                                  ((((CH) + hi) << 3) ^ rsw));                \
    accO0 = MFMA32(v0_, pb_, accO0);                                          \
    accO1 = MFMA32(v1_, pb_, accO1);                                          \
  } while (0)
      PRIO1;
      PVSTEP(pw00, 0);
      PVSTEP(pw01, 2);
      if (has1) {
        PVSTEP(pw10, 4);
        PVSTEP(pw11, 6);
      }
      PRIO0;
#undef PVSTEP
    }
    WAITL0();
    BAR();
  }
#undef STAGE

  // epilogue: write UNNORMALIZED partial; d = qd*8 + hi*4 + {0..3} (+32)
  u16* pout = c ? p1 : p0;
#pragma unroll
  for (int qd = 0; qd < 4; qd++) {
    u16x4 o0, o1;
#pragma unroll
    for (int e = 0; e < 4; e++) {
      o0[e] = f2bf(accO0[qd * 4 + e]);
      o1[e] = f2bf(accO1[qd * 4 + e]);
    }
    u16* op = pout + (size_t)qrow * 1024 + (h << 6) + qd * 8 + hi * 4;
    *(u16x4*)(op) = o0;
    *(u16x4*)(op + 32) = o1;
  }
  if (hi == 0) {
    int mli = c * 65536 + (bh << 11) + rb + q5;
    mbuf[mli] = m_r;
    lbuf[mli] = l_r;
  }
}

// ---------- 4b. merge the two KV-split partials: ab = (O0 w0 + O1 w1)/l ----
__global__ __launch_bounds__(256) void attn_merge(const u16* __restrict__ p1,
                                                  const float* __restrict__ mbuf,
                                                  const float* __restrict__ lbuf,
                                                  u16* __restrict__ ab) {
  int t = blockIdx.x * 256 + threadIdx.x;  // 524288
  int dg = t & 7, row = t >> 3;            // row in [0, 65536)
  int bh = row >> 11, s = row & 2047;
  int b = bh >> 4, h = bh & 15;
  size_t addr = (size_t)((b << 11) + s) * 1024 + (h << 6) + dg * 8;
  float m0 = mbuf[row], m1 = mbuf[65536 + row];
  float l0 = lbuf[row], l1 = lbuf[65536 + row];
  float m = fmaxf(m0, m1);
  float w0 = exp2hw(m0 - m), w1 = exp2hw(m1 - m);
  float inv = 1.0f / (l0 * w0 + l1 * w1);
  u16x8 o0 = *(const u16x8*)(ab + addr);
  u16x8 o1 = *(const u16x8*)(p1 + addr);
  u16x8 o;
#pragma unroll
  for (int i = 0; i < 8; i++)
    o[i] = f2bf((bf2f(o0[i]) * w0 + bf2f(o1[i]) * w1) * inv);
  *(u16x8*)(ab + addr) = o;
}

// ---------- 5. output projection: out = attn * wo^T (f32 out) ----------
__global__ __launch_bounds__(256) void gemm_ao(const u16* __restrict__ ab,
                                               const u16* __restrict__ wob,
                                               float* __restrict__ out) {
  __shared__ u16 As[2][128 * 64], Bs[2][128 * 64];
  f32x4 acc[4][4];
  gemm_tile(ab, wob, 1024, blockIdx.y * 128, blockIdx.x * 128, As[0], Bs[0], acc);
  const int lane = threadIdx.x & 63, wid = threadIdx.x >> 6;
  const int wr = wid >> 1, wc = wid & 1, g = lane >> 4, r = lane & 15;
  const int rowB = blockIdx.y * 128 + wr * 64;
  const int colB = blockIdx.x * 128 + wc * 64;
#pragma unroll
  for (int m = 0; m < 4; m++)
#pragma unroll
    for (int n = 0; n < 4; n++)
#pragma unroll
      for (int i = 0; i < 4; i++)
        out[(size_t)(rowB + m * 16 + g * 4 + i) * 1024 + colB + n * 16 + r] =
            acc[m][n][i];
}

extern "C" void kernel_launch(void* const* d_in, const int* in_sizes, int n_in,
                              void* d_out, int out_size, void* d_ws,
                              size_t ws_size, hipStream_t stream) {
  const float* x = (const float*)d_in[0];
  const int* tp = (const int*)d_in[1];
  const float* wq = (const float*)d_in[2];
  const float* wk = (const float*)d_in[3];
  const float* wv = (const float*)d_in[4];
  const float* wo = (const float*)d_in[5];
  float* out = (float*)d_out;

  u16* ws = (u16*)d_ws;
  u16* xb = ws;                   // 4194304 (partial-1 O after qkv256)
  u16* wqb = xb + 4194304;        // 1048576 — wq|wk|wv CONTIGUOUS (fused B)
  u16* wkb = wqb + 1048576;
  u16* wvb = wkb + 1048576;
  u16* wob = wvb + 1048576;
  u16* qb = wob + 1048576;        // 4194304
  u16* kb = qb + 4194304;
  u16* vtb = kb + 4194304;        // [b][h][d][s]
  u16* ab = vtb + 4194304;        // partial-0 O, then merged attn out
  float* tab = (float*)ab;        // 1 MB, aliases ab (dead before attn writes)
  float* mbuf = (float*)wqb;      // 512 KB (wq weights dead after qkv256)
  float* lbuf = (float*)wkb;      // 512 KB (wk weights dead after qkv256)

  convert_kernel<<<4096, 256, 0, stream>>>(x, wq, wk, wv, wo, ws);
  rope_table<<<512, 256, 0, stream>>>(tp, tab);
  gemm_qkv256<<<dim3(16, 16), 512, 0, stream>>>(xb, wqb, tab, qb, kb, vtb);
  attn_kernel<<<1024, 256, 0, stream>>>(qb, kb, vtb, ab, xb, mbuf, lbuf);
  attn_merge<<<2048, 256, 0, stream>>>(xb, mbuf, lbuf, ab);
  gemm_ao<<<dim3(8, 32), 256, 0, stream>>>(ab, wob, out);
}